// Round 2
// baseline (302.073 us; speedup 1.0000x reference)
//
#include <hip/hip_runtime.h>
#include <cstdint>
#include <cstddef>

// Problem constants
#define S_LEN 1024
#define BATCH 2
#define DM    1024
#define NH    16
#define DH    64
#define CC    32     // compressed length
#define SB    2048   // S*B rows
// scan chunking (sums/scan/main)
#define TS    64
#define NCH   16
// down-kernel chunking
#define TSD   128
#define NCHD  8

using short8 = __attribute__((ext_vector_type(8))) short;
using f32x4  = __attribute__((ext_vector_type(4))) float;

__device__ __forceinline__ float b2f(unsigned short u) {
    union { unsigned int i; float f; } v; v.i = ((unsigned int)u) << 16; return v.f;
}
__device__ __forceinline__ unsigned short f2b(float f) {
    union { float f; unsigned int i; } v; v.f = f;
    unsigned int x = v.i;
    unsigned int r = x + 0x7FFFu + ((x >> 16) & 1u);
    return (unsigned short)(r >> 16);
}

// async global->LDS, 16B per lane; LDS dest is wave-uniform base + lane*16
__device__ __forceinline__ void async_ld16(const unsigned short* g, unsigned short* l) {
    __builtin_amdgcn_global_load_lds(
        (const __attribute__((address_space(1))) unsigned int*)g,
        (__attribute__((address_space(3))) unsigned int*)l,
        16, 0, 0);
}

// ---------------------------------------------------------------------------
// dtype sniffer: bf16 tensors have sane exponent fields at EVERY uint16;
// fp32 tensors read as uint16 have random mantissa bits at even indices.
// flag = 1 -> inputs are bf16; flag = 0 -> inputs are fp32.
// ---------------------------------------------------------------------------
__global__ void k_sniff(const unsigned short* x, int* flag) {
    __shared__ int cnt;
    if (threadIdx.x == 0) cnt = 0;
    __syncthreads();
    int local = 0;
    for (int i = threadIdx.x; i < 1024; i += 256) {
        unsigned e = (x[i * 2] >> 7) & 0xFF;
        if (e >= 90 && e <= 160) local++;
    }
    atomicAdd(&cnt, local);
    __syncthreads();
    if (threadIdx.x == 0) *flag = (cnt >= 640) ? 1 : 0;
}

// ---------------------------------------------------------------------------
// normalize all inputs: x, q_down, W* -> bf16 in ws; biases -> f32 in ws
// ---------------------------------------------------------------------------
__global__ __launch_bounds__(256) void k_convert(
    const void* x, const void* qd,
    const void* wq, const void* wk, const void* wv, const void* wo,
    const void* bq, const void* bk, const void* bv, const void* bo,
    const int* __restrict__ flag,
    unsigned short* xb, unsigned short* qdb,
    unsigned short* Wqb, unsigned short* Wkb, unsigned short* Wvb, unsigned short* Wob,
    float* biasf)
{
    const int isbf = *flag;
    const size_t tid = (size_t)blockIdx.x * 256 + threadIdx.x;
    const size_t stride = (size_t)gridDim.x * 256;

    auto cv = [&](const void* src, unsigned short* dst, size_t n) {
        if (isbf) {
            const unsigned short* s = (const unsigned short*)src;
            for (size_t i = tid; i < n; i += stride) dst[i] = s[i];
        } else {
            const float* s = (const float*)src;
            for (size_t i = tid; i < n; i += stride) dst[i] = f2b(s[i]);
        }
    };
    cv(x,  xb,  (size_t)SB * DM);
    cv(qd, qdb, (size_t)CC * DM);
    cv(wq, Wqb, (size_t)DM * DM);
    cv(wk, Wkb, (size_t)DM * DM);
    cv(wv, Wvb, (size_t)DM * DM);
    cv(wo, Wob, (size_t)DM * DM);
    for (size_t i = tid; i < 4 * DM; i += stride) {
        int w = (int)(i >> 10), o = (int)(i & 1023);
        const void* bp = (w == 0) ? bq : ((w == 1) ? bk : ((w == 2) ? bv : bo));
        biasf[i] = isbf ? b2f(((const unsigned short*)bp)[o]) : ((const float*)bp)[o];
    }
}

// ---------------------------------------------------------------------------
// GEMM: out[M,N] = (A[M,K] . Bt[N,K]^T + bias[N]) * scale
// A,Bt bf16; bias f32. mode: 0 = f32 out, 1 = bf16 out, 2 = flag ? bf16 : f32
// m97 structure: 128x128 tile, BK=32, 4 waves (2x2), 4x4 16x16x32 mfma/wave.
// ---------------------------------------------------------------------------
struct GArg {
    const unsigned short* A;
    const unsigned short* Bt;
    const float* bias;
    void* out;
    float scale;
    int mode;
};

__global__ __launch_bounds__(256) void gemm_bt(GArg g0, GArg g1, GArg g2,
                                               const int* __restrict__ flag,
                                               int M, int N, int K)
{
    GArg ga = (blockIdx.z == 0) ? g0 : ((blockIdx.z == 1) ? g1 : g2);
    const int m0 = blockIdx.y * 128;
    const int n0 = blockIdx.x * 128;
    __shared__ __align__(16) unsigned short As[128 * 32];
    __shared__ __align__(16) unsigned short Bs[128 * 32];
    const int t = threadIdx.x;
    const int w = t >> 6, l = t & 63;
    const int wy = w >> 1, wx = w & 1;
    const int lr = l >> 2;        // 0..15
    const int lk = (l & 3) * 8;   // k offset 0/8/16/24
    const int ln = l & 15;
    const int lq = l >> 4;        // 0..3

    f32x4 acc[4][4] = {};

    const unsigned short* Ab0 = ga.A  + (size_t)(m0 + w * 32 +      lr) * K + lk;
    const unsigned short* Ab1 = ga.A  + (size_t)(m0 + w * 32 + 16 + lr) * K + lk;
    const unsigned short* Bb0 = ga.Bt + (size_t)(n0 + w * 32 +      lr) * K + lk;
    const unsigned short* Bb1 = ga.Bt + (size_t)(n0 + w * 32 + 16 + lr) * K + lk;
    unsigned short* Al0 = &As[w * 1024];
    unsigned short* Al1 = &As[w * 1024 + 512];
    unsigned short* Bl0 = &Bs[w * 1024];
    unsigned short* Bl1 = &Bs[w * 1024 + 512];

    for (int kk = 0; kk < K; kk += 32) {
        async_ld16(Ab0 + kk, Al0);
        async_ld16(Ab1 + kk, Al1);
        async_ld16(Bb0 + kk, Bl0);
        async_ld16(Bb1 + kk, Bl1);
        __syncthreads();
        short8 af[4], bfr[4];
#pragma unroll
        for (int i = 0; i < 4; ++i)
            af[i] = *(const short8*)&As[(wy * 64 + i * 16 + ln) * 32 + lq * 8];
#pragma unroll
        for (int j = 0; j < 4; ++j)
            bfr[j] = *(const short8*)&Bs[(wx * 64 + j * 16 + ln) * 32 + lq * 8];
#pragma unroll
        for (int i = 0; i < 4; ++i)
#pragma unroll
            for (int j = 0; j < 4; ++j)
                acc[i][j] = __builtin_amdgcn_mfma_f32_16x16x32_bf16(af[i], bfr[j], acc[i][j], 0, 0, 0);
        __syncthreads();
    }

    int f32o;
    if (ga.mode == 0)      f32o = 1;
    else if (ga.mode == 1) f32o = 0;
    else                   f32o = (*flag == 0);

    const float sc = ga.scale;
#pragma unroll
    for (int j = 0; j < 4; ++j) {
        int col = n0 + wx * 64 + j * 16 + ln;
        float bv = ga.bias[col];
#pragma unroll
        for (int i = 0; i < 4; ++i) {
            int row0 = m0 + wy * 64 + i * 16 + lq * 4;
#pragma unroll
            for (int r = 0; r < 4; ++r) {
                float v = (acc[i][j][r] + bv) * sc;
                size_t idx = (size_t)(row0 + r) * N + col;
                if (f32o) ((float*)ga.out)[idx] = v;
                else      ((unsigned short*)ga.out)[idx] = f2b(v);
            }
        }
    }
}

// ---------------------------------------------------------------------------
// down[bh,c,s] = 0.125 * sum_d q_down[c, h*64+d] * k_d[b,h,s,d]; also chunk max
// ---------------------------------------------------------------------------
__global__ __launch_bounds__(256) void k_down(const float* __restrict__ kd,
                                              const unsigned short* __restrict__ qdw,
                                              float* __restrict__ wbuf,
                                              float* __restrict__ cmax)
{
    const int bh = blockIdx.x;
    const int b = bh >> 4, h = bh & 15;
    const int chunk = blockIdx.y;
    const int s0 = chunk * TSD;
    const int t = threadIdx.x;

    __shared__ float qd[CC * DH];
    __shared__ float kt[TSD * DH];
    __shared__ float pm[CC * 8];

    for (int idx = t; idx < CC * DH; idx += 256)
        qd[idx] = b2f(qdw[(idx >> 6) * DM + h * DH + (idx & 63)]);
    for (int u = t; u < TSD * DH / 4; u += 256) {
        int sl = u >> 4, d4 = (u & 15) * 4;
        *(float4*)&kt[sl * DH + d4] =
            *(const float4*)&kd[(size_t)((s0 + sl) * BATCH + b) * DM + h * DH + d4];
    }
    __syncthreads();

    const int c = t & 31;
    float lmax = -3.4e38f;
    for (int idx = t; idx < CC * TSD; idx += 256) {
        int sl = idx >> 5;
        float s = 0.f;
#pragma unroll
        for (int d = 0; d < DH; d += 4) {
            float4 qa = *(const float4*)&qd[c * DH + d];
            float4 kb = *(const float4*)&kt[sl * DH + d];
            s += qa.x * kb.x + qa.y * kb.y + qa.z * kb.z + qa.w * kb.w;
        }
        s *= 0.125f;
        wbuf[((size_t)bh * CC + c) * S_LEN + s0 + sl] = s;
        lmax = fmaxf(lmax, s);
    }
    pm[c * 8 + (t >> 5)] = lmax;
    __syncthreads();
    if (t < CC) {
        float m = pm[t * 8];
#pragma unroll
        for (int g = 1; g < 8; ++g) m = fmaxf(m, pm[t * 8 + g]);
        cmax[((size_t)bh * CC + t) * NCHD + chunk] = m;
    }
}

__global__ void k_gmax(const float* __restrict__ cmax, float* __restrict__ gmax)
{
    int i = blockIdx.x * 256 + threadIdx.x;
    if (i < BATCH * NH * CC) {
        float m = cmax[(size_t)i * NCHD];
        for (int g = 1; g < NCHD; ++g) m = fmaxf(m, cmax[(size_t)i * NCHD + g]);
        gmax[i] = m;
    }
}

// ---------------------------------------------------------------------------
// per-chunk partial sums; rewrites wbuf in place: down -> w = exp(down - gmax)
// ---------------------------------------------------------------------------
__global__ __launch_bounds__(256) void k_sums(float* __restrict__ wbuf,
                                              const float* __restrict__ gmax,
                                              const float* __restrict__ vdk,
                                              const float* __restrict__ vdv,
                                              float* __restrict__ Svk,
                                              float* __restrict__ Ssum)
{
    const int bh = blockIdx.x, b = bh >> 4, h = bh & 15;
    const int chunk = blockIdx.y, s0 = chunk * TS;
    const int t = threadIdx.x;
    __shared__ float wl[CC * TS];
    __shared__ float vt[TS * 128];

    for (int idx = t; idx < CC * TS; idx += 256) {
        int c2 = idx >> 6, sl = idx & 63;
        size_t wi = ((size_t)bh * CC + c2) * S_LEN + s0 + sl;
        float wv = __expf(wbuf[wi] - gmax[bh * CC + c2]);
        wl[c2 * TS + sl] = wv;
        wbuf[wi] = wv;
    }
    for (int u = t; u < TS * 128 / 4; u += 256) {
        int sl = u >> 5, e4 = u & 31;
        const float* src = (e4 < 16)
            ? &vdk[(size_t)((s0 + sl) * BATCH + b) * DM + h * DH + e4 * 4]
            : &vdv[(size_t)((s0 + sl) * BATCH + b) * DM + h * DH + (e4 - 16) * 4];
        *(float4*)&vt[sl * 128 + e4 * 4] = *(const float4*)src;
    }
    __syncthreads();

    const int c = t >> 3, g = t & 7;
    float acc[16];
#pragma unroll
    for (int i = 0; i < 16; ++i) acc[i] = 0.f;
    float wsum = 0.f;
    for (int sl = 0; sl < TS; ++sl) {
        float wv = wl[c * TS + sl];
        wsum += wv;
        const float* vp = &vt[sl * 128 + g * 16];
#pragma unroll
        for (int i = 0; i < 16; i += 4) {
            float4 vv = *(const float4*)&vp[i];
            acc[i]     += wv * vv.x; acc[i + 1] += wv * vv.y;
            acc[i + 2] += wv * vv.z; acc[i + 3] += wv * vv.w;
        }
    }
    size_t base = (((size_t)bh * CC + c) * NCH + chunk) * 128 + g * 16;
#pragma unroll
    for (int i = 0; i < 16; ++i) Svk[base + i] = acc[i];
    if (g == 0) Ssum[((size_t)bh * CC + c) * NCH + chunk] = wsum;
}

// exclusive prefix over chunks, in place
__global__ void k_scan(float* __restrict__ Svk, float* __restrict__ Ssum)
{
    const int bhc = blockIdx.x;   // 0..1023
    const int e = threadIdx.x;    // 0..127
    float run = 0.f;
    for (int ch = 0; ch < NCH; ++ch) {
        size_t idx = ((size_t)bhc * NCH + ch) * 128 + e;
        float v = Svk[idx]; Svk[idx] = run; run += v;
    }
    if (e == 0) {
        float rn = 0.f;
        for (int ch = 0; ch < NCH; ++ch) {
            size_t idx = (size_t)bhc * NCH + ch;
            float v = Ssum[idx]; Ssum[idx] = rn; rn += v;
        }
    }
}

// ---------------------------------------------------------------------------
// main pass: per (bh, chunk), carry base state, serial over TS=64 steps.
// LDS = 8 (wl) + 32 (vt) + 8 (qtb bf16) + 8 (red) KB = 56.5 KB < 64 KB.
// ---------------------------------------------------------------------------
__global__ __launch_bounds__(256) void k_main(const float* __restrict__ wbuf,
                                              const float* __restrict__ vdk,
                                              const float* __restrict__ vdv,
                                              const float* __restrict__ qu,
                                              const float* __restrict__ Svk,
                                              const float* __restrict__ Ssum,
                                              unsigned short* __restrict__ att_out)
{
    const int bh = blockIdx.x, b = bh >> 4, h = bh & 15;
    const int chunk = blockIdx.y, s0 = chunk * TS;
    const int t = threadIdx.x;
    __shared__ float wl[CC * TS];                         // 8 KB  [c][sl]
    __shared__ float vt[TS * 128];                        // 32 KB [sl][e]
    __shared__ __align__(16) unsigned short qtb[TS * DH]; // 8 KB  [sl][d] bf16
    __shared__ float red[CC * DH];                        // 8 KB
    __shared__ float upv[CC];
    __shared__ float pv[CC];

    for (int idx = t; idx < CC * TS; idx += 256) {
        int c2 = idx >> 6, sl = idx & 63;
        wl[c2 * TS + sl] = wbuf[((size_t)bh * CC + c2) * S_LEN + s0 + sl];
    }
    for (int u = t; u < TS * 128 / 4; u += 256) {
        int sl = u >> 5, e4 = u & 31;
        const float* src = (e4 < 16)
            ? &vdk[(size_t)((s0 + sl) * BATCH + b) * DM + h * DH + e4 * 4]
            : &vdv[(size_t)((s0 + sl) * BATCH + b) * DM + h * DH + (e4 - 16) * 4];
        *(float4*)&vt[sl * 128 + e4 * 4] = *(const float4*)src;
    }
    for (int u = t; u < TS * DH / 4; u += 256) {
        int sl = u >> 4, d4 = (u & 15) * 4;
        float4 qv = *(const float4*)&qu[(size_t)((s0 + sl) * BATCH + b) * DM + h * DH + d4];
        qtb[sl * DH + d4 + 0] = f2b(qv.x);
        qtb[sl * DH + d4 + 1] = f2b(qv.y);
        qtb[sl * DH + d4 + 2] = f2b(qv.z);
        qtb[sl * DH + d4 + 3] = f2b(qv.w);
    }

    const int c = t >> 3, g = t & 7;
    float acc[16];
    size_t base = (((size_t)bh * CC + c) * NCH + chunk) * 128 + g * 16;
#pragma unroll
    for (int i = 0; i < 16; ++i) acc[i] = Svk[base + i];
    float nn = Ssum[((size_t)bh * CC + c) * NCH + chunk];
    __syncthreads();

    for (int sl = 0; sl < TS; ++sl) {
        // A: update private accumulator slice (inclusive at sl)
        float wv = wl[c * TS + sl];
        nn += wv;
        const float innv = 1.0f / fmaxf(nn, 1e-30f);
        const float* vp = &vt[sl * 128 + g * 16];
#pragma unroll
        for (int i = 0; i < 16; i += 4) {
            float4 vv = *(const float4*)&vp[i];
            acc[i]     += wv * vv.x; acc[i + 1] += wv * vv.y;
            acc[i + 2] += wv * vv.z; acc[i + 3] += wv * vv.w;
        }
        // B: up[c] = q_u[sl] . acc_k[c] / n  (K-half owners, g<4)
        if (g < 4) {
            short8 qa = *(const short8*)&qtb[sl * DH + g * 16];
            short8 qb = *(const short8*)&qtb[sl * DH + g * 16 + 8];
            float p = 0.f;
#pragma unroll
            for (int i = 0; i < 8; ++i) {
                p += b2f((unsigned short)qa[i]) * acc[i];
                p += b2f((unsigned short)qb[i]) * acc[8 + i];
            }
            p += __shfl_xor(p, 1);
            p += __shfl_xor(p, 2);
            if (g == 0) upv[c] = p * innv;
        }
        __syncthreads();
        // softmax over c (wave 0, lanes 0..31)
        if (t < CC) {
            float v = upv[t];
            float m = v;
#pragma unroll
            for (int msk = 1; msk < CC; msk <<= 1) m = fmaxf(m, __shfl_xor(m, msk));
            float e = __expf(v - m);
            float Z = e;
#pragma unroll
            for (int msk = 1; msk < CC; msk <<= 1) Z += __shfl_xor(Z, msk);
            pv[t] = e / Z;
        }
        __syncthreads();
        // out partials: red[c][d] = (p[c]/n[c]) * acc_v[c][d]  (V-half owners)
        if (g >= 4) {
            float pc = pv[c] * innv;
            int dbase = (g - 4) * 16;
#pragma unroll
            for (int i = 0; i < 16; ++i) red[c * DH + dbase + i] = pc * acc[i];
        }
        __syncthreads();
        // final reduce over c, store bf16 row
        if (t < DH) {
            float o = 0.f;
#pragma unroll
            for (int c2 = 0; c2 < CC; ++c2) o += red[c2 * DH + t];
            att_out[(size_t)((s0 + sl) * BATCH + b) * DM + h * DH + t] = f2b(o);
        }
        __syncthreads();   // protect red before next iteration's write
    }
}

// ---------------------------------------------------------------------------
extern "C" void kernel_launch(void* const* d_in, const int* in_sizes, int n_in,
                              void* d_out, int out_size, void* d_ws, size_t ws_size,
                              hipStream_t stream)
{
    (void)in_sizes; (void)n_in; (void)out_size; (void)ws_size;
    char* ws = (char*)d_ws;
    const size_t MB = (size_t)1 << 20;
    const size_t KB = (size_t)1 << 10;
    unsigned short* v_d    = (unsigned short*)(ws + 0 * MB);   // 4 MB bf16
    unsigned short* attout = (unsigned short*)(ws + 4 * MB);   // 4 MB bf16
    float* q_u  = (float*)(ws + 8 * MB);    // 8 MB f32 (pre-scaled by 0.125)
    float* k_d  = (float*)(ws + 16 * MB);   // 8 MB
    float* v_dk = (float*)(ws + 24 * MB);   // 8 MB
    float* v_dv = (float*)(ws + 32 * MB);   // 8 MB
    float* wbuf = (float*)(ws + 40 * MB);   // 4 MB (down -> w, in place)
    float* Svk  = (float*)(ws + 44 * MB);   // 8 MB
    unsigned short* xb  = (unsigned short*)(ws + 52 * MB);   // 4 MB
    unsigned short* Wqb = (unsigned short*)(ws + 56 * MB);   // 2 MB
    unsigned short* Wkb = (unsigned short*)(ws + 58 * MB);   // 2 MB
    unsigned short* Wvb = (unsigned short*)(ws + 60 * MB);   // 2 MB
    unsigned short* Wob = (unsigned short*)(ws + 62 * MB);   // 2 MB
    unsigned short* qdb = (unsigned short*)(ws + 64 * MB);   // 64 KB
    float* biasf = (float*)(ws + 64 * MB + 64 * KB);         // 16 KB (bq,bk,bv,bo)
    float* cmax  = (float*)(ws + 64 * MB + 128 * KB);        // 32 KB
    float* gmax  = (float*)(ws + 64 * MB + 192 * KB);        // 4 KB
    float* Ssum  = (float*)(ws + 64 * MB + 256 * KB);        // 64 KB
    int*   flag  = (int*)  (ws + 65 * MB);

    // dtype sniff + input normalization
    k_sniff<<<1, 256, 0, stream>>>((const unsigned short*)d_in[0], flag);
    k_convert<<<1024, 256, 0, stream>>>(
        d_in[0], d_in[1], d_in[2], d_in[4], d_in[6], d_in[8],
        d_in[3], d_in[5], d_in[7], d_in[9],
        flag, xb, qdb, Wqb, Wkb, Wvb, Wob, biasf);

    const float* bqf = biasf;
    const float* bkf = biasf + 1024;
    const float* bvf = biasf + 2048;
    const float* bof = biasf + 3072;

    // pass 1: q_u (scaled, f32), k_d (f32), v_d (bf16)
    GArg gq{ xb, Wqb, bqf, (void*)q_u, 0.125f, 0 };
    GArg gk{ xb, Wkb, bkf, (void*)k_d, 1.0f, 0 };
    GArg gv{ xb, Wvb, bvf, (void*)v_d, 1.0f, 1 };
    gemm_bt<<<dim3(8, 16, 3), 256, 0, stream>>>(gq, gk, gv, flag, SB, DM, DM);

    // pass 2: v_d_k, v_d_v (f32)
    GArg gvk{ v_d, Wkb, bkf, (void*)v_dk, 1.0f, 0 };
    GArg gvv{ v_d, Wvb, bvf, (void*)v_dv, 1.0f, 0 };
    gemm_bt<<<dim3(8, 16, 2), 256, 0, stream>>>(gvk, gvv, gvk, flag, SB, DM, DM);

    // attention mid-section
    k_down<<<dim3(32, NCHD), 256, 0, stream>>>(k_d, qdb, wbuf, cmax);
    k_gmax<<<4, 256, 0, stream>>>(cmax, gmax);
    k_sums<<<dim3(32, NCH), 256, 0, stream>>>(wbuf, gmax, v_dk, v_dv, Svk, Ssum);
    k_scan<<<BATCH * NH * CC, 128, 0, stream>>>(Svk, Ssum);
    k_main<<<dim3(32, NCH), 256, 0, stream>>>(wbuf, v_dk, v_dv, q_u, Svk, Ssum, attout);

    // final projection: out dtype follows the sniffed input dtype
    GArg go{ attout, Wob, bof, d_out, 1.0f, 2 };
    gemm_bt<<<dim3(8, 16, 1), 256, 0, stream>>>(go, go, go, flag, SB, DM, DM);
}

// Round 3
// 293.191 us; speedup vs baseline: 1.0303x; 1.0303x over previous
//
#include <hip/hip_runtime.h>
#include <cstdint>
#include <cstddef>

// Problem constants
#define S_LEN 1024
#define BATCH 2
#define DM    1024
#define NH    16
#define DH    64
#define CC    32     // compressed length
#define SB    2048   // S*B rows
// down-kernel chunking
#define TSD   128
#define NCHD  8

using short8 = __attribute__((ext_vector_type(8))) short;
using f32x4  = __attribute__((ext_vector_type(4))) float;

__device__ __forceinline__ float b2f(unsigned short u) {
    union { unsigned int i; float f; } v; v.i = ((unsigned int)u) << 16; return v.f;
}
__device__ __forceinline__ unsigned short f2b(float f) {
    union { float f; unsigned int i; } v; v.f = f;
    unsigned int x = v.i;
    unsigned int r = x + 0x7FFFu + ((x >> 16) & 1u);
    return (unsigned short)(r >> 16);
}

// async global->LDS, 16B per lane; LDS dest is wave-uniform base + lane*16
__device__ __forceinline__ void async_ld16(const unsigned short* g, unsigned short* l) {
    __builtin_amdgcn_global_load_lds(
        (const __attribute__((address_space(1))) unsigned int*)g,
        (__attribute__((address_space(3))) unsigned int*)l,
        16, 0, 0);
}

// ---------------------------------------------------------------------------
// dtype sniffer: flag=1 -> inputs bf16; flag=0 -> inputs fp32.
// ---------------------------------------------------------------------------
__global__ void k_sniff(const unsigned short* x, int* flag) {
    __shared__ int cnt;
    if (threadIdx.x == 0) cnt = 0;
    __syncthreads();
    int local = 0;
    for (int i = threadIdx.x; i < 1024; i += 256) {
        unsigned e = (x[i * 2] >> 7) & 0xFF;
        if (e >= 90 && e <= 160) local++;
    }
    atomicAdd(&cnt, local);
    __syncthreads();
    if (threadIdx.x == 0) *flag = (cnt >= 640) ? 1 : 0;
}

// ---------------------------------------------------------------------------
// normalize inputs: x, q_down, W* -> bf16; biases -> f32 (vectorized)
// ---------------------------------------------------------------------------
__global__ __launch_bounds__(256) void k_convert(
    const void* x, const void* qd,
    const void* wq, const void* wk, const void* wv, const void* wo,
    const void* bq, const void* bk, const void* bv, const void* bo,
    const int* __restrict__ flag,
    unsigned short* xb, unsigned short* qdb,
    unsigned short* Wqb, unsigned short* Wkb, unsigned short* Wvb, unsigned short* Wob,
    float* biasf)
{
    const int isbf = *flag;
    const size_t tid = (size_t)blockIdx.x * 256 + threadIdx.x;
    const size_t stride = (size_t)gridDim.x * 256;

    auto cv = [&](const void* src, unsigned short* dst, size_t n) {
        if (isbf) {
            const short8* s = (const short8*)src;
            short8* d = (short8*)dst;
            for (size_t i = tid; i < n / 8; i += stride) d[i] = s[i];
        } else {
            const float4* s = (const float4*)src;
            for (size_t i = tid; i < n / 4; i += stride) {
                float4 v = s[i];
                ushort4 o;
                o.x = f2b(v.x); o.y = f2b(v.y); o.z = f2b(v.z); o.w = f2b(v.w);
                ((ushort4*)dst)[i] = o;
            }
        }
    };
    cv(x,  xb,  (size_t)SB * DM);
    cv(qd, qdb, (size_t)CC * DM);
    cv(wq, Wqb, (size_t)DM * DM);
    cv(wk, Wkb, (size_t)DM * DM);
    cv(wv, Wvb, (size_t)DM * DM);
    cv(wo, Wob, (size_t)DM * DM);
    for (size_t i = tid; i < 4 * DM; i += stride) {
        int w = (int)(i >> 10), o = (int)(i & 1023);
        const void* bp = (w == 0) ? bq : ((w == 1) ? bk : ((w == 2) ? bv : bo));
        biasf[i] = isbf ? b2f(((const unsigned short*)bp)[o]) : ((const float*)bp)[o];
    }
}

// ---------------------------------------------------------------------------
// GEMM: out[M,N] = (A[M,K] . Bt[N,K]^T + bias[N]) * scale
// mode: 0 = f32 out, 1 = bf16 out, 2 = flag ? bf16 : f32
// ---------------------------------------------------------------------------
struct GArg {
    const unsigned short* A;
    const unsigned short* Bt;
    const float* bias;
    void* out;
    float scale;
    int mode;
};

__global__ __launch_bounds__(256) void gemm_bt(GArg g0, GArg g1, GArg g2,
                                               const int* __restrict__ flag,
                                               int M, int N, int K)
{
    GArg ga = (blockIdx.z == 0) ? g0 : ((blockIdx.z == 1) ? g1 : g2);
    const int m0 = blockIdx.y * 128;
    const int n0 = blockIdx.x * 128;
    __shared__ __align__(16) unsigned short As[128 * 32];
    __shared__ __align__(16) unsigned short Bs[128 * 32];
    const int t = threadIdx.x;
    const int w = t >> 6, l = t & 63;
    const int wy = w >> 1, wx = w & 1;
    const int lr = l >> 2;
    const int lk = (l & 3) * 8;
    const int ln = l & 15;
    const int lq = l >> 4;

    f32x4 acc[4][4] = {};

    const unsigned short* Ab0 = ga.A  + (size_t)(m0 + w * 32 +      lr) * K + lk;
    const unsigned short* Ab1 = ga.A  + (size_t)(m0 + w * 32 + 16 + lr) * K + lk;
    const unsigned short* Bb0 = ga.Bt + (size_t)(n0 + w * 32 +      lr) * K + lk;
    const unsigned short* Bb1 = ga.Bt + (size_t)(n0 + w * 32 + 16 + lr) * K + lk;
    unsigned short* Al0 = &As[w * 1024];
    unsigned short* Al1 = &As[w * 1024 + 512];
    unsigned short* Bl0 = &Bs[w * 1024];
    unsigned short* Bl1 = &Bs[w * 1024 + 512];

    for (int kk = 0; kk < K; kk += 32) {
        async_ld16(Ab0 + kk, Al0);
        async_ld16(Ab1 + kk, Al1);
        async_ld16(Bb0 + kk, Bl0);
        async_ld16(Bb1 + kk, Bl1);
        __syncthreads();
        short8 af[4], bfr[4];
#pragma unroll
        for (int i = 0; i < 4; ++i)
            af[i] = *(const short8*)&As[(wy * 64 + i * 16 + ln) * 32 + lq * 8];
#pragma unroll
        for (int j = 0; j < 4; ++j)
            bfr[j] = *(const short8*)&Bs[(wx * 64 + j * 16 + ln) * 32 + lq * 8];
#pragma unroll
        for (int i = 0; i < 4; ++i)
#pragma unroll
            for (int j = 0; j < 4; ++j)
                acc[i][j] = __builtin_amdgcn_mfma_f32_16x16x32_bf16(af[i], bfr[j], acc[i][j], 0, 0, 0);
        __syncthreads();
    }

    int f32o;
    if (ga.mode == 0)      f32o = 1;
    else if (ga.mode == 1) f32o = 0;
    else                   f32o = (*flag == 0);

    const float sc = ga.scale;
#pragma unroll
    for (int j = 0; j < 4; ++j) {
        int col = n0 + wx * 64 + j * 16 + ln;
        float bv = ga.bias[col];
#pragma unroll
        for (int i = 0; i < 4; ++i) {
            int row0 = m0 + wy * 64 + i * 16 + lq * 4;
#pragma unroll
            for (int r = 0; r < 4; ++r) {
                float v = (acc[i][j][r] + bv) * sc;
                size_t idx = (size_t)(row0 + r) * N + col;
                if (f32o) ((float*)ga.out)[idx] = v;
                else      ((unsigned short*)ga.out)[idx] = f2b(v);
            }
        }
    }
}

// ---------------------------------------------------------------------------
// down[bh,c,s] = 0.125 * sum_d q_down[c, h*64+d] * k_d[b,h,s,d]; chunk max
// ---------------------------------------------------------------------------
__global__ __launch_bounds__(256) void k_down(const float* __restrict__ kd,
                                              const unsigned short* __restrict__ qdw,
                                              float* __restrict__ wbuf,
                                              float* __restrict__ cmax)
{
    const int bh = blockIdx.x;
    const int b = bh >> 4, h = bh & 15;
    const int chunk = blockIdx.y;
    const int s0 = chunk * TSD;
    const int t = threadIdx.x;

    __shared__ float qd[CC * DH];
    __shared__ float kt[TSD * DH];
    __shared__ float pm[CC * 8];

    for (int idx = t; idx < CC * DH; idx += 256)
        qd[idx] = b2f(qdw[(idx >> 6) * DM + h * DH + (idx & 63)]);
    for (int u = t; u < TSD * DH / 4; u += 256) {
        int sl = u >> 4, d4 = (u & 15) * 4;
        *(float4*)&kt[sl * DH + d4] =
            *(const float4*)&kd[(size_t)((s0 + sl) * BATCH + b) * DM + h * DH + d4];
    }
    __syncthreads();

    const int c = t & 31;
    float lmax = -3.4e38f;
    for (int idx = t; idx < CC * TSD; idx += 256) {
        int sl = idx >> 5;
        float s = 0.f;
#pragma unroll
        for (int d = 0; d < DH; d += 4) {
            float4 qa = *(const float4*)&qd[c * DH + d];
            float4 kb = *(const float4*)&kt[sl * DH + d];
            s += qa.x * kb.x + qa.y * kb.y + qa.z * kb.z + qa.w * kb.w;
        }
        s *= 0.125f;
        wbuf[((size_t)bh * CC + c) * S_LEN + s0 + sl] = s;
        lmax = fmaxf(lmax, s);
    }
    pm[c * 8 + (t >> 5)] = lmax;
    __syncthreads();
    if (t < CC) {
        float m = pm[t * 8];
#pragma unroll
        for (int g = 1; g < 8; ++g) m = fmaxf(m, pm[t * 8 + g]);
        cmax[((size_t)bh * CC + t) * NCHD + chunk] = m;
    }
}

__global__ void k_gmax(const float* __restrict__ cmax, float* __restrict__ gmax)
{
    int i = blockIdx.x * 256 + threadIdx.x;
    if (i < BATCH * NH * CC) {
        float m = cmax[(size_t)i * NCHD];
        for (int g = 1; g < NCHD; ++g) m = fmaxf(m, cmax[(size_t)i * NCHD + g]);
        gmax[i] = m;
    }
}

// ---------------------------------------------------------------------------
// k_w: w = exp(down-gmax) -> wb bf16 [bh][c][s], wT bf16 [bh][s][c];
//      invn f32 [bh][s][c] = 1/cumsum_s(w) (fp32 w)
// one block per bh; thread (c = t>>3, seg = t&7) owns s-range seg*128..+128
// ---------------------------------------------------------------------------
__global__ __launch_bounds__(256) void k_w(const float* __restrict__ wbuf,
                                           const float* __restrict__ gmax,
                                           unsigned short* __restrict__ wbb,
                                           unsigned short* __restrict__ wTb,
                                           float* __restrict__ invn)
{
    const int bh = blockIdx.x;
    const int t = threadIdx.x;
    const int c = t >> 3, seg = t & 7;
    __shared__ float segsum[256];
    const float gm = gmax[bh * 32 + c];
    const size_t wbase = (size_t)bh * 32768 + c * 1024 + seg * 128;
    float sum = 0.f;
    for (int i = 0; i < 128; ++i) {
        float v = __expf(wbuf[wbase + i] - gm);
        sum += v;
        unsigned short bv = f2b(v);
        wbb[wbase + i] = bv;
        wTb[(size_t)bh * 32768 + (seg * 128 + i) * 32 + c] = bv;
    }
    segsum[t] = sum;
    __syncthreads();
    float run = 0.f;
    for (int k = 0; k < seg; ++k) run += segsum[(c << 3) + k];
    for (int i = 0; i < 128; ++i) {
        float v = __expf(wbuf[wbase + i] - gm);
        run += v;
        invn[(size_t)bh * 32768 + (seg * 128 + i) * 32 + c] = 1.0f / fmaxf(run, 1e-30f);
    }
}

// ---------------------------------------------------------------------------
// k_vt: transpose v_dv bf16 [s][b][dm] -> vT bf16 [bh][d][s]
// ---------------------------------------------------------------------------
__global__ __launch_bounds__(256) void k_vt(const unsigned short* __restrict__ vdv,
                                            unsigned short* __restrict__ vT)
{
    const int bh = blockIdx.x, b = bh >> 4, h = bh & 15;
    const int s0 = blockIdx.y * 128;
    const int t = threadIdx.x;
    __shared__ unsigned short T[128 * 68];
    for (int u = t; u < 128 * 8; u += 256) {
        int r = u >> 3, cb = (u & 7) * 8;
        *(short8*)&T[r * 68 + cb] =
            *(const short8*)&vdv[(size_t)(s0 + r) * 2048 + b * 1024 + h * 64 + cb];
    }
    __syncthreads();
    for (int u = t; u < 64 * 16; u += 256) {
        int d = u >> 4, s8 = (u & 15) * 8;
        short8 o;
#pragma unroll
        for (int k = 0; k < 8; ++k) o[k] = T[(s8 + k) * 68 + d];
        *(short8*)&vT[(size_t)bh * 65536 + d * 1024 + s0 + s8] = o;
    }
}

// ---------------------------------------------------------------------------
// pass1: per (bh, q-tile 128): G = q_u @ v_dk^T (causal), up += G @ w^T,
// logits = up*invn, softmax over c, ptil = p*invn -> bf16 [bh][s][c]
// ---------------------------------------------------------------------------
__global__ __launch_bounds__(256) void k_pass1(
    const unsigned short* __restrict__ qu,
    const unsigned short* __restrict__ vdk,
    const unsigned short* __restrict__ wb,
    const float* __restrict__ invn,
    unsigned short* __restrict__ ptil)
{
    const int bh = blockIdx.x, b = bh >> 4, h = bh & 15;
    const int qi = (int)gridDim.y - 1 - (int)blockIdx.y;  // heavy blocks first
    const int s0 = qi * 128;
    const int t = threadIdx.x;
    const int w = t >> 6, l = t & 63;
    const int wy = w >> 1, wx = w & 1;
    const int ln = l & 15, lq = l >> 4;

    __shared__ __align__(16) unsigned short Kt[128 * 72];   // 18 KB [s'][d] pad
    __shared__ __align__(16) unsigned short Wt[32 * 136];   // 8.5 KB [c][s'] pad
    __shared__ __align__(16) unsigned short Gs[128 * 136];  // 34 KB [s][s'] pad

    // stage q tile (128 x 64) into Gs, load A-frags into regs
    for (int u = t; u < 128 * 8; u += 256) {
        int r = u >> 3, cb = (u & 7) * 8;
        *(short8*)&Gs[r * 136 + cb] =
            *(const short8*)&qu[(size_t)(s0 + r) * 2048 + b * 1024 + h * 64 + cb];
    }
    __syncthreads();
    short8 af[4][2];
#pragma unroll
    for (int i = 0; i < 4; ++i)
#pragma unroll
        for (int ks = 0; ks < 2; ++ks)
            af[i][ks] = *(const short8*)&Gs[(wy * 64 + i * 16 + ln) * 136 + ks * 32 + lq * 8];

    f32x4 accU[2][2] = {};

    for (int kt = 0; kt <= qi; ++kt) {
        const int sp0 = kt * 128;
        __syncthreads();  // A: prior up-phase done (Gs/Wt free); q-frags in regs
        for (int u = t; u < 128 * 8; u += 256) {
            int r = u >> 3, cb = (u & 7) * 8;
            *(short8*)&Kt[r * 72 + cb] =
                *(const short8*)&vdk[(size_t)(sp0 + r) * 2048 + b * 1024 + h * 64 + cb];
        }
        for (int u = t; u < 32 * 16; u += 256) {
            int r = u >> 4, cb = (u & 15) * 8;
            *(short8*)&Wt[r * 136 + cb] =
                *(const short8*)&wb[(size_t)bh * 32768 + r * 1024 + sp0 + cb];
        }
        __syncthreads();  // B
        f32x4 accG[4][4] = {};
#pragma unroll
        for (int ks = 0; ks < 2; ++ks) {
            short8 bf[4];
#pragma unroll
            for (int j = 0; j < 4; ++j)
                bf[j] = *(const short8*)&Kt[(wx * 64 + j * 16 + ln) * 72 + ks * 32 + lq * 8];
#pragma unroll
            for (int i = 0; i < 4; ++i)
#pragma unroll
                for (int j = 0; j < 4; ++j)
                    accG[i][j] = __builtin_amdgcn_mfma_f32_16x16x32_bf16(af[i][ks], bf[j], accG[i][j], 0, 0, 0);
        }
        const bool diag = (kt == qi);
#pragma unroll
        for (int i = 0; i < 4; ++i) {
            int row = wy * 64 + i * 16 + lq * 4;
#pragma unroll
            for (int j = 0; j < 4; ++j) {
                int col = wx * 64 + j * 16 + ln;
#pragma unroll
                for (int r = 0; r < 4; ++r) {
                    float v = accG[i][j][r];
                    if (diag && col > row + r) v = 0.f;
                    Gs[(row + r) * 136 + col] = f2b(v);
                }
            }
        }
        __syncthreads();  // C
        // up += G @ w^T  (wave w owns rows w*32..+32; cols = all 32 c)
#pragma unroll
        for (int ks = 0; ks < 4; ++ks) {
            short8 ga[2], wf[2];
#pragma unroll
            for (int u = 0; u < 2; ++u)
                ga[u] = *(const short8*)&Gs[(w * 32 + u * 16 + ln) * 136 + ks * 32 + lq * 8];
#pragma unroll
            for (int v = 0; v < 2; ++v)
                wf[v] = *(const short8*)&Wt[(v * 16 + ln) * 136 + ks * 32 + lq * 8];
#pragma unroll
            for (int u = 0; u < 2; ++u)
#pragma unroll
                for (int v = 0; v < 2; ++v)
                    accU[u][v] = __builtin_amdgcn_mfma_f32_16x16x32_bf16(ga[u], wf[v], accU[u][v], 0, 0, 0);
        }
    }

    // epilogue: logits = up*invn, softmax over 32 c, ptil = p*invn
#pragma unroll
    for (int u = 0; u < 2; ++u) {
        int rowb = s0 + w * 32 + u * 16 + lq * 4;
#pragma unroll
        for (int r = 0; r < 4; ++r) {
            int srow = rowb + r;
            float inv0 = invn[(size_t)bh * 32768 + srow * 32 + ln];
            float inv1 = invn[(size_t)bh * 32768 + srow * 32 + 16 + ln];
            float l0 = accU[u][0][r] * inv0;
            float l1 = accU[u][1][r] * inv1;
            float m = fmaxf(l0, l1);
#pragma unroll
            for (int msk = 1; msk < 16; msk <<= 1) m = fmaxf(m, __shfl_xor(m, msk));
            float e0 = __expf(l0 - m), e1 = __expf(l1 - m);
            float Z = e0 + e1;
#pragma unroll
            for (int msk = 1; msk < 16; msk <<= 1) Z += __shfl_xor(Z, msk);
            float iz = 1.0f / Z;
            ptil[(size_t)bh * 32768 + srow * 32 + ln]      = f2b(e0 * iz * inv0);
            ptil[(size_t)bh * 32768 + srow * 32 + 16 + ln] = f2b(e1 * iz * inv1);
        }
    }
}

// ---------------------------------------------------------------------------
// pass2: SC = ptil @ wT^T (causal), out += SC @ v_dv -> attout bf16 [s][b][dm]
// ---------------------------------------------------------------------------
__global__ __launch_bounds__(256) void k_pass2(
    const unsigned short* __restrict__ ptil,
    const unsigned short* __restrict__ wT,
    const unsigned short* __restrict__ vT,
    unsigned short* __restrict__ attout)
{
    const int bh = blockIdx.x, b = bh >> 4, h = bh & 15;
    const int qi = (int)gridDim.y - 1 - (int)blockIdx.y;
    const int s0 = qi * 128;
    const int t = threadIdx.x;
    const int w = t >> 6, l = t & 63;
    const int wy = w >> 1, wx = w & 1;
    const int ln = l & 15, lq = l >> 4;

    __shared__ __align__(16) unsigned short WTt[128 * 40];  // 10 KB [s'][c] pad
    __shared__ __align__(16) unsigned short Vt[64 * 136];   // 17 KB [d][s'] pad
    __shared__ __align__(16) unsigned short SCs[128 * 136]; // 34 KB [s][s'] pad

    // stage ptil tile (128 x 32) into SCs, load A-frags (K=32: one kstep)
    for (int u = t; u < 128 * 4; u += 256) {
        int r = u >> 2, cb = (u & 3) * 8;
        *(short8*)&SCs[r * 136 + cb] =
            *(const short8*)&ptil[(size_t)bh * 32768 + (s0 + r) * 32 + cb];
    }
    __syncthreads();
    short8 pa[4];
#pragma unroll
    for (int i = 0; i < 4; ++i)
        pa[i] = *(const short8*)&SCs[(wy * 64 + i * 16 + ln) * 136 + lq * 8];

    f32x4 accO[4][2] = {};

    for (int kt = 0; kt <= qi; ++kt) {
        const int sp0 = kt * 128;
        __syncthreads();  // A
        for (int u = t; u < 128 * 4; u += 256) {
            int r = u >> 2, cb = (u & 3) * 8;
            *(short8*)&WTt[r * 40 + cb] =
                *(const short8*)&wT[(size_t)bh * 32768 + (sp0 + r) * 32 + cb];
        }
        for (int u = t; u < 64 * 16; u += 256) {
            int r = u >> 4, cb = (u & 15) * 8;
            *(short8*)&Vt[r * 136 + cb] =
                *(const short8*)&vT[(size_t)bh * 65536 + r * 1024 + sp0 + cb];
        }
        __syncthreads();  // B
        f32x4 accS[4][4] = {};
        {
            short8 bf[4];
#pragma unroll
            for (int j = 0; j < 4; ++j)
                bf[j] = *(const short8*)&WTt[(wx * 64 + j * 16 + ln) * 40 + lq * 8];
#pragma unroll
            for (int i = 0; i < 4; ++i)
#pragma unroll
                for (int j = 0; j < 4; ++j)
                    accS[i][j] = __builtin_amdgcn_mfma_f32_16x16x32_bf16(pa[i], bf[j], accS[i][j], 0, 0, 0);
        }
        const bool diag = (kt == qi);
#pragma unroll
        for (int i = 0; i < 4; ++i) {
            int row = wy * 64 + i * 16 + lq * 4;
#pragma unroll
            for (int j = 0; j < 4; ++j) {
                int col = wx * 64 + j * 16 + ln;
#pragma unroll
                for (int r = 0; r < 4; ++r) {
                    float v = accS[i][j][r];
                    if (diag && col > row + r) v = 0.f;
                    SCs[(row + r) * 136 + col] = f2b(v);
                }
            }
        }
        __syncthreads();  // C
#pragma unroll
        for (int ks = 0; ks < 4; ++ks) {
            short8 sa[4], vb[2];
#pragma unroll
            for (int i = 0; i < 4; ++i)
                sa[i] = *(const short8*)&SCs[(wy * 64 + i * 16 + ln) * 136 + ks * 32 + lq * 8];
#pragma unroll
            for (int j = 0; j < 2; ++j)
                vb[j] = *(const short8*)&Vt[(wx * 32 + j * 16 + ln) * 136 + ks * 32 + lq * 8];
#pragma unroll
            for (int i = 0; i < 4; ++i)
#pragma unroll
                for (int j = 0; j < 2; ++j)
                    accO[i][j] = __builtin_amdgcn_mfma_f32_16x16x32_bf16(sa[i], vb[j], accO[i][j], 0, 0, 0);
        }
    }

#pragma unroll
    for (int i = 0; i < 4; ++i) {
        int rowb = s0 + wy * 64 + i * 16 + lq * 4;
#pragma unroll
        for (int j = 0; j < 2; ++j) {
            int d = wx * 32 + j * 16 + ln;
#pragma unroll
            for (int r = 0; r < 4; ++r)
                attout[(size_t)(rowb + r) * 2048 + b * 1024 + h * 64 + d] = f2b(accO[i][j][r]);
        }
    }
}

// ---------------------------------------------------------------------------
extern "C" void kernel_launch(void* const* d_in, const int* in_sizes, int n_in,
                              void* d_out, int out_size, void* d_ws, size_t ws_size,
                              hipStream_t stream)
{
    (void)in_sizes; (void)n_in; (void)out_size; (void)ws_size;
    char* ws = (char*)d_ws;
    const size_t MB = (size_t)1 << 20;
    const size_t KB = (size_t)1 << 10;
    unsigned short* v_d    = (unsigned short*)(ws + 0 * MB);   // 4 MB bf16
    unsigned short* attout = (unsigned short*)(ws + 4 * MB);   // 4 MB bf16
    unsigned short* q_u    = (unsigned short*)(ws + 8 * MB);   // 4 MB bf16 (pre-scaled)
    float* k_d  = (float*)(ws + 12 * MB);                      // 8 MB f32
    unsigned short* v_dk = (unsigned short*)(ws + 20 * MB);    // 4 MB bf16
    unsigned short* v_dv = (unsigned short*)(ws + 24 * MB);    // 4 MB bf16
    float* wbuf = (float*)(ws + 28 * MB);                      // 4 MB (down)
    unsigned short* wb  = (unsigned short*)(ws + 32 * MB);     // 2 MB bf16 [bh][c][s]
    unsigned short* wT  = (unsigned short*)(ws + 34 * MB);     // 2 MB bf16 [bh][s][c]
    float* invn = (float*)(ws + 36 * MB);                      // 4 MB f32 [bh][s][c]
    unsigned short* ptil = (unsigned short*)(ws + 40 * MB);    // 2 MB bf16 [bh][s][c]
    unsigned short* vT   = (unsigned short*)(ws + 42 * MB);    // 4 MB bf16 [bh][d][s]
    unsigned short* xb  = (unsigned short*)(ws + 46 * MB);     // 4 MB
    unsigned short* Wqb = (unsigned short*)(ws + 50 * MB);     // 2 MB
    unsigned short* Wkb = (unsigned short*)(ws + 52 * MB);     // 2 MB
    unsigned short* Wvb = (unsigned short*)(ws + 54 * MB);     // 2 MB
    unsigned short* Wob = (unsigned short*)(ws + 56 * MB);     // 2 MB
    unsigned short* qdb = (unsigned short*)(ws + 58 * MB);     // 64 KB
    float* biasf = (float*)(ws + 58 * MB + 64 * KB);           // 16 KB
    float* cmax  = (float*)(ws + 58 * MB + 128 * KB);          // 32 KB
    float* gmax  = (float*)(ws + 58 * MB + 192 * KB);          // 4 KB
    int*   flag  = (int*)  (ws + 58 * MB + 256 * KB);

    // dtype sniff + input normalization
    k_sniff<<<1, 256, 0, stream>>>((const unsigned short*)d_in[0], flag);
    k_convert<<<1024, 256, 0, stream>>>(
        d_in[0], d_in[1], d_in[2], d_in[4], d_in[6], d_in[8],
        d_in[3], d_in[5], d_in[7], d_in[9],
        flag, xb, qdb, Wqb, Wkb, Wvb, Wob, biasf);

    const float* bqf = biasf;
    const float* bkf = biasf + 1024;
    const float* bvf = biasf + 2048;
    const float* bof = biasf + 3072;

    // pass 1 GEMMs: q_u bf16 (scaled), k_d f32, v_d bf16
    GArg gq{ xb, Wqb, bqf, (void*)q_u, 0.125f, 1 };
    GArg gk{ xb, Wkb, bkf, (void*)k_d, 1.0f, 0 };
    GArg gv{ xb, Wvb, bvf, (void*)v_d, 1.0f, 1 };
    gemm_bt<<<dim3(8, 16, 3), 256, 0, stream>>>(gq, gk, gv, flag, SB, DM, DM);

    // pass 2 GEMMs: v_d_k, v_d_v bf16
    GArg gvk{ v_d, Wkb, bkf, (void*)v_dk, 1.0f, 1 };
    GArg gvv{ v_d, Wvb, bvf, (void*)v_dv, 1.0f, 1 };
    gemm_bt<<<dim3(8, 16, 2), 256, 0, stream>>>(gvk, gvv, gvk, flag, SB, DM, DM);

    // attention mid-section (all-MFMA reformulation)
    k_down<<<dim3(32, NCHD), 256, 0, stream>>>(k_d, qdb, wbuf, cmax);
    k_gmax<<<4, 256, 0, stream>>>(cmax, gmax);
    k_w<<<32, 256, 0, stream>>>(wbuf, gmax, wb, wT, invn);
    k_vt<<<dim3(32, 8), 256, 0, stream>>>(v_dv, vT);
    k_pass1<<<dim3(32, 8), 256, 0, stream>>>(q_u, v_dk, wb, invn, ptil);
    k_pass2<<<dim3(32, 8), 256, 0, stream>>>(ptil, wT, vT, attout);

    // final projection: out dtype follows sniffed input dtype
    GArg go{ attout, Wob, bof, d_out, 1.0f, 2 };
    gemm_bt<<<dim3(8, 16, 1), 256, 0, stream>>>(go, go, go, flag, SB, DM, DM);
}

// Round 4
// 254.573 us; speedup vs baseline: 1.1866x; 1.1517x over previous
//
#include <hip/hip_runtime.h>
#include <cstdint>
#include <cstddef>

// Problem constants
#define S_LEN 1024
#define BATCH 2
#define DM    1024
#define NH    16
#define DH    64
#define CC    32     // compressed length
#define SB    2048   // S*B rows
#define TSD   128
#define NCHD  8

using short8 = __attribute__((ext_vector_type(8))) short;
using f32x4  = __attribute__((ext_vector_type(4))) float;

__device__ __forceinline__ float b2f(unsigned short u) {
    union { unsigned int i; float f; } v; v.i = ((unsigned int)u) << 16; return v.f;
}
__device__ __forceinline__ unsigned short f2b(float f) {
    union { float f; unsigned int i; } v; v.f = f;
    unsigned int x = v.i;
    unsigned int r = x + 0x7FFFu + ((x >> 16) & 1u);
    return (unsigned short)(r >> 16);
}

__device__ __forceinline__ void async_ld16(const unsigned short* g, unsigned short* l) {
    __builtin_amdgcn_global_load_lds(
        (const __attribute__((address_space(1))) unsigned int*)g,
        (__attribute__((address_space(3))) unsigned int*)l,
        16, 0, 0);
}

// ---------------------------------------------------------------------------
// dtype sniffer: flag=1 -> inputs bf16; flag=0 -> inputs fp32.
// ---------------------------------------------------------------------------
__global__ void k_sniff(const unsigned short* x, int* flag) {
    __shared__ int cnt;
    if (threadIdx.x == 0) cnt = 0;
    __syncthreads();
    int local = 0;
    for (int i = threadIdx.x; i < 1024; i += 256) {
        unsigned e = (x[i * 2] >> 7) & 0xFF;
        if (e >= 90 && e <= 160) local++;
    }
    atomicAdd(&cnt, local);
    __syncthreads();
    if (threadIdx.x == 0) *flag = (cnt >= 640) ? 1 : 0;
}

// ---------------------------------------------------------------------------
// normalize inputs: x, q_down, W* -> bf16; biases -> f32 (vectorized)
// ---------------------------------------------------------------------------
__global__ __launch_bounds__(256) void k_convert(
    const void* x, const void* qd,
    const void* wq, const void* wk, const void* wv, const void* wo,
    const void* bq, const void* bk, const void* bv, const void* bo,
    const int* __restrict__ flag,
    unsigned short* xb, unsigned short* qdb,
    unsigned short* Wqb, unsigned short* Wkb, unsigned short* Wvb, unsigned short* Wob,
    float* biasf)
{
    const int isbf = *flag;
    const size_t tid = (size_t)blockIdx.x * 256 + threadIdx.x;
    const size_t stride = (size_t)gridDim.x * 256;

    auto cv = [&](const void* src, unsigned short* dst, size_t n) {
        if (isbf) {
            const short8* s = (const short8*)src;
            short8* d = (short8*)dst;
            for (size_t i = tid; i < n / 8; i += stride) d[i] = s[i];
        } else {
            const float4* s = (const float4*)src;
            for (size_t i = tid; i < n / 4; i += stride) {
                float4 v = s[i];
                ushort4 o;
                o.x = f2b(v.x); o.y = f2b(v.y); o.z = f2b(v.z); o.w = f2b(v.w);
                ((ushort4*)dst)[i] = o;
            }
        }
    };
    cv(x,  xb,  (size_t)SB * DM);
    cv(qd, qdb, (size_t)CC * DM);
    cv(wq, Wqb, (size_t)DM * DM);
    cv(wk, Wkb, (size_t)DM * DM);
    cv(wv, Wvb, (size_t)DM * DM);
    cv(wo, Wob, (size_t)DM * DM);
    for (size_t i = tid; i < 4 * DM; i += stride) {
        int w = (int)(i >> 10), o = (int)(i & 1023);
        const void* bp = (w == 0) ? bq : ((w == 1) ? bk : ((w == 2) ? bv : bo));
        biasf[i] = isbf ? b2f(((const unsigned short*)bp)[o]) : ((const float*)bp)[o];
    }
}

// ---------------------------------------------------------------------------
// GEMM: out[M,N] = (A[M,K] . Bt[N,K]^T + bias[N]) * scale
// mode: 0 = f32 out, 1 = bf16 out, 2 = flag ? bf16 : f32
// ---------------------------------------------------------------------------
struct GArg {
    const unsigned short* A;
    const unsigned short* Bt;
    const float* bias;
    void* out;
    float scale;
    int mode;
};

__global__ __launch_bounds__(256) void gemm_bt(GArg g0, GArg g1, GArg g2,
                                               const int* __restrict__ flag,
                                               int M, int N, int K)
{
    GArg ga = (blockIdx.z == 0) ? g0 : ((blockIdx.z == 1) ? g1 : g2);
    const int m0 = blockIdx.y * 128;
    const int n0 = blockIdx.x * 128;
    __shared__ __align__(16) unsigned short As[128 * 32];
    __shared__ __align__(16) unsigned short Bs[128 * 32];
    const int t = threadIdx.x;
    const int w = t >> 6, l = t & 63;
    const int wy = w >> 1, wx = w & 1;
    const int lr = l >> 2;
    const int lk = (l & 3) * 8;
    const int ln = l & 15;
    const int lq = l >> 4;

    f32x4 acc[4][4] = {};

    const unsigned short* Ab0 = ga.A  + (size_t)(m0 + w * 32 +      lr) * K + lk;
    const unsigned short* Ab1 = ga.A  + (size_t)(m0 + w * 32 + 16 + lr) * K + lk;
    const unsigned short* Bb0 = ga.Bt + (size_t)(n0 + w * 32 +      lr) * K + lk;
    const unsigned short* Bb1 = ga.Bt + (size_t)(n0 + w * 32 + 16 + lr) * K + lk;
    unsigned short* Al0 = &As[w * 1024];
    unsigned short* Al1 = &As[w * 1024 + 512];
    unsigned short* Bl0 = &Bs[w * 1024];
    unsigned short* Bl1 = &Bs[w * 1024 + 512];

    for (int kk = 0; kk < K; kk += 32) {
        async_ld16(Ab0 + kk, Al0);
        async_ld16(Ab1 + kk, Al1);
        async_ld16(Bb0 + kk, Bl0);
        async_ld16(Bb1 + kk, Bl1);
        __syncthreads();
        short8 af[4], bfr[4];
#pragma unroll
        for (int i = 0; i < 4; ++i)
            af[i] = *(const short8*)&As[(wy * 64 + i * 16 + ln) * 32 + lq * 8];
#pragma unroll
        for (int j = 0; j < 4; ++j)
            bfr[j] = *(const short8*)&Bs[(wx * 64 + j * 16 + ln) * 32 + lq * 8];
#pragma unroll
        for (int i = 0; i < 4; ++i)
#pragma unroll
            for (int j = 0; j < 4; ++j)
                acc[i][j] = __builtin_amdgcn_mfma_f32_16x16x32_bf16(af[i], bfr[j], acc[i][j], 0, 0, 0);
        __syncthreads();
    }

    int f32o;
    if (ga.mode == 0)      f32o = 1;
    else if (ga.mode == 1) f32o = 0;
    else                   f32o = (*flag == 0);

    const float sc = ga.scale;
#pragma unroll
    for (int j = 0; j < 4; ++j) {
        int col = n0 + wx * 64 + j * 16 + ln;
        float bv = ga.bias[col];
#pragma unroll
        for (int i = 0; i < 4; ++i) {
            int row0 = m0 + wy * 64 + i * 16 + lq * 4;
#pragma unroll
            for (int r = 0; r < 4; ++r) {
                float v = (acc[i][j][r] + bv) * sc;
                size_t idx = (size_t)(row0 + r) * N + col;
                if (f32o) ((float*)ga.out)[idx] = v;
                else      ((unsigned short*)ga.out)[idx] = f2b(v);
            }
        }
    }
}

// ---------------------------------------------------------------------------
// down[bh,c,s] = 0.125 * sum_d q_down[c,h*64+d] * k_d[s,b,h*64+d]; chunk max
// k_d is bf16 now.
// ---------------------------------------------------------------------------
__global__ __launch_bounds__(256) void k_down(const unsigned short* __restrict__ kd,
                                              const unsigned short* __restrict__ qdw,
                                              float* __restrict__ wbuf,
                                              float* __restrict__ cmax)
{
    const int bh = blockIdx.x;
    const int b = bh >> 4, h = bh & 15;
    const int chunk = blockIdx.y;
    const int s0 = chunk * TSD;
    const int t = threadIdx.x;

    __shared__ float qd[CC * DH];
    __shared__ float kt[TSD * DH];
    __shared__ float pm[CC * 8];

    for (int idx = t; idx < CC * DH; idx += 256)
        qd[idx] = b2f(qdw[(idx >> 6) * DM + h * DH + (idx & 63)]);
    for (int u = t; u < TSD * DH / 8; u += 256) {
        int sl = u >> 3, d8 = (u & 7) * 8;
        short8 v = *(const short8*)&kd[(size_t)((s0 + sl) * BATCH + b) * DM + h * DH + d8];
#pragma unroll
        for (int j = 0; j < 8; ++j) kt[sl * DH + d8 + j] = b2f((unsigned short)v[j]);
    }
    __syncthreads();

    const int c = t & 31;
    float lmax = -3.4e38f;
    for (int idx = t; idx < CC * TSD; idx += 256) {
        int sl = idx >> 5;
        float s = 0.f;
#pragma unroll
        for (int d = 0; d < DH; d += 4) {
            float4 qa = *(const float4*)&qd[c * DH + d];
            float4 kb = *(const float4*)&kt[sl * DH + d];
            s += qa.x * kb.x + qa.y * kb.y + qa.z * kb.z + qa.w * kb.w;
        }
        s *= 0.125f;
        wbuf[((size_t)bh * CC + c) * S_LEN + s0 + sl] = s;
        lmax = fmaxf(lmax, s);
    }
    pm[c * 8 + (t >> 5)] = lmax;
    __syncthreads();
    if (t < CC) {
        float m = pm[t * 8];
#pragma unroll
        for (int g = 1; g < 8; ++g) m = fmaxf(m, pm[t * 8 + g]);
        cmax[((size_t)bh * CC + t) * NCHD + chunk] = m;
    }
}

// ---------------------------------------------------------------------------
// k_wsum: per (bh, seg of 128): segsum[bh,c,seg] = sum_{s in seg} exp(down-gmax)
// gmax recomputed from cmax in-block (deterministic).
// ---------------------------------------------------------------------------
__global__ __launch_bounds__(256) void k_wsum(const float* __restrict__ wbuf,
                                              const float* __restrict__ cmax,
                                              float* __restrict__ segsum)
{
    const int bh = blockIdx.x, seg = blockIdx.y;
    const int t = threadIdx.x;
    __shared__ float gm[CC];
    if (t < CC) {
        float m = cmax[(size_t)(bh * CC + t) * NCHD];
#pragma unroll
        for (int g = 1; g < NCHD; ++g) m = fmaxf(m, cmax[(size_t)(bh * CC + t) * NCHD + g]);
        gm[t] = m;
    }
    __syncthreads();
    const int c = t >> 3, sub = t & 7;
    const float gmc = gm[c];
    const size_t base = (size_t)bh * 32768 + c * 1024 + seg * 128 + sub * 16;
    float s = 0.f;
#pragma unroll
    for (int i = 0; i < 16; ++i) s += __expf(wbuf[base + i] - gmc);
    s += __shfl_xor(s, 1);
    s += __shfl_xor(s, 2);
    s += __shfl_xor(s, 4);
    if (sub == 0) segsum[(size_t)(bh * CC + c) * 8 + seg] = s;
}

// ---------------------------------------------------------------------------
// k_wapply: per (bh, seg): w = exp(down-gmax) -> wb[bh][c][s] (coalesced) and
// wT[bh][s][c] (LDS transpose), invn[bh][s][c] = 1/cumsum (LDS transpose).
// ---------------------------------------------------------------------------
__global__ __launch_bounds__(256) void k_wapply(const float* __restrict__ wbuf,
                                                const float* __restrict__ cmax,
                                                const float* __restrict__ segsum,
                                                unsigned short* __restrict__ wb,
                                                unsigned short* __restrict__ wT,
                                                float* __restrict__ invn)
{
    const int bh = blockIdx.x, seg = blockIdx.y;
    const int t = threadIdx.x;
    __shared__ float gm[CC];
    __shared__ float basep[CC];
    __shared__ float psum[CC][9];
    __shared__ unsigned short wTt[128 * 40];  // 10 KB [s_local][c] pad
    __shared__ float invt[128 * 36];          // 18 KB [s_local][c] pad

    if (t < CC) {
        float m = cmax[(size_t)(bh * CC + t) * NCHD];
#pragma unroll
        for (int g = 1; g < NCHD; ++g) m = fmaxf(m, cmax[(size_t)(bh * CC + t) * NCHD + g]);
        gm[t] = m;
        float bsum = 0.f;
        for (int k = 0; k < seg; ++k) bsum += segsum[(size_t)(bh * CC + t) * 8 + k];
        basep[t] = bsum;
    }
    __syncthreads();

    const int c = t >> 3, sub = t & 7;
    const float gmc = gm[c];
    const size_t rbase = (size_t)bh * 32768 + c * 1024 + seg * 128 + sub * 16;
    float w16[16];
    float s = 0.f;
#pragma unroll
    for (int i = 0; i < 16; ++i) {
        float v = __expf(wbuf[rbase + i] - gmc);
        w16[i] = v; s += v;
    }
    psum[c][sub] = s;
    // wb store: 16 contiguous ushort per thread (coalesced 256B rows)
    short8 o0, o1;
#pragma unroll
    for (int i = 0; i < 8; ++i) { o0[i] = f2b(w16[i]); o1[i] = f2b(w16[8 + i]); }
    *(short8*)&wb[rbase] = o0;
    *(short8*)&wb[rbase + 8] = o1;
    // wT LDS transpose writes
#pragma unroll
    for (int i = 0; i < 16; ++i) wTt[(sub * 16 + i) * 40 + c] = f2b(w16[i]);
    __syncthreads();

    float run = basep[c];
    for (int k = 0; k < sub; ++k) run += psum[c][k];
#pragma unroll
    for (int i = 0; i < 16; ++i) {
        run += w16[i];
        invt[(sub * 16 + i) * 36 + c] = 1.0f / fmaxf(run, 1e-30f);
    }
    __syncthreads();

    // coalesced stores: wT rows (s-major, 64B/row, contiguous 8KB region)
    for (int u = t; u < 128 * 4; u += 256) {
        int r = u >> 2, cb = (u & 3) * 8;
        *(short8*)&wT[(size_t)bh * 32768 + (seg * 128 + r) * 32 + cb] =
            *(const short8*)&wTt[r * 40 + cb];
    }
    // invn rows (128B/row, contiguous 16KB region)
    for (int u = t; u < 128 * 8; u += 256) {
        int r = u >> 3, cb = (u & 7) * 4;
        *(float4*)&invn[(size_t)bh * 32768 + (seg * 128 + r) * 32 + cb] =
            *(const float4*)&invt[r * 36 + cb];
    }
}

// ---------------------------------------------------------------------------
// k_vt: transpose v_dv bf16 [s][b][dm] -> vT bf16 [bh][d][s]
// ---------------------------------------------------------------------------
__global__ __launch_bounds__(256) void k_vt(const unsigned short* __restrict__ vdv,
                                            unsigned short* __restrict__ vT)
{
    const int bh = blockIdx.x, b = bh >> 4, h = bh & 15;
    const int s0 = blockIdx.y * 128;
    const int t = threadIdx.x;
    __shared__ unsigned short T[128 * 68];
    for (int u = t; u < 128 * 8; u += 256) {
        int r = u >> 3, cb = (u & 7) * 8;
        *(short8*)&T[r * 68 + cb] =
            *(const short8*)&vdv[(size_t)(s0 + r) * 2048 + b * 1024 + h * 64 + cb];
    }
    __syncthreads();
    for (int u = t; u < 64 * 16; u += 256) {
        int d = u >> 4, s8 = (u & 15) * 8;
        short8 o;
#pragma unroll
        for (int k = 0; k < 8; ++k) o[k] = T[(s8 + k) * 68 + d];
        *(short8*)&vT[(size_t)bh * 65536 + d * 1024 + s0 + s8] = o;
    }
}

// ---------------------------------------------------------------------------
// k_att: fused pass1+pass2 per (bh, q-tile of 128 rows).
// pass1: G = q_u @ v_dk^T (causal), up += G @ w^T, softmax -> ptil (LDS only)
// pass2: SC = ptil @ wT^T (causal), out += SC @ v_dv^T -> attout
// LDS union: bufA 34 KB (Gs/SCs/ptil), bufB 29.5 KB (Kt+Wt | WTt+Vt)
// ---------------------------------------------------------------------------
__global__ __launch_bounds__(256) void k_att(
    const unsigned short* __restrict__ qu,
    const unsigned short* __restrict__ vdk,
    const unsigned short* __restrict__ wb,
    const float* __restrict__ invn,
    const unsigned short* __restrict__ wT,
    const unsigned short* __restrict__ vT,
    unsigned short* __restrict__ attout)
{
    const int bh = blockIdx.x, b = bh >> 4, h = bh & 15;
    const int qi = (int)gridDim.y - 1 - (int)blockIdx.y;  // heavy blocks first
    const int s0 = qi * 128;
    const int t = threadIdx.x;
    const int w = t >> 6, l = t & 63;
    const int wy = w >> 1, wx = w & 1;
    const int ln = l & 15, lq = l >> 4;

    __shared__ __align__(16) unsigned short bufA[128 * 136];  // 34 KB
    __shared__ __align__(16) unsigned short bufB[15104];      // 29.5 KB
    unsigned short* Kt  = bufB;           // pass1: 128*72 = 9216
    unsigned short* Wt  = bufB + 9216;    // pass1: 32*136 = 4352 (13568 total)
    unsigned short* WTt = bufB;           // pass2: 128*40 = 5120
    unsigned short* Vt  = bufB + 5120;    // pass2: 64*136 = 8704 (13824 total)

    // ---- pass 1 ----
    for (int u = t; u < 128 * 8; u += 256) {
        int r = u >> 3, cb = (u & 7) * 8;
        *(short8*)&bufA[r * 136 + cb] =
            *(const short8*)&qu[(size_t)(s0 + r) * 2048 + b * 1024 + h * 64 + cb];
    }
    __syncthreads();
    short8 af[4][2];
#pragma unroll
    for (int i = 0; i < 4; ++i)
#pragma unroll
        for (int ks = 0; ks < 2; ++ks)
            af[i][ks] = *(const short8*)&bufA[(wy * 64 + i * 16 + ln) * 136 + ks * 32 + lq * 8];

    f32x4 accU[2][2] = {};

    for (int kt = 0; kt <= qi; ++kt) {
        const int sp0 = kt * 128;
        __syncthreads();  // A: prior phase's bufA/bufB reads done
        for (int u = t; u < 128 * 8; u += 256) {
            int r = u >> 3, cb = (u & 7) * 8;
            *(short8*)&Kt[r * 72 + cb] =
                *(const short8*)&vdk[(size_t)(sp0 + r) * 2048 + b * 1024 + h * 64 + cb];
        }
        for (int u = t; u < 32 * 16; u += 256) {
            int r = u >> 4, cb = (u & 15) * 8;
            *(short8*)&Wt[r * 136 + cb] =
                *(const short8*)&wb[(size_t)bh * 32768 + r * 1024 + sp0 + cb];
        }
        __syncthreads();  // B
        f32x4 accG[4][4] = {};
#pragma unroll
        for (int ks = 0; ks < 2; ++ks) {
            short8 bf[4];
#pragma unroll
            for (int j = 0; j < 4; ++j)
                bf[j] = *(const short8*)&Kt[(wx * 64 + j * 16 + ln) * 72 + ks * 32 + lq * 8];
#pragma unroll
            for (int i = 0; i < 4; ++i)
#pragma unroll
                for (int j = 0; j < 4; ++j)
                    accG[i][j] = __builtin_amdgcn_mfma_f32_16x16x32_bf16(af[i][ks], bf[j], accG[i][j], 0, 0, 0);
        }
        const bool diag = (kt == qi);
#pragma unroll
        for (int i = 0; i < 4; ++i) {
            int row = wy * 64 + i * 16 + lq * 4;
#pragma unroll
            for (int j = 0; j < 4; ++j) {
                int col = wx * 64 + j * 16 + ln;
#pragma unroll
                for (int r = 0; r < 4; ++r) {
                    float v = accG[i][j][r];
                    if (diag && col > row + r) v = 0.f;
                    bufA[(row + r) * 136 + col] = f2b(v);
                }
            }
        }
        __syncthreads();  // C
#pragma unroll
        for (int ks = 0; ks < 4; ++ks) {
            short8 ga[2], wf[2];
#pragma unroll
            for (int u = 0; u < 2; ++u)
                ga[u] = *(const short8*)&bufA[(w * 32 + u * 16 + ln) * 136 + ks * 32 + lq * 8];
#pragma unroll
            for (int v = 0; v < 2; ++v)
                wf[v] = *(const short8*)&Wt[(v * 16 + ln) * 136 + ks * 32 + lq * 8];
#pragma unroll
            for (int u = 0; u < 2; ++u)
#pragma unroll
                for (int v = 0; v < 2; ++v)
                    accU[u][v] = __builtin_amdgcn_mfma_f32_16x16x32_bf16(ga[u], wf[v], accU[u][v], 0, 0, 0);
        }
    }

    __syncthreads();  // all up-GEMM reads of bufA done; reuse bufA for ptil
    // epilogue pass1: logits = up*invn, softmax over c, ptil -> bufA
#pragma unroll
    for (int u = 0; u < 2; ++u) {
        int rowl = w * 32 + u * 16 + lq * 4;
#pragma unroll
        for (int r = 0; r < 4; ++r) {
            int srow = s0 + rowl + r;
            float inv0 = invn[(size_t)bh * 32768 + srow * 32 + ln];
            float inv1 = invn[(size_t)bh * 32768 + srow * 32 + 16 + ln];
            float l0 = accU[u][0][r] * inv0;
            float l1 = accU[u][1][r] * inv1;
            float m = fmaxf(l0, l1);
#pragma unroll
            for (int msk = 1; msk < 16; msk <<= 1) m = fmaxf(m, __shfl_xor(m, msk));
            float e0 = __expf(l0 - m), e1 = __expf(l1 - m);
            float Z = e0 + e1;
#pragma unroll
            for (int msk = 1; msk < 16; msk <<= 1) Z += __shfl_xor(Z, msk);
            float iz = 1.0f / Z;
            bufA[(rowl + r) * 136 + ln]      = f2b(e0 * iz * inv0);
            bufA[(rowl + r) * 136 + 16 + ln] = f2b(e1 * iz * inv1);
        }
    }
    __syncthreads();

    // ---- pass 2 ----
    short8 pa[4];
#pragma unroll
    for (int i = 0; i < 4; ++i)
        pa[i] = *(const short8*)&bufA[(wy * 64 + i * 16 + ln) * 136 + lq * 8];

    f32x4 accO[4][2] = {};

    for (int kt = 0; kt <= qi; ++kt) {
        const int sp0 = kt * 128;
        __syncthreads();  // A (first iter: pa reads done)
        for (int u = t; u < 128 * 4; u += 256) {
            int r = u >> 2, cb = (u & 3) * 8;
            *(short8*)&WTt[r * 40 + cb] =
                *(const short8*)&wT[(size_t)bh * 32768 + (sp0 + r) * 32 + cb];
        }
        for (int u = t; u < 64 * 16; u += 256) {
            int r = u >> 4, cb = (u & 15) * 8;
            *(short8*)&Vt[r * 136 + cb] =
                *(const short8*)&vT[(size_t)bh * 65536 + r * 1024 + sp0 + cb];
        }
        __syncthreads();  // B
        f32x4 accS[4][4] = {};
        {
            short8 bf[4];
#pragma unroll
            for (int j = 0; j < 4; ++j)
                bf[j] = *(const short8*)&WTt[(wx * 64 + j * 16 + ln) * 40 + lq * 8];
#pragma unroll
            for (int i = 0; i < 4; ++i)
#pragma unroll
                for (int j = 0; j < 4; ++j)
                    accS[i][j] = __builtin_amdgcn_mfma_f32_16x16x32_bf16(pa[i], bf[j], accS[i][j], 0, 0, 0);
        }
        const bool diag = (kt == qi);
#pragma unroll
        for (int i = 0; i < 4; ++i) {
            int row = wy * 64 + i * 16 + lq * 4;
#pragma unroll
            for (int j = 0; j < 4; ++j) {
                int col = wx * 64 + j * 16 + ln;
#pragma unroll
                for (int r = 0; r < 4; ++r) {
                    float v = accS[i][j][r];
                    if (diag && col > row + r) v = 0.f;
                    bufA[(row + r) * 136 + col] = f2b(v);
                }
            }
        }
        __syncthreads();  // C
#pragma unroll
        for (int ks = 0; ks < 4; ++ks) {
            short8 sa[4], vb[2];
#pragma unroll
            for (int i = 0; i < 4; ++i)
                sa[i] = *(const short8*)&bufA[(wy * 64 + i * 16 + ln) * 136 + ks * 32 + lq * 8];
#pragma unroll
            for (int j = 0; j < 2; ++j)
                vb[j] = *(const short8*)&Vt[(wx * 32 + j * 16 + ln) * 136 + ks * 32 + lq * 8];
#pragma unroll
            for (int i = 0; i < 4; ++i)
#pragma unroll
                for (int j = 0; j < 2; ++j)
                    accO[i][j] = __builtin_amdgcn_mfma_f32_16x16x32_bf16(sa[i], vb[j], accO[i][j], 0, 0, 0);
        }
    }

#pragma unroll
    for (int i = 0; i < 4; ++i) {
        int rowb = s0 + wy * 64 + i * 16 + lq * 4;
#pragma unroll
        for (int j = 0; j < 2; ++j) {
            int d = wx * 32 + j * 16 + ln;
#pragma unroll
            for (int r = 0; r < 4; ++r)
                attout[(size_t)(rowb + r) * 2048 + b * 1024 + h * 64 + d] = f2b(accO[i][j][r]);
        }
    }
}

// ---------------------------------------------------------------------------
extern "C" void kernel_launch(void* const* d_in, const int* in_sizes, int n_in,
                              void* d_out, int out_size, void* d_ws, size_t ws_size,
                              hipStream_t stream)
{
    (void)in_sizes; (void)n_in; (void)out_size; (void)ws_size;
    char* ws = (char*)d_ws;
    const size_t MB = (size_t)1 << 20;
    const size_t KB = (size_t)1 << 10;
    unsigned short* v_d    = (unsigned short*)(ws + 0 * MB);   // 4 MB
    unsigned short* attout = (unsigned short*)(ws + 4 * MB);   // 4 MB
    unsigned short* q_u    = (unsigned short*)(ws + 8 * MB);   // 4 MB (pre-scaled)
    unsigned short* k_d    = (unsigned short*)(ws + 12 * MB);  // 4 MB bf16
    unsigned short* v_dk   = (unsigned short*)(ws + 16 * MB);  // 4 MB
    unsigned short* v_dv   = (unsigned short*)(ws + 20 * MB);  // 4 MB
    float* wbuf = (float*)(ws + 24 * MB);                      // 4 MB (down scores)
    unsigned short* wb  = (unsigned short*)(ws + 28 * MB);     // 2 MB [bh][c][s]
    unsigned short* wT  = (unsigned short*)(ws + 30 * MB);     // 2 MB [bh][s][c]
    float* invn = (float*)(ws + 32 * MB);                      // 4 MB [bh][s][c]
    unsigned short* vT  = (unsigned short*)(ws + 36 * MB);     // 4 MB [bh][d][s]
    unsigned short* xb  = (unsigned short*)(ws + 40 * MB);     // 4 MB
    unsigned short* Wqb = (unsigned short*)(ws + 44 * MB);     // 2 MB
    unsigned short* Wkb = (unsigned short*)(ws + 46 * MB);     // 2 MB
    unsigned short* Wvb = (unsigned short*)(ws + 48 * MB);     // 2 MB
    unsigned short* Wob = (unsigned short*)(ws + 50 * MB);     // 2 MB
    unsigned short* qdb = (unsigned short*)(ws + 52 * MB);     // 64 KB
    float* biasf  = (float*)(ws + 52 * MB + 64 * KB);          // 16 KB
    float* cmax   = (float*)(ws + 52 * MB + 128 * KB);         // 32 KB
    float* segsum = (float*)(ws + 52 * MB + 192 * KB);         // 32 KB
    int*   flag   = (int*)  (ws + 52 * MB + 256 * KB);

    k_sniff<<<1, 256, 0, stream>>>((const unsigned short*)d_in[0], flag);
    k_convert<<<1024, 256, 0, stream>>>(
        d_in[0], d_in[1], d_in[2], d_in[4], d_in[6], d_in[8],
        d_in[3], d_in[5], d_in[7], d_in[9],
        flag, xb, qdb, Wqb, Wkb, Wvb, Wob, biasf);

    const float* bqf = biasf;
    const float* bkf = biasf + 1024;
    const float* bvf = biasf + 2048;
    const float* bof = biasf + 3072;

    // pass 1 GEMMs: q_u (scaled), k_d, v_d — all bf16 out
    GArg gq{ xb, Wqb, bqf, (void*)q_u, 0.125f, 1 };
    GArg gk{ xb, Wkb, bkf, (void*)k_d, 1.0f, 1 };
    GArg gv{ xb, Wvb, bvf, (void*)v_d, 1.0f, 1 };
    gemm_bt<<<dim3(8, 16, 3), 256, 0, stream>>>(gq, gk, gv, flag, SB, DM, DM);

    // pass 2 GEMMs: v_d_k, v_d_v bf16
    GArg gvk{ v_d, Wkb, bkf, (void*)v_dk, 1.0f, 1 };
    GArg gvv{ v_d, Wvb, bvf, (void*)v_dv, 1.0f, 1 };
    gemm_bt<<<dim3(8, 16, 2), 256, 0, stream>>>(gvk, gvv, gvk, flag, SB, DM, DM);

    // attention mid-section
    k_down<<<dim3(32, NCHD), 256, 0, stream>>>(k_d, qdb, wbuf, cmax);
    k_wsum<<<dim3(32, 8), 256, 0, stream>>>(wbuf, cmax, segsum);
    k_wapply<<<dim3(32, 8), 256, 0, stream>>>(wbuf, cmax, segsum, wb, wT, invn);
    k_vt<<<dim3(32, 8), 256, 0, stream>>>(v_dv, vT);
    k_att<<<dim3(32, 8), 256, 0, stream>>>(q_u, v_dk, wb, invn, wT, vT, attout);

    // final projection: out dtype follows sniffed input dtype
    GArg go{ attout, Wob, bof, d_out, 1.0f, 2 };
    gemm_bt<<<dim3(8, 16, 1), 256, 0, stream>>>(go, go, go, flag, SB, DM, DM);
}

// Round 5
// 240.675 us; speedup vs baseline: 1.2551x; 1.0577x over previous
//
#include <hip/hip_runtime.h>
#include <cstdint>
#include <cstddef>

// Problem constants
#define S_LEN 1024
#define BATCH 2
#define DM    1024
#define NH    16
#define DH    64
#define CC    32     // compressed length
#define SB    2048   // S*B rows
#define TSD   128
#define NCHD  8

using short8 = __attribute__((ext_vector_type(8))) short;
using f32x4  = __attribute__((ext_vector_type(4))) float;

__device__ __forceinline__ float b2f(unsigned short u) {
    union { unsigned int i; float f; } v; v.i = ((unsigned int)u) << 16; return v.f;
}
__device__ __forceinline__ unsigned short f2b(float f) {
    union { float f; unsigned int i; } v; v.f = f;
    unsigned int x = v.i;
    unsigned int r = x + 0x7FFFu + ((x >> 16) & 1u);
    return (unsigned short)(r >> 16);
}

__device__ __forceinline__ void async_ld16(const unsigned short* g, unsigned short* l) {
    __builtin_amdgcn_global_load_lds(
        (const __attribute__((address_space(1))) unsigned int*)g,
        (__attribute__((address_space(3))) unsigned int*)l,
        16, 0, 0);
}

// ---------------------------------------------------------------------------
// dtype sniffer: flag=1 -> inputs bf16; flag=0 -> inputs fp32.
// ---------------------------------------------------------------------------
__global__ void k_sniff(const unsigned short* x, int* flag) {
    __shared__ int cnt;
    if (threadIdx.x == 0) cnt = 0;
    __syncthreads();
    int local = 0;
    for (int i = threadIdx.x; i < 1024; i += 256) {
        unsigned e = (x[i * 2] >> 7) & 0xFF;
        if (e >= 90 && e <= 160) local++;
    }
    atomicAdd(&cnt, local);
    __syncthreads();
    if (threadIdx.x == 0) *flag = (cnt >= 640) ? 1 : 0;
}

// ---------------------------------------------------------------------------
// normalize inputs: x, q_down, W* -> bf16; biases -> f32 (vectorized)
// ---------------------------------------------------------------------------
__global__ __launch_bounds__(256) void k_convert(
    const void* x, const void* qd,
    const void* wq, const void* wk, const void* wv, const void* wo,
    const void* bq, const void* bk, const void* bv, const void* bo,
    const int* __restrict__ flag,
    unsigned short* xb, unsigned short* qdb,
    unsigned short* Wqb, unsigned short* Wkb, unsigned short* Wvb, unsigned short* Wob,
    float* biasf)
{
    const int isbf = *flag;
    const size_t tid = (size_t)blockIdx.x * 256 + threadIdx.x;
    const size_t stride = (size_t)gridDim.x * 256;

    auto cv = [&](const void* src, unsigned short* dst, size_t n) {
        if (isbf) {
            const short8* s = (const short8*)src;
            short8* d = (short8*)dst;
            for (size_t i = tid; i < n / 8; i += stride) d[i] = s[i];
        } else {
            const float4* s = (const float4*)src;
            for (size_t i = tid; i < n / 4; i += stride) {
                float4 v = s[i];
                ushort4 o;
                o.x = f2b(v.x); o.y = f2b(v.y); o.z = f2b(v.z); o.w = f2b(v.w);
                ((ushort4*)dst)[i] = o;
            }
        }
    };
    cv(x,  xb,  (size_t)SB * DM);
    cv(qd, qdb, (size_t)CC * DM);
    cv(wq, Wqb, (size_t)DM * DM);
    cv(wk, Wkb, (size_t)DM * DM);
    cv(wv, Wvb, (size_t)DM * DM);
    cv(wo, Wob, (size_t)DM * DM);
    for (size_t i = tid; i < 4 * DM; i += stride) {
        int w = (int)(i >> 10), o = (int)(i & 1023);
        const void* bp = (w == 0) ? bq : ((w == 1) ? bk : ((w == 2) ? bv : bo));
        biasf[i] = isbf ? b2f(((const unsigned short*)bp)[o]) : ((const float*)bp)[o];
    }
}

// ---------------------------------------------------------------------------
// GEMM: out[M,N] = (A[M,K] . Bt[N,K]^T + bias[N]) * scale
// mode: 0 = f32 out, 1 = bf16 out, 2 = flag ? bf16 : f32
// ---------------------------------------------------------------------------
struct GArg {
    const unsigned short* A;
    const unsigned short* Bt;
    const float* bias;
    void* out;
    float scale;
    int mode;
};

__global__ __launch_bounds__(256) void gemm_bt(GArg g0, GArg g1, GArg g2,
                                               const int* __restrict__ flag,
                                               int M, int N, int K)
{
    GArg ga = (blockIdx.z == 0) ? g0 : ((blockIdx.z == 1) ? g1 : g2);
    const int m0 = blockIdx.y * 128;
    const int n0 = blockIdx.x * 128;
    __shared__ __align__(16) unsigned short As[128 * 32];
    __shared__ __align__(16) unsigned short Bs[128 * 32];
    const int t = threadIdx.x;
    const int w = t >> 6, l = t & 63;
    const int wy = w >> 1, wx = w & 1;
    const int lr = l >> 2;
    const int lk = (l & 3) * 8;
    const int ln = l & 15;
    const int lq = l >> 4;

    f32x4 acc[4][4] = {};

    const unsigned short* Ab0 = ga.A  + (size_t)(m0 + w * 32 +      lr) * K + lk;
    const unsigned short* Ab1 = ga.A  + (size_t)(m0 + w * 32 + 16 + lr) * K + lk;
    const unsigned short* Bb0 = ga.Bt + (size_t)(n0 + w * 32 +      lr) * K + lk;
    const unsigned short* Bb1 = ga.Bt + (size_t)(n0 + w * 32 + 16 + lr) * K + lk;
    unsigned short* Al0 = &As[w * 1024];
    unsigned short* Al1 = &As[w * 1024 + 512];
    unsigned short* Bl0 = &Bs[w * 1024];
    unsigned short* Bl1 = &Bs[w * 1024 + 512];

    for (int kk = 0; kk < K; kk += 32) {
        async_ld16(Ab0 + kk, Al0);
        async_ld16(Ab1 + kk, Al1);
        async_ld16(Bb0 + kk, Bl0);
        async_ld16(Bb1 + kk, Bl1);
        __syncthreads();
        short8 af[4], bfr[4];
#pragma unroll
        for (int i = 0; i < 4; ++i)
            af[i] = *(const short8*)&As[(wy * 64 + i * 16 + ln) * 32 + lq * 8];
#pragma unroll
        for (int j = 0; j < 4; ++j)
            bfr[j] = *(const short8*)&Bs[(wx * 64 + j * 16 + ln) * 32 + lq * 8];
#pragma unroll
        for (int i = 0; i < 4; ++i)
#pragma unroll
            for (int j = 0; j < 4; ++j)
                acc[i][j] = __builtin_amdgcn_mfma_f32_16x16x32_bf16(af[i], bfr[j], acc[i][j], 0, 0, 0);
        __syncthreads();
    }

    int f32o;
    if (ga.mode == 0)      f32o = 1;
    else if (ga.mode == 1) f32o = 0;
    else                   f32o = (*flag == 0);

    const float sc = ga.scale;
#pragma unroll
    for (int j = 0; j < 4; ++j) {
        int col = n0 + wx * 64 + j * 16 + ln;
        float bv = ga.bias[col];
#pragma unroll
        for (int i = 0; i < 4; ++i) {
            int row0 = m0 + wy * 64 + i * 16 + lq * 4;
#pragma unroll
            for (int r = 0; r < 4; ++r) {
                float v = (acc[i][j][r] + bv) * sc;
                size_t idx = (size_t)(row0 + r) * N + col;
                if (f32o) ((float*)ga.out)[idx] = v;
                else      ((unsigned short*)ga.out)[idx] = f2b(v);
            }
        }
    }
}

// ---------------------------------------------------------------------------
// down[bh,c,s] = 0.125 * sum_d q_down[c,h*64+d] * k_d[s,b,h*64+d]; chunk max
// ---------------------------------------------------------------------------
__global__ __launch_bounds__(256) void k_down(const unsigned short* __restrict__ kd,
                                              const unsigned short* __restrict__ qdw,
                                              float* __restrict__ wbuf,
                                              float* __restrict__ cmax)
{
    const int bh = blockIdx.x;
    const int b = bh >> 4, h = bh & 15;
    const int chunk = blockIdx.y;
    const int s0 = chunk * TSD;
    const int t = threadIdx.x;

    __shared__ float qd[CC * DH];
    __shared__ float kt[TSD * DH];
    __shared__ float pm[CC * 8];

    for (int idx = t; idx < CC * DH; idx += 256)
        qd[idx] = b2f(qdw[(idx >> 6) * DM + h * DH + (idx & 63)]);
    for (int u = t; u < TSD * DH / 8; u += 256) {
        int sl = u >> 3, d8 = (u & 7) * 8;
        short8 v = *(const short8*)&kd[(size_t)((s0 + sl) * BATCH + b) * DM + h * DH + d8];
#pragma unroll
        for (int j = 0; j < 8; ++j) kt[sl * DH + d8 + j] = b2f((unsigned short)v[j]);
    }
    __syncthreads();

    const int c = t & 31;
    float lmax = -3.4e38f;
    for (int idx = t; idx < CC * TSD; idx += 256) {
        int sl = idx >> 5;
        float s = 0.f;
#pragma unroll
        for (int d = 0; d < DH; d += 4) {
            float4 qa = *(const float4*)&qd[c * DH + d];
            float4 kb = *(const float4*)&kt[sl * DH + d];
            s += qa.x * kb.x + qa.y * kb.y + qa.z * kb.z + qa.w * kb.w;
        }
        s *= 0.125f;
        wbuf[((size_t)bh * CC + c) * S_LEN + s0 + sl] = s;
        lmax = fmaxf(lmax, s);
    }
    pm[c * 8 + (t >> 5)] = lmax;
    __syncthreads();
    if (t < CC) {
        float m = pm[t * 8];
#pragma unroll
        for (int g = 1; g < 8; ++g) m = fmaxf(m, pm[t * 8 + g]);
        cmax[((size_t)bh * CC + t) * NCHD + chunk] = m;
    }
}

// ---------------------------------------------------------------------------
// k_wsum: per (bh, seg of 128): segsum[bh,c,seg] = sum_{s in seg} exp(down-gmax)
// ---------------------------------------------------------------------------
__global__ __launch_bounds__(256) void k_wsum(const float* __restrict__ wbuf,
                                              const float* __restrict__ cmax,
                                              float* __restrict__ segsum)
{
    const int bh = blockIdx.x, seg = blockIdx.y;
    const int t = threadIdx.x;
    __shared__ float gm[CC];
    if (t < CC) {
        float m = cmax[(size_t)(bh * CC + t) * NCHD];
#pragma unroll
        for (int g = 1; g < NCHD; ++g) m = fmaxf(m, cmax[(size_t)(bh * CC + t) * NCHD + g]);
        gm[t] = m;
    }
    __syncthreads();
    const int c = t >> 3, sub = t & 7;
    const float gmc = gm[c];
    const size_t base = (size_t)bh * 32768 + c * 1024 + seg * 128 + sub * 16;
    float s = 0.f;
#pragma unroll
    for (int i = 0; i < 16; ++i) s += __expf(wbuf[base + i] - gmc);
    s += __shfl_xor(s, 1);
    s += __shfl_xor(s, 2);
    s += __shfl_xor(s, 4);
    if (sub == 0) segsum[(size_t)(bh * CC + c) * 8 + seg] = s;
}

// ---------------------------------------------------------------------------
// k_wapply: w -> wb[bh][c][s], wT[bh][s][c], invn[bh][s][c] = 1/cumsum
// ---------------------------------------------------------------------------
__global__ __launch_bounds__(256) void k_wapply(const float* __restrict__ wbuf,
                                                const float* __restrict__ cmax,
                                                const float* __restrict__ segsum,
                                                unsigned short* __restrict__ wb,
                                                unsigned short* __restrict__ wT,
                                                float* __restrict__ invn)
{
    const int bh = blockIdx.x, seg = blockIdx.y;
    const int t = threadIdx.x;
    __shared__ float gm[CC];
    __shared__ float basep[CC];
    __shared__ float psum[CC][9];
    __shared__ unsigned short wTt[128 * 40];
    __shared__ float invt[128 * 36];

    if (t < CC) {
        float m = cmax[(size_t)(bh * CC + t) * NCHD];
#pragma unroll
        for (int g = 1; g < NCHD; ++g) m = fmaxf(m, cmax[(size_t)(bh * CC + t) * NCHD + g]);
        gm[t] = m;
        float bsum = 0.f;
        for (int k = 0; k < seg; ++k) bsum += segsum[(size_t)(bh * CC + t) * 8 + k];
        basep[t] = bsum;
    }
    __syncthreads();

    const int c = t >> 3, sub = t & 7;
    const float gmc = gm[c];
    const size_t rbase = (size_t)bh * 32768 + c * 1024 + seg * 128 + sub * 16;
    float w16[16];
    float s = 0.f;
#pragma unroll
    for (int i = 0; i < 16; ++i) {
        float v = __expf(wbuf[rbase + i] - gmc);
        w16[i] = v; s += v;
    }
    psum[c][sub] = s;
    short8 o0, o1;
#pragma unroll
    for (int i = 0; i < 8; ++i) { o0[i] = f2b(w16[i]); o1[i] = f2b(w16[8 + i]); }
    *(short8*)&wb[rbase] = o0;
    *(short8*)&wb[rbase + 8] = o1;
#pragma unroll
    for (int i = 0; i < 16; ++i) wTt[(sub * 16 + i) * 40 + c] = f2b(w16[i]);
    __syncthreads();

    float run = basep[c];
    for (int k = 0; k < sub; ++k) run += psum[c][k];
#pragma unroll
    for (int i = 0; i < 16; ++i) {
        run += w16[i];
        invt[(sub * 16 + i) * 36 + c] = 1.0f / fmaxf(run, 1e-30f);
    }
    __syncthreads();

    for (int u = t; u < 128 * 4; u += 256) {
        int r = u >> 2, cb = (u & 3) * 8;
        *(short8*)&wT[(size_t)bh * 32768 + (seg * 128 + r) * 32 + cb] =
            *(const short8*)&wTt[r * 40 + cb];
    }
    for (int u = t; u < 128 * 8; u += 256) {
        int r = u >> 3, cb = (u & 7) * 4;
        *(float4*)&invn[(size_t)bh * 32768 + (seg * 128 + r) * 32 + cb] =
            *(const float4*)&invt[r * 36 + cb];
    }
}

// ---------------------------------------------------------------------------
// k_vt: transpose v_dv bf16 [s][b][dm] -> vT bf16 [bh][d][s]
// ---------------------------------------------------------------------------
__global__ __launch_bounds__(256) void k_vt(const unsigned short* __restrict__ vdv,
                                            unsigned short* __restrict__ vT)
{
    const int bh = blockIdx.x, b = bh >> 4, h = bh & 15;
    const int s0 = blockIdx.y * 128;
    const int t = threadIdx.x;
    __shared__ unsigned short T[128 * 68];
    for (int u = t; u < 128 * 8; u += 256) {
        int r = u >> 3, cb = (u & 7) * 8;
        *(short8*)&T[r * 68 + cb] =
            *(const short8*)&vdv[(size_t)(s0 + r) * 2048 + b * 1024 + h * 64 + cb];
    }
    __syncthreads();
    for (int u = t; u < 64 * 16; u += 256) {
        int d = u >> 4, s8 = (u & 15) * 8;
        short8 o;
#pragma unroll
        for (int k = 0; k < 8; ++k) o[k] = T[(s8 + k) * 68 + d];
        *(short8*)&vT[(size_t)bh * 65536 + d * 1024 + s0 + s8] = o;
    }
}

// ---------------------------------------------------------------------------
// k_att: fused pass1+pass2 per (bh, q-tile of 64 rows). Grid 32 x 16 = 512
// blocks, LDS ~44 KB -> 3 blocks/CU co-resident + HW tail balancing.
// pass1: G = q_u @ v_dk^T (causal), up += G @ w^T, softmax -> ptil (LDS)
// pass2: SC = ptil @ wT^T (causal), out += SC @ v_dv -> attout
// ---------------------------------------------------------------------------
__global__ __launch_bounds__(256) void k_att(
    const unsigned short* __restrict__ qu,
    const unsigned short* __restrict__ vdk,
    const unsigned short* __restrict__ wb,
    const float* __restrict__ invn,
    const unsigned short* __restrict__ wT,
    const unsigned short* __restrict__ vT,
    unsigned short* __restrict__ attout)
{
    const int bh = blockIdx.x, b = bh >> 4, h = bh & 15;
    const int qi = (int)gridDim.y - 1 - (int)blockIdx.y;  // heavy blocks first
    const int s0 = qi * 64;
    const int nkt = qi / 2 + 1;     // causal k-tile count (128-wide k-tiles)
    const int t = threadIdx.x;
    const int w = t >> 6, l = t & 63;
    const int wy = w >> 1, wx = w & 1;
    const int ln = l & 15, lq = l >> 4;

    __shared__ __align__(16) unsigned short bufA[64 * 136];   // 17 KB (G/ptil/SC)
    __shared__ __align__(16) unsigned short bufB[13824];      // 27 KB
    unsigned short* Kt  = bufB;           // pass1: 128*72 = 9216
    unsigned short* Wt  = bufB + 9216;    // pass1: 32*136 = 4352
    unsigned short* WTt = bufB;           // pass2: 128*40 = 5120
    unsigned short* Vt  = bufB + 5120;    // pass2: 64*136 = 8704

    // ---- pass 1 ----
    // stage q tile (64 x 64) into bufA
    for (int u = t; u < 64 * 8; u += 256) {
        int r = u >> 3, cb = (u & 7) * 8;
        *(short8*)&bufA[r * 136 + cb] =
            *(const short8*)&qu[(size_t)(s0 + r) * 2048 + b * 1024 + h * 64 + cb];
    }
    __syncthreads();
    short8 af[2][2];
#pragma unroll
    for (int i = 0; i < 2; ++i)
#pragma unroll
        for (int ks = 0; ks < 2; ++ks)
            af[i][ks] = *(const short8*)&bufA[(wy * 32 + i * 16 + ln) * 136 + ks * 32 + lq * 8];

    f32x4 accU[2] = {};

    for (int kt = 0; kt < nkt; ++kt) {
        const int sp0 = kt * 128;
        __syncthreads();  // A: prior phase's bufA/bufB reads done
        for (int u = t; u < 128 * 8; u += 256) {
            int r = u >> 3, cb = (u & 7) * 8;
            *(short8*)&Kt[r * 72 + cb] =
                *(const short8*)&vdk[(size_t)(sp0 + r) * 2048 + b * 1024 + h * 64 + cb];
        }
        for (int u = t; u < 32 * 16; u += 256) {
            int r = u >> 4, cb = (u & 15) * 8;
            *(short8*)&Wt[r * 136 + cb] =
                *(const short8*)&wb[(size_t)bh * 32768 + r * 1024 + sp0 + cb];
        }
        __syncthreads();  // B
        f32x4 accG[2][4] = {};
#pragma unroll
        for (int ks = 0; ks < 2; ++ks) {
            short8 bf[4];
#pragma unroll
            for (int j = 0; j < 4; ++j)
                bf[j] = *(const short8*)&Kt[(wx * 64 + j * 16 + ln) * 72 + ks * 32 + lq * 8];
#pragma unroll
            for (int i = 0; i < 2; ++i)
#pragma unroll
                for (int j = 0; j < 4; ++j)
                    accG[i][j] = __builtin_amdgcn_mfma_f32_16x16x32_bf16(af[i][ks], bf[j], accG[i][j], 0, 0, 0);
        }
        const bool diag = (kt == nkt - 1);
#pragma unroll
        for (int i = 0; i < 2; ++i) {
            int row = wy * 32 + i * 16 + lq * 4;
#pragma unroll
            for (int j = 0; j < 4; ++j) {
                int col = wx * 64 + j * 16 + ln;
#pragma unroll
                for (int r = 0; r < 4; ++r) {
                    float v = accG[i][j][r];
                    if (diag && sp0 + col > s0 + row + r) v = 0.f;
                    bufA[(row + r) * 136 + col] = f2b(v);
                }
            }
        }
        __syncthreads();  // C
        // up += G @ w^T : out 64x32, wave w owns rows w*16..+16
#pragma unroll
        for (int ks = 0; ks < 4; ++ks) {
            short8 ga = *(const short8*)&bufA[(w * 16 + ln) * 136 + ks * 32 + lq * 8];
            short8 wf[2];
#pragma unroll
            for (int v = 0; v < 2; ++v)
                wf[v] = *(const short8*)&Wt[(v * 16 + ln) * 136 + ks * 32 + lq * 8];
#pragma unroll
            for (int v = 0; v < 2; ++v)
                accU[v] = __builtin_amdgcn_mfma_f32_16x16x32_bf16(ga, wf[v], accU[v], 0, 0, 0);
        }
    }

    __syncthreads();  // up-GEMM reads of bufA done; reuse bufA for ptil
    // epilogue pass1: logits = up*invn, softmax over c, ptil -> bufA
    {
        int rowl = w * 16 + lq * 4;
#pragma unroll
        for (int r = 0; r < 4; ++r) {
            int srow = s0 + rowl + r;
            float inv0 = invn[(size_t)bh * 32768 + srow * 32 + ln];
            float inv1 = invn[(size_t)bh * 32768 + srow * 32 + 16 + ln];
            float l0 = accU[0][r] * inv0;
            float l1 = accU[1][r] * inv1;
            float m = fmaxf(l0, l1);
#pragma unroll
            for (int msk = 1; msk < 16; msk <<= 1) m = fmaxf(m, __shfl_xor(m, msk));
            float e0 = __expf(l0 - m), e1 = __expf(l1 - m);
            float Z = e0 + e1;
#pragma unroll
            for (int msk = 1; msk < 16; msk <<= 1) Z += __shfl_xor(Z, msk);
            float iz = 1.0f / Z;
            bufA[(rowl + r) * 136 + ln]      = f2b(e0 * iz * inv0);
            bufA[(rowl + r) * 136 + 16 + ln] = f2b(e1 * iz * inv1);
        }
    }
    __syncthreads();

    // ---- pass 2 ----
    short8 pa[2];
#pragma unroll
    for (int i = 0; i < 2; ++i)
        pa[i] = *(const short8*)&bufA[(wy * 32 + i * 16 + ln) * 136 + lq * 8];

    f32x4 accO[2][2] = {};

    for (int kt = 0; kt < nkt; ++kt) {
        const int sp0 = kt * 128;
        __syncthreads();  // A (first iter: pa reads done)
        for (int u = t; u < 128 * 4; u += 256) {
            int r = u >> 2, cb = (u & 3) * 8;
            *(short8*)&WTt[r * 40 + cb] =
                *(const short8*)&wT[(size_t)bh * 32768 + (sp0 + r) * 32 + cb];
        }
        for (int u = t; u < 64 * 16; u += 256) {
            int r = u >> 4, cb = (u & 15) * 8;
            *(short8*)&Vt[r * 136 + cb] =
                *(const short8*)&vT[(size_t)bh * 65536 + r * 1024 + sp0 + cb];
        }
        __syncthreads();  // B
        f32x4 accS[2][4] = {};
        {
            short8 bf[4];
#pragma unroll
            for (int j = 0; j < 4; ++j)
                bf[j] = *(const short8*)&WTt[(wx * 64 + j * 16 + ln) * 40 + lq * 8];
#pragma unroll
            for (int i = 0; i < 2; ++i)
#pragma unroll
                for (int j = 0; j < 4; ++j)
                    accS[i][j] = __builtin_amdgcn_mfma_f32_16x16x32_bf16(pa[i], bf[j], accS[i][j], 0, 0, 0);
        }
        const bool diag = (kt == nkt - 1);
#pragma unroll
        for (int i = 0; i < 2; ++i) {
            int row = wy * 32 + i * 16 + lq * 4;
#pragma unroll
            for (int j = 0; j < 4; ++j) {
                int col = wx * 64 + j * 16 + ln;
#pragma unroll
                for (int r = 0; r < 4; ++r) {
                    float v = accS[i][j][r];
                    if (diag && sp0 + col > s0 + row + r) v = 0.f;
                    bufA[(row + r) * 136 + col] = f2b(v);
                }
            }
        }
        __syncthreads();  // C
#pragma unroll
        for (int ks = 0; ks < 4; ++ks) {
            short8 sa[2], vb[2];
#pragma unroll
            for (int i = 0; i < 2; ++i)
                sa[i] = *(const short8*)&bufA[(wy * 32 + i * 16 + ln) * 136 + ks * 32 + lq * 8];
#pragma unroll
            for (int j = 0; j < 2; ++j)
                vb[j] = *(const short8*)&Vt[(wx * 32 + j * 16 + ln) * 136 + ks * 32 + lq * 8];
#pragma unroll
            for (int i = 0; i < 2; ++i)
#pragma unroll
                for (int j = 0; j < 2; ++j)
                    accO[i][j] = __builtin_amdgcn_mfma_f32_16x16x32_bf16(sa[i], vb[j], accO[i][j], 0, 0, 0);
        }
    }

#pragma unroll
    for (int i = 0; i < 2; ++i) {
        int rowb = s0 + wy * 32 + i * 16 + lq * 4;
#pragma unroll
        for (int j = 0; j < 2; ++j) {
            int d = wx * 32 + j * 16 + ln;
#pragma unroll
            for (int r = 0; r < 4; ++r)
                attout[(size_t)(rowb + r) * 2048 + b * 1024 + h * 64 + d] = f2b(accO[i][j][r]);
        }
    }
}

// ---------------------------------------------------------------------------
extern "C" void kernel_launch(void* const* d_in, const int* in_sizes, int n_in,
                              void* d_out, int out_size, void* d_ws, size_t ws_size,
                              hipStream_t stream)
{
    (void)in_sizes; (void)n_in; (void)out_size; (void)ws_size;
    char* ws = (char*)d_ws;
    const size_t MB = (size_t)1 << 20;
    const size_t KB = (size_t)1 << 10;
    unsigned short* v_d    = (unsigned short*)(ws + 0 * MB);   // 4 MB
    unsigned short* attout = (unsigned short*)(ws + 4 * MB);   // 4 MB
    unsigned short* q_u    = (unsigned short*)(ws + 8 * MB);   // 4 MB (pre-scaled)
    unsigned short* k_d    = (unsigned short*)(ws + 12 * MB);  // 4 MB
    unsigned short* v_dk   = (unsigned short*)(ws + 16 * MB);  // 4 MB
    unsigned short* v_dv   = (unsigned short*)(ws + 20 * MB);  // 4 MB
    float* wbuf = (float*)(ws + 24 * MB);                      // 4 MB (down scores)
    unsigned short* wb  = (unsigned short*)(ws + 28 * MB);     // 2 MB [bh][c][s]
    unsigned short* wT  = (unsigned short*)(ws + 30 * MB);     // 2 MB [bh][s][c]
    float* invn = (float*)(ws + 32 * MB);                      // 4 MB [bh][s][c]
    unsigned short* vT  = (unsigned short*)(ws + 36 * MB);     // 4 MB [bh][d][s]
    unsigned short* xb  = (unsigned short*)(ws + 40 * MB);     // 4 MB
    unsigned short* Wqb = (unsigned short*)(ws + 44 * MB);     // 2 MB
    unsigned short* Wkb = (unsigned short*)(ws + 46 * MB);     // 2 MB
    unsigned short* Wvb = (unsigned short*)(ws + 48 * MB);     // 2 MB
    unsigned short* Wob = (unsigned short*)(ws + 50 * MB);     // 2 MB
    unsigned short* qdb = (unsigned short*)(ws + 52 * MB);     // 64 KB
    float* biasf  = (float*)(ws + 52 * MB + 64 * KB);          // 16 KB
    float* cmax   = (float*)(ws + 52 * MB + 128 * KB);         // 32 KB
    float* segsum = (float*)(ws + 52 * MB + 192 * KB);         // 32 KB
    int*   flag   = (int*)  (ws + 52 * MB + 256 * KB);

    k_sniff<<<1, 256, 0, stream>>>((const unsigned short*)d_in[0], flag);
    k_convert<<<1024, 256, 0, stream>>>(
        d_in[0], d_in[1], d_in[2], d_in[4], d_in[6], d_in[8],
        d_in[3], d_in[5], d_in[7], d_in[9],
        flag, xb, qdb, Wqb, Wkb, Wvb, Wob, biasf);

    const float* bqf = biasf;
    const float* bkf = biasf + 1024;
    const float* bvf = biasf + 2048;
    const float* bof = biasf + 3072;

    // pass 1 GEMMs: q_u (scaled), k_d, v_d — all bf16 out
    GArg gq{ xb, Wqb, bqf, (void*)q_u, 0.125f, 1 };
    GArg gk{ xb, Wkb, bkf, (void*)k_d, 1.0f, 1 };
    GArg gv{ xb, Wvb, bvf, (void*)v_d, 1.0f, 1 };
    gemm_bt<<<dim3(8, 16, 3), 256, 0, stream>>>(gq, gk, gv, flag, SB, DM, DM);

    // pass 2 GEMMs: v_d_k, v_d_v bf16
    GArg gvk{ v_d, Wkb, bkf, (void*)v_dk, 1.0f, 1 };
    GArg gvv{ v_d, Wvb, bvf, (void*)v_dv, 1.0f, 1 };
    gemm_bt<<<dim3(8, 16, 2), 256, 0, stream>>>(gvk, gvv, gvk, flag, SB, DM, DM);

    // attention mid-section
    k_down<<<dim3(32, NCHD), 256, 0, stream>>>(k_d, qdb, wbuf, cmax);
    k_wsum<<<dim3(32, 8), 256, 0, stream>>>(wbuf, cmax, segsum);
    k_wapply<<<dim3(32, 8), 256, 0, stream>>>(wbuf, cmax, segsum, wb, wT, invn);
    k_vt<<<dim3(32, 8), 256, 0, stream>>>(v_dv, vT);
    k_att<<<dim3(32, 16), 256, 0, stream>>>(q_u, v_dk, wb, invn, wT, vT, attout);

    // final projection: out dtype follows sniffed input dtype
    GArg go{ attout, Wob, bof, d_out, 1.0f, 2 };
    gemm_bt<<<dim3(8, 16, 1), 256, 0, stream>>>(go, go, go, flag, SB, DM, DM);
}

// Round 6
// 216.850 us; speedup vs baseline: 1.3930x; 1.1099x over previous
//
#include <hip/hip_runtime.h>
#include <cstdint>
#include <cstddef>

// Problem constants
#define S_LEN 1024
#define BATCH 2
#define DM    1024
#define NH    16
#define DH    64
#define CC    32     // compressed length
#define SB    2048   // S*B rows
#define TSD   128
#define NCHD  8

using short8 = __attribute__((ext_vector_type(8))) short;
using f32x4  = __attribute__((ext_vector_type(4))) float;

__device__ __forceinline__ float b2f(unsigned short u) {
    union { unsigned int i; float f; } v; v.i = ((unsigned int)u) << 16; return v.f;
}
__device__ __forceinline__ unsigned short f2b(float f) {
    union { float f; unsigned int i; } v; v.f = f;
    unsigned int x = v.i;
    unsigned int r = x + 0x7FFFu + ((x >> 16) & 1u);
    return (unsigned short)(r >> 16);
}

__device__ __forceinline__ void async_ld16(const unsigned short* g, unsigned short* l) {
    __builtin_amdgcn_global_load_lds(
        (const __attribute__((address_space(1))) unsigned int*)g,
        (__attribute__((address_space(3))) unsigned int*)l,
        16, 0, 0);
}

// ---------------------------------------------------------------------------
// dtype sniffer: flag=1 -> inputs bf16; flag=0 -> inputs fp32.
// ---------------------------------------------------------------------------
__global__ void k_sniff(const unsigned short* x, int* flag) {
    __shared__ int cnt;
    if (threadIdx.x == 0) cnt = 0;
    __syncthreads();
    int local = 0;
    for (int i = threadIdx.x; i < 1024; i += 256) {
        unsigned e = (x[i * 2] >> 7) & 0xFF;
        if (e >= 90 && e <= 160) local++;
    }
    atomicAdd(&cnt, local);
    __syncthreads();
    if (threadIdx.x == 0) *flag = (cnt >= 640) ? 1 : 0;
}

// ---------------------------------------------------------------------------
// normalize inputs: x, q_down, W* -> bf16; biases -> f32 (vectorized)
// ---------------------------------------------------------------------------
__global__ __launch_bounds__(256) void k_convert(
    const void* x, const void* qd,
    const void* wq, const void* wk, const void* wv, const void* wo,
    const void* bq, const void* bk, const void* bv, const void* bo,
    const int* __restrict__ flag,
    unsigned short* xb, unsigned short* qdb,
    unsigned short* Wqb, unsigned short* Wkb, unsigned short* Wvb, unsigned short* Wob,
    float* biasf)
{
    const int isbf = *flag;
    const size_t tid = (size_t)blockIdx.x * 256 + threadIdx.x;
    const size_t stride = (size_t)gridDim.x * 256;

    auto cv = [&](const void* src, unsigned short* dst, size_t n) {
        if (isbf) {
            const short8* s = (const short8*)src;
            short8* d = (short8*)dst;
            for (size_t i = tid; i < n / 8; i += stride) d[i] = s[i];
        } else {
            const float4* s = (const float4*)src;
            for (size_t i = tid; i < n / 4; i += stride) {
                float4 v = s[i];
                ushort4 o;
                o.x = f2b(v.x); o.y = f2b(v.y); o.z = f2b(v.z); o.w = f2b(v.w);
                ((ushort4*)dst)[i] = o;
            }
        }
    };
    cv(x,  xb,  (size_t)SB * DM);
    cv(qd, qdb, (size_t)CC * DM);
    cv(wq, Wqb, (size_t)DM * DM);
    cv(wk, Wkb, (size_t)DM * DM);
    cv(wv, Wvb, (size_t)DM * DM);
    cv(wo, Wob, (size_t)DM * DM);
    for (size_t i = tid; i < 4 * DM; i += stride) {
        int w = (int)(i >> 10), o = (int)(i & 1023);
        const void* bp = (w == 0) ? bq : ((w == 1) ? bk : ((w == 2) ? bv : bo));
        biasf[i] = isbf ? b2f(((const unsigned short*)bp)[o]) : ((const float*)bp)[o];
    }
}

// ---------------------------------------------------------------------------
// GEMM: out[M,N] = (A[M,K] . Bt[N,K]^T + bias[N]) * scale
// mode: 0 = f32 out, 1 = bf16 out, 2 = flag ? bf16 : f32
// ---------------------------------------------------------------------------
struct GArg {
    const unsigned short* A;
    const unsigned short* Bt;
    const float* bias;
    void* out;
    float scale;
    int mode;
};

__global__ __launch_bounds__(256) void gemm_bt(GArg g0, GArg g1, GArg g2,
                                               const int* __restrict__ flag,
                                               int M, int N, int K)
{
    GArg ga = (blockIdx.z == 0) ? g0 : ((blockIdx.z == 1) ? g1 : g2);
    const int m0 = blockIdx.y * 128;
    const int n0 = blockIdx.x * 128;
    __shared__ __align__(16) unsigned short As[128 * 32];
    __shared__ __align__(16) unsigned short Bs[128 * 32];
    const int t = threadIdx.x;
    const int w = t >> 6, l = t & 63;
    const int wy = w >> 1, wx = w & 1;
    const int lr = l >> 2;
    const int lk = (l & 3) * 8;
    const int ln = l & 15;
    const int lq = l >> 4;

    f32x4 acc[4][4] = {};

    const unsigned short* Ab0 = ga.A  + (size_t)(m0 + w * 32 +      lr) * K + lk;
    const unsigned short* Ab1 = ga.A  + (size_t)(m0 + w * 32 + 16 + lr) * K + lk;
    const unsigned short* Bb0 = ga.Bt + (size_t)(n0 + w * 32 +      lr) * K + lk;
    const unsigned short* Bb1 = ga.Bt + (size_t)(n0 + w * 32 + 16 + lr) * K + lk;
    unsigned short* Al0 = &As[w * 1024];
    unsigned short* Al1 = &As[w * 1024 + 512];
    unsigned short* Bl0 = &Bs[w * 1024];
    unsigned short* Bl1 = &Bs[w * 1024 + 512];

    for (int kk = 0; kk < K; kk += 32) {
        async_ld16(Ab0 + kk, Al0);
        async_ld16(Ab1 + kk, Al1);
        async_ld16(Bb0 + kk, Bl0);
        async_ld16(Bb1 + kk, Bl1);
        __syncthreads();
        short8 af[4], bfr[4];
#pragma unroll
        for (int i = 0; i < 4; ++i)
            af[i] = *(const short8*)&As[(wy * 64 + i * 16 + ln) * 32 + lq * 8];
#pragma unroll
        for (int j = 0; j < 4; ++j)
            bfr[j] = *(const short8*)&Bs[(wx * 64 + j * 16 + ln) * 32 + lq * 8];
#pragma unroll
        for (int i = 0; i < 4; ++i)
#pragma unroll
            for (int j = 0; j < 4; ++j)
                acc[i][j] = __builtin_amdgcn_mfma_f32_16x16x32_bf16(af[i], bfr[j], acc[i][j], 0, 0, 0);
        __syncthreads();
    }

    int f32o;
    if (ga.mode == 0)      f32o = 1;
    else if (ga.mode == 1) f32o = 0;
    else                   f32o = (*flag == 0);

    const float sc = ga.scale;
#pragma unroll
    for (int j = 0; j < 4; ++j) {
        int col = n0 + wx * 64 + j * 16 + ln;
        float bv = ga.bias[col];
#pragma unroll
        for (int i = 0; i < 4; ++i) {
            int row0 = m0 + wy * 64 + i * 16 + lq * 4;
#pragma unroll
            for (int r = 0; r < 4; ++r) {
                float v = (acc[i][j][r] + bv) * sc;
                size_t idx = (size_t)(row0 + r) * N + col;
                if (f32o) ((float*)ga.out)[idx] = v;
                else      ((unsigned short*)ga.out)[idx] = f2b(v);
            }
        }
    }
}

// ---------------------------------------------------------------------------
// down[bh,c,s] = 0.125 * sum_d q_down[c,h*64+d] * k_d[s,b,h*64+d]; chunk max
// ---------------------------------------------------------------------------
__global__ __launch_bounds__(256) void k_down(const unsigned short* __restrict__ kd,
                                              const unsigned short* __restrict__ qdw,
                                              float* __restrict__ wbuf,
                                              float* __restrict__ cmax)
{
    const int bh = blockIdx.x;
    const int b = bh >> 4, h = bh & 15;
    const int chunk = blockIdx.y;
    const int s0 = chunk * TSD;
    const int t = threadIdx.x;

    __shared__ float qd[CC * DH];
    __shared__ float kt[TSD * DH];
    __shared__ float pm[CC * 8];

    for (int idx = t; idx < CC * DH; idx += 256)
        qd[idx] = b2f(qdw[(idx >> 6) * DM + h * DH + (idx & 63)]);
    for (int u = t; u < TSD * DH / 8; u += 256) {
        int sl = u >> 3, d8 = (u & 7) * 8;
        short8 v = *(const short8*)&kd[(size_t)((s0 + sl) * BATCH + b) * DM + h * DH + d8];
#pragma unroll
        for (int j = 0; j < 8; ++j) kt[sl * DH + d8 + j] = b2f((unsigned short)v[j]);
    }
    __syncthreads();

    const int c = t & 31;
    float lmax = -3.4e38f;
    for (int idx = t; idx < CC * TSD; idx += 256) {
        int sl = idx >> 5;
        float s = 0.f;
#pragma unroll
        for (int d = 0; d < DH; d += 4) {
            float4 qa = *(const float4*)&qd[c * DH + d];
            float4 kb = *(const float4*)&kt[sl * DH + d];
            s += qa.x * kb.x + qa.y * kb.y + qa.z * kb.z + qa.w * kb.w;
        }
        s *= 0.125f;
        wbuf[((size_t)bh * CC + c) * S_LEN + s0 + sl] = s;
        lmax = fmaxf(lmax, s);
    }
    pm[c * 8 + (t >> 5)] = lmax;
    __syncthreads();
    if (t < CC) {
        float m = pm[t * 8];
#pragma unroll
        for (int g = 1; g < 8; ++g) m = fmaxf(m, pm[t * 8 + g]);
        cmax[((size_t)bh * CC + t) * NCHD + chunk] = m;
    }
}

// ---------------------------------------------------------------------------
// k_wsum: per (bh, seg of 128): segsum[bh,c,seg] = sum_{s in seg} exp(down-gmax)
// ---------------------------------------------------------------------------
__global__ __launch_bounds__(256) void k_wsum(const float* __restrict__ wbuf,
                                              const float* __restrict__ cmax,
                                              float* __restrict__ segsum)
{
    const int bh = blockIdx.x, seg = blockIdx.y;
    const int t = threadIdx.x;
    __shared__ float gm[CC];
    if (t < CC) {
        float m = cmax[(size_t)(bh * CC + t) * NCHD];
#pragma unroll
        for (int g = 1; g < NCHD; ++g) m = fmaxf(m, cmax[(size_t)(bh * CC + t) * NCHD + g]);
        gm[t] = m;
    }
    __syncthreads();
    const int c = t >> 3, sub = t & 7;
    const float gmc = gm[c];
    const size_t base = (size_t)bh * 32768 + c * 1024 + seg * 128 + sub * 16;
    float s = 0.f;
#pragma unroll
    for (int i = 0; i < 16; ++i) s += __expf(wbuf[base + i] - gmc);
    s += __shfl_xor(s, 1);
    s += __shfl_xor(s, 2);
    s += __shfl_xor(s, 4);
    if (sub == 0) segsum[(size_t)(bh * CC + c) * 8 + seg] = s;
}

// ---------------------------------------------------------------------------
// k_wapply: w -> wb[bh][c][s], wT[bh][s][c], invn[bh][s][c] = 1/cumsum
// ---------------------------------------------------------------------------
__global__ __launch_bounds__(256) void k_wapply(const float* __restrict__ wbuf,
                                                const float* __restrict__ cmax,
                                                const float* __restrict__ segsum,
                                                unsigned short* __restrict__ wb,
                                                unsigned short* __restrict__ wT,
                                                float* __restrict__ invn)
{
    const int bh = blockIdx.x, seg = blockIdx.y;
    const int t = threadIdx.x;
    __shared__ float gm[CC];
    __shared__ float basep[CC];
    __shared__ float psum[CC][9];
    __shared__ unsigned short wTt[128 * 40];
    __shared__ float invt[128 * 36];

    if (t < CC) {
        float m = cmax[(size_t)(bh * CC + t) * NCHD];
#pragma unroll
        for (int g = 1; g < NCHD; ++g) m = fmaxf(m, cmax[(size_t)(bh * CC + t) * NCHD + g]);
        gm[t] = m;
        float bsum = 0.f;
        for (int k = 0; k < seg; ++k) bsum += segsum[(size_t)(bh * CC + t) * 8 + k];
        basep[t] = bsum;
    }
    __syncthreads();

    const int c = t >> 3, sub = t & 7;
    const float gmc = gm[c];
    const size_t rbase = (size_t)bh * 32768 + c * 1024 + seg * 128 + sub * 16;
    float w16[16];
    float s = 0.f;
#pragma unroll
    for (int i = 0; i < 16; ++i) {
        float v = __expf(wbuf[rbase + i] - gmc);
        w16[i] = v; s += v;
    }
    psum[c][sub] = s;
    short8 o0, o1;
#pragma unroll
    for (int i = 0; i < 8; ++i) { o0[i] = f2b(w16[i]); o1[i] = f2b(w16[8 + i]); }
    *(short8*)&wb[rbase] = o0;
    *(short8*)&wb[rbase + 8] = o1;
#pragma unroll
    for (int i = 0; i < 16; ++i) wTt[(sub * 16 + i) * 40 + c] = f2b(w16[i]);
    __syncthreads();

    float run = basep[c];
    for (int k = 0; k < sub; ++k) run += psum[c][k];
#pragma unroll
    for (int i = 0; i < 16; ++i) {
        run += w16[i];
        invt[(sub * 16 + i) * 36 + c] = 1.0f / fmaxf(run, 1e-30f);
    }
    __syncthreads();

    for (int u = t; u < 128 * 4; u += 256) {
        int r = u >> 2, cb = (u & 3) * 8;
        *(short8*)&wT[(size_t)bh * 32768 + (seg * 128 + r) * 32 + cb] =
            *(const short8*)&wTt[r * 40 + cb];
    }
    for (int u = t; u < 128 * 8; u += 256) {
        int r = u >> 3, cb = (u & 7) * 4;
        *(float4*)&invn[(size_t)bh * 32768 + (seg * 128 + r) * 32 + cb] =
            *(const float4*)&invt[r * 36 + cb];
    }
}

// ---------------------------------------------------------------------------
// k_vt: transpose [s][b][dm] -> [bh][d][s] for v_dk (z=0) and v_dv (z=1)
// ---------------------------------------------------------------------------
__global__ __launch_bounds__(256) void k_vt(const unsigned short* __restrict__ vdk,
                                            const unsigned short* __restrict__ vdv,
                                            unsigned short* __restrict__ vTk,
                                            unsigned short* __restrict__ vTv)
{
    const unsigned short* src = blockIdx.z ? vdv : vdk;
    unsigned short* dst = blockIdx.z ? vTv : vTk;
    const int bh = blockIdx.x, b = bh >> 4, h = bh & 15;
    const int s0 = blockIdx.y * 128;
    const int t = threadIdx.x;
    __shared__ unsigned short T[128 * 68];
    for (int u = t; u < 128 * 8; u += 256) {
        int r = u >> 3, cb = (u & 7) * 8;
        *(short8*)&T[r * 68 + cb] =
            *(const short8*)&src[(size_t)(s0 + r) * 2048 + b * 1024 + h * 64 + cb];
    }
    __syncthreads();
    for (int u = t; u < 64 * 16; u += 256) {
        int d = u >> 4, s8 = (u & 15) * 8;
        short8 o;
#pragma unroll
        for (int k = 0; k < 8; ++k) o[k] = T[(s8 + k) * 68 + d];
        *(short8*)&dst[(size_t)bh * 65536 + d * 1024 + s0 + s8] = o;
    }
}

// ---------------------------------------------------------------------------
// k_state: per (bh, chunk of 64): M[c,d] = sum_s' w[c,s']*v_dk[s',d] (f32)
//                                 NT[d,c] = sum_s' v_dv[s',d]*w[c,s'] (f32)
// ---------------------------------------------------------------------------
__global__ __launch_bounds__(256) void k_state(const unsigned short* __restrict__ wb,
                                               const unsigned short* __restrict__ vTk,
                                               const unsigned short* __restrict__ vTv,
                                               float* __restrict__ Mst,
                                               float* __restrict__ NTst)
{
    const int bh = blockIdx.x, ch = blockIdx.y;
    const int s0 = ch * 64;
    const int t = threadIdx.x;
    const int w = t >> 6, l = t & 63;
    const int ln = l & 15, lq = l >> 4;
    __shared__ __align__(16) unsigned short Ws[32 * 72];
    __shared__ __align__(16) unsigned short KT[64 * 72];
    __shared__ __align__(16) unsigned short VT[64 * 72];

    for (int u = t; u < 32 * 8; u += 256) {
        int r = u >> 3, cb = (u & 7) * 8;
        *(short8*)&Ws[r * 72 + cb] = *(const short8*)&wb[(size_t)bh * 32768 + r * 1024 + s0 + cb];
    }
    for (int u = t; u < 64 * 8; u += 256) {
        int r = u >> 3, cb = (u & 7) * 8;
        *(short8*)&KT[r * 72 + cb] = *(const short8*)&vTk[(size_t)bh * 65536 + r * 1024 + s0 + cb];
        *(short8*)&VT[r * 72 + cb] = *(const short8*)&vTv[(size_t)bh * 65536 + r * 1024 + s0 + cb];
    }
    __syncthreads();

    // M: wave w owns d-cols w*16..+16, both c row-tiles
    f32x4 accM[2] = {};
#pragma unroll
    for (int ks = 0; ks < 2; ++ks) {
        short8 b8 = *(const short8*)&KT[(w * 16 + ln) * 72 + ks * 32 + lq * 8];
#pragma unroll
        for (int i = 0; i < 2; ++i) {
            short8 a8 = *(const short8*)&Ws[(i * 16 + ln) * 72 + ks * 32 + lq * 8];
            accM[i] = __builtin_amdgcn_mfma_f32_16x16x32_bf16(a8, b8, accM[i], 0, 0, 0);
        }
    }
#pragma unroll
    for (int i = 0; i < 2; ++i)
#pragma unroll
        for (int r = 0; r < 4; ++r)
            Mst[((size_t)(bh * 16 + ch) * 32 + i * 16 + lq * 4 + r) * 64 + w * 16 + ln] = accM[i][r];

    // NT: wave w owns d-rows w*16..+16, both c col-tiles
    f32x4 accN[2] = {};
#pragma unroll
    for (int ks = 0; ks < 2; ++ks) {
        short8 a8 = *(const short8*)&VT[(w * 16 + ln) * 72 + ks * 32 + lq * 8];
#pragma unroll
        for (int j = 0; j < 2; ++j) {
            short8 b8 = *(const short8*)&Ws[(j * 16 + ln) * 72 + ks * 32 + lq * 8];
            accN[j] = __builtin_amdgcn_mfma_f32_16x16x32_bf16(a8, b8, accN[j], 0, 0, 0);
        }
    }
#pragma unroll
    for (int j = 0; j < 2; ++j)
#pragma unroll
        for (int r = 0; r < 4; ++r)
            NTst[((size_t)(bh * 16 + ch) * 64 + w * 16 + lq * 4 + r) * 32 + j * 16 + ln] = accN[j][r];
}

// ---------------------------------------------------------------------------
// k_prefix: exclusive prefix over 16 chunks (f32) -> bf16 Mcum / NTcum
// ---------------------------------------------------------------------------
__global__ __launch_bounds__(256) void k_prefix(const float* __restrict__ Mst,
                                                const float* __restrict__ NTst,
                                                unsigned short* __restrict__ Mcum,
                                                unsigned short* __restrict__ NTcum)
{
    const int bh = blockIdx.x;
    const int t = threadIdx.x;
    const int e0 = t * 8;
    float run[8];
#pragma unroll
    for (int j = 0; j < 8; ++j) run[j] = 0.f;
    for (int ch = 0; ch < 16; ++ch) {
        size_t off = (size_t)(bh * 16 + ch) * 2048 + e0;
        short8 ob;
#pragma unroll
        for (int j = 0; j < 8; ++j) ob[j] = f2b(run[j]);
        *(short8*)&Mcum[off] = ob;
#pragma unroll
        for (int j = 0; j < 8; ++j) run[j] += Mst[off + j];
    }
#pragma unroll
    for (int j = 0; j < 8; ++j) run[j] = 0.f;
    for (int ch = 0; ch < 16; ++ch) {
        size_t off = (size_t)(bh * 16 + ch) * 2048 + e0;
        short8 ob;
#pragma unroll
        for (int j = 0; j < 8; ++j) ob[j] = f2b(run[j]);
        *(short8*)&NTcum[off] = ob;
#pragma unroll
        for (int j = 0; j < 8; ++j) run[j] += NTst[off + j];
    }
}

// ---------------------------------------------------------------------------
// k_att (chunked): per (bh, q-tile 64). UNIFORM work: diagonal 64x64 block
// explicit + one state GEMM against exclusive chunk prefix. 5 barriers/block.
//  P2: G = q @ k_diag^T (causal)           -> Gs
//  P3: up = G @ w_diag^T + q @ Mcum^T
//  P4: softmax(up*invn) -> ptil (reuses Qs, stride 40)
//  P5: SC = ptil @ wT_diag^T (causal)      -> Gs
//  P6: out = SC @ vT_diag^T + ptil @ NTcum^T -> attout
// ---------------------------------------------------------------------------
__global__ __launch_bounds__(256) void k_att(
    const unsigned short* __restrict__ qu,
    const unsigned short* __restrict__ vdk,
    const unsigned short* __restrict__ wb,
    const float* __restrict__ invn,
    const unsigned short* __restrict__ wT,
    const unsigned short* __restrict__ vTv,
    const unsigned short* __restrict__ Mcum,
    const unsigned short* __restrict__ NTcum,
    unsigned short* __restrict__ attout)
{
    const int bh = blockIdx.x, b = bh >> 4, h = bh & 15;
    const int qi = blockIdx.y;
    const int s0 = qi * 64;
    const int t = threadIdx.x;
    const int w = t >> 6, l = t & 63;
    const int wy = w >> 1, wx = w & 1;
    const int ln = l & 15, lq = l >> 4;

    __shared__ __align__(16) unsigned short Qs[64 * 72];   // q tile; later ptil (stride 40)
    __shared__ __align__(16) unsigned short Gs[64 * 72];   // G; later SC
    __shared__ __align__(16) unsigned short Kd[64 * 72];   // vdk diag [s'][d]
    __shared__ __align__(16) unsigned short Wd[32 * 72];   // wb diag [c][s']
    __shared__ __align__(16) unsigned short WTd[64 * 40];  // wT diag [s'][c]
    __shared__ __align__(16) unsigned short VTd[64 * 72];  // vdvT diag [d][s']
    __shared__ __align__(16) unsigned short Mc[32 * 72];   // Mcum [c][d]
    __shared__ __align__(16) unsigned short Nc[64 * 40];   // NTcum [d][c]

    // P0: stage everything
    for (int u = t; u < 64 * 8; u += 256) {
        int r = u >> 3, cb = (u & 7) * 8;
        *(short8*)&Qs[r * 72 + cb] =
            *(const short8*)&qu[(size_t)(s0 + r) * 2048 + b * 1024 + h * 64 + cb];
        *(short8*)&Kd[r * 72 + cb] =
            *(const short8*)&vdk[(size_t)(s0 + r) * 2048 + b * 1024 + h * 64 + cb];
        *(short8*)&VTd[r * 72 + cb] =
            *(const short8*)&vTv[(size_t)bh * 65536 + r * 1024 + s0 + cb];
    }
    for (int u = t; u < 32 * 8; u += 256) {
        int r = u >> 3, cb = (u & 7) * 8;
        *(short8*)&Wd[r * 72 + cb] =
            *(const short8*)&wb[(size_t)bh * 32768 + r * 1024 + s0 + cb];
        *(short8*)&Mc[r * 72 + cb] =
            *(const short8*)&Mcum[((size_t)(bh * 16 + qi) * 32 + r) * 64 + cb];
    }
    for (int u = t; u < 64 * 4; u += 256) {
        int r = u >> 2, cb = (u & 3) * 8;
        *(short8*)&WTd[r * 40 + cb] =
            *(const short8*)&wT[(size_t)bh * 32768 + (s0 + r) * 32 + cb];
        *(short8*)&Nc[r * 40 + cb] =
            *(const short8*)&NTcum[((size_t)(bh * 16 + qi) * 64 + r) * 32 + cb];
    }
    __syncthreads();

    // P2: G = q @ k_diag^T, causal mask, -> Gs (bf16)
    {
        f32x4 accG[2][2] = {};
#pragma unroll
        for (int ks = 0; ks < 2; ++ks) {
            short8 a8[2], b8[2];
#pragma unroll
            for (int i = 0; i < 2; ++i)
                a8[i] = *(const short8*)&Qs[(wy * 32 + i * 16 + ln) * 72 + ks * 32 + lq * 8];
#pragma unroll
            for (int j = 0; j < 2; ++j)
                b8[j] = *(const short8*)&Kd[(wx * 32 + j * 16 + ln) * 72 + ks * 32 + lq * 8];
#pragma unroll
            for (int i = 0; i < 2; ++i)
#pragma unroll
                for (int j = 0; j < 2; ++j)
                    accG[i][j] = __builtin_amdgcn_mfma_f32_16x16x32_bf16(a8[i], b8[j], accG[i][j], 0, 0, 0);
        }
#pragma unroll
        for (int i = 0; i < 2; ++i) {
            int row = wy * 32 + i * 16 + lq * 4;
#pragma unroll
            for (int j = 0; j < 2; ++j) {
                int col = wx * 32 + j * 16 + ln;
#pragma unroll
                for (int r = 0; r < 4; ++r) {
                    float v = accG[i][j][r];
                    if (col > row + r) v = 0.f;
                    Gs[(row + r) * 72 + col] = f2b(v);
                }
            }
        }
    }
    __syncthreads();

    // P3: up = G @ w_diag^T + q @ Mcum^T (64x32, wave w owns rows w*16..+16)
    f32x4 accU[2] = {};
#pragma unroll
    for (int ks = 0; ks < 2; ++ks) {
        short8 ga = *(const short8*)&Gs[(w * 16 + ln) * 72 + ks * 32 + lq * 8];
        short8 qa = *(const short8*)&Qs[(w * 16 + ln) * 72 + ks * 32 + lq * 8];
#pragma unroll
        for (int j = 0; j < 2; ++j) {
            short8 wf = *(const short8*)&Wd[(j * 16 + ln) * 72 + ks * 32 + lq * 8];
            short8 mf = *(const short8*)&Mc[(j * 16 + ln) * 72 + ks * 32 + lq * 8];
            accU[j] = __builtin_amdgcn_mfma_f32_16x16x32_bf16(ga, wf, accU[j], 0, 0, 0);
            accU[j] = __builtin_amdgcn_mfma_f32_16x16x32_bf16(qa, mf, accU[j], 0, 0, 0);
        }
    }
    __syncthreads();

    // P4: softmax(up*invn) -> ptil into Qs (stride 40)
    {
        int rowl = w * 16 + lq * 4;
#pragma unroll
        for (int r = 0; r < 4; ++r) {
            int srow = s0 + rowl + r;
            float inv0 = invn[(size_t)bh * 32768 + srow * 32 + ln];
            float inv1 = invn[(size_t)bh * 32768 + srow * 32 + 16 + ln];
            float l0 = accU[0][r] * inv0;
            float l1 = accU[1][r] * inv1;
            float m = fmaxf(l0, l1);
#pragma unroll
            for (int msk = 1; msk < 16; msk <<= 1) m = fmaxf(m, __shfl_xor(m, msk));
            float e0 = __expf(l0 - m), e1 = __expf(l1 - m);
            float Z = e0 + e1;
#pragma unroll
            for (int msk = 1; msk < 16; msk <<= 1) Z += __shfl_xor(Z, msk);
            float iz = 1.0f / Z;
            Qs[(rowl + r) * 40 + ln]      = f2b(e0 * iz * inv0);
            Qs[(rowl + r) * 40 + 16 + ln] = f2b(e1 * iz * inv1);
        }
    }
    __syncthreads();

    // P5: SC = ptil @ wT_diag^T (K=32), causal mask, -> Gs
    short8 pa[2];
#pragma unroll
    for (int i = 0; i < 2; ++i)
        pa[i] = *(const short8*)&Qs[(wy * 32 + i * 16 + ln) * 40 + lq * 8];
    {
        f32x4 accS[2][2] = {};
        short8 b8[2];
#pragma unroll
        for (int j = 0; j < 2; ++j)
            b8[j] = *(const short8*)&WTd[(wx * 32 + j * 16 + ln) * 40 + lq * 8];
#pragma unroll
        for (int i = 0; i < 2; ++i)
#pragma unroll
            for (int j = 0; j < 2; ++j)
                accS[i][j] = __builtin_amdgcn_mfma_f32_16x16x32_bf16(pa[i], b8[j], accS[i][j], 0, 0, 0);
#pragma unroll
        for (int i = 0; i < 2; ++i) {
            int row = wy * 32 + i * 16 + lq * 4;
#pragma unroll
            for (int j = 0; j < 2; ++j) {
                int col = wx * 32 + j * 16 + ln;
#pragma unroll
                for (int r = 0; r < 4; ++r) {
                    float v = accS[i][j][r];
                    if (col > row + r) v = 0.f;
                    Gs[(row + r) * 72 + col] = f2b(v);
                }
            }
        }
    }
    __syncthreads();

    // P6: out = SC @ vT_diag^T + ptil @ NTcum^T -> attout
    {
        f32x4 accO[2][2] = {};
        // state part (K=32): pa still in regs
        short8 n8[2];
#pragma unroll
        for (int j = 0; j < 2; ++j)
            n8[j] = *(const short8*)&Nc[(wx * 32 + j * 16 + ln) * 40 + lq * 8];
#pragma unroll
        for (int i = 0; i < 2; ++i)
#pragma unroll
            for (int j = 0; j < 2; ++j)
                accO[i][j] = __builtin_amdgcn_mfma_f32_16x16x32_bf16(pa[i], n8[j], accO[i][j], 0, 0, 0);
        // diagonal part (K=64)
#pragma unroll
        for (int ks = 0; ks < 2; ++ks) {
            short8 a8[2], b8[2];
#pragma unroll
            for (int i = 0; i < 2; ++i)
                a8[i] = *(const short8*)&Gs[(wy * 32 + i * 16 + ln) * 72 + ks * 32 + lq * 8];
#pragma unroll
            for (int j = 0; j < 2; ++j)
                b8[j] = *(const short8*)&VTd[(wx * 32 + j * 16 + ln) * 72 + ks * 32 + lq * 8];
#pragma unroll
            for (int i = 0; i < 2; ++i)
#pragma unroll
                for (int j = 0; j < 2; ++j)
                    accO[i][j] = __builtin_amdgcn_mfma_f32_16x16x32_bf16(a8[i], b8[j], accO[i][j], 0, 0, 0);
        }
#pragma unroll
        for (int i = 0; i < 2; ++i) {
            int rowb = s0 + wy * 32 + i * 16 + lq * 4;
#pragma unroll
            for (int j = 0; j < 2; ++j) {
                int d = wx * 32 + j * 16 + ln;
#pragma unroll
                for (int r = 0; r < 4; ++r)
                    attout[(size_t)(rowb + r) * 2048 + b * 1024 + h * 64 + d] = f2b(accO[i][j][r]);
            }
        }
    }
}

// ---------------------------------------------------------------------------
extern "C" void kernel_launch(void* const* d_in, const int* in_sizes, int n_in,
                              void* d_out, int out_size, void* d_ws, size_t ws_size,
                              hipStream_t stream)
{
    (void)in_sizes; (void)n_in; (void)out_size; (void)ws_size;
    char* ws = (char*)d_ws;
    const size_t MB = (size_t)1 << 20;
    const size_t KB = (size_t)1 << 10;
    unsigned short* v_d    = (unsigned short*)(ws + 0 * MB);   // 4 MB
    unsigned short* attout = (unsigned short*)(ws + 4 * MB);   // 4 MB
    unsigned short* q_u    = (unsigned short*)(ws + 8 * MB);   // 4 MB (pre-scaled)
    unsigned short* k_d    = (unsigned short*)(ws + 12 * MB);  // 4 MB
    unsigned short* v_dk   = (unsigned short*)(ws + 16 * MB);  // 4 MB
    unsigned short* v_dv   = (unsigned short*)(ws + 20 * MB);  // 4 MB
    float* wbuf = (float*)(ws + 24 * MB);                      // 4 MB (down scores)
    unsigned short* wb  = (unsigned short*)(ws + 28 * MB);     // 2 MB [bh][c][s]
    unsigned short* wT  = (unsigned short*)(ws + 30 * MB);     // 2 MB [bh][s][c]
    float* invn = (float*)(ws + 32 * MB);                      // 4 MB [bh][s][c]
    unsigned short* vTk = (unsigned short*)(ws + 36 * MB);     // 4 MB [bh][d][s]
    unsigned short* vTv = (unsigned short*)(ws + 40 * MB);     // 4 MB [bh][d][s]
    float* Mst  = (float*)(ws + 44 * MB);                      // 4 MB [bh][16][32][64]
    float* NTst = (float*)(ws + 48 * MB);                      // 4 MB [bh][16][64][32]
    unsigned short* Mcum  = (unsigned short*)(ws + 52 * MB);   // 2 MB
    unsigned short* NTcum = (unsigned short*)(ws + 54 * MB);   // 2 MB
    unsigned short* xb  = (unsigned short*)(ws + 56 * MB);     // 4 MB
    unsigned short* Wqb = (unsigned short*)(ws + 60 * MB);     // 2 MB
    unsigned short* Wkb = (unsigned short*)(ws + 62 * MB);     // 2 MB
    unsigned short* Wvb = (unsigned short*)(ws + 64 * MB);     // 2 MB
    unsigned short* Wob = (unsigned short*)(ws + 66 * MB);     // 2 MB
    unsigned short* qdb = (unsigned short*)(ws + 68 * MB);     // 64 KB
    float* biasf  = (float*)(ws + 68 * MB + 64 * KB);          // 16 KB
    float* cmax   = (float*)(ws + 68 * MB + 128 * KB);         // 32 KB
    float* segsum = (float*)(ws + 68 * MB + 192 * KB);         // 32 KB
    int*   flag   = (int*)  (ws + 68 * MB + 256 * KB);

    k_sniff<<<1, 256, 0, stream>>>((const unsigned short*)d_in[0], flag);
    k_convert<<<1024, 256, 0, stream>>>(
        d_in[0], d_in[1], d_in[2], d_in[4], d_in[6], d_in[8],
        d_in[3], d_in[5], d_in[7], d_in[9],
        flag, xb, qdb, Wqb, Wkb, Wvb, Wob, biasf);

    const float* bqf = biasf;
    const float* bkf = biasf + 1024;
    const float* bvf = biasf + 2048;
    const float* bof = biasf + 3072;

    // pass 1 GEMMs: q_u (scaled), k_d, v_d — all bf16 out
    GArg gq{ xb, Wqb, bqf, (void*)q_u, 0.125f, 1 };
    GArg gk{ xb, Wkb, bkf, (void*)k_d, 1.0f, 1 };
    GArg gv{ xb, Wvb, bvf, (void*)v_d, 1.0f, 1 };
    gemm_bt<<<dim3(8, 16, 3), 256, 0, stream>>>(gq, gk, gv, flag, SB, DM, DM);

    // pass 2 GEMMs: v_d_k, v_d_v bf16
    GArg gvk{ v_d, Wkb, bkf, (void*)v_dk, 1.0f, 1 };
    GArg gvv{ v_d, Wvb, bvf, (void*)v_dv, 1.0f, 1 };
    gemm_bt<<<dim3(8, 16, 2), 256, 0, stream>>>(gvk, gvv, gvk, flag, SB, DM, DM);

    // attention mid-section
    k_down<<<dim3(32, NCHD), 256, 0, stream>>>(k_d, qdb, wbuf, cmax);
    k_wsum<<<dim3(32, 8), 256, 0, stream>>>(wbuf, cmax, segsum);
    k_wapply<<<dim3(32, 8), 256, 0, stream>>>(wbuf, cmax, segsum, wb, wT, invn);
    k_vt<<<dim3(32, 8, 2), 256, 0, stream>>>(v_dk, v_dv, vTk, vTv);
    k_state<<<dim3(32, 16), 256, 0, stream>>>(wb, vTk, vTv, Mst, NTst);
    k_prefix<<<32, 256, 0, stream>>>(Mst, NTst, Mcum, NTcum);
    k_att<<<dim3(32, 16), 256, 0, stream>>>(q_u, v_dk, wb, invn, wT, vTv, Mcum, NTcum, attout);

    // final projection: out dtype follows sniffed input dtype
    GArg go{ attout, Wob, bof, d_out, 1.0f, 2 };
    gemm_bt<<<dim3(8, 16, 1), 256, 0, stream>>>(go, go, go, flag, SB, DM, DM);
}

// Round 7
// 210.286 us; speedup vs baseline: 1.4365x; 1.0312x over previous
//
#include <hip/hip_runtime.h>
#include <cstdint>
#include <cstddef>

// Problem constants
#define S_LEN 1024
#define BATCH 2
#define DM    1024
#define NH    16
#define DH    64
#define CC    32     // compressed length
#define SB    2048   // S*B rows
#define TSD   128
#define NCHD  8

using short8 = __attribute__((ext_vector_type(8))) short;
using f32x4  = __attribute__((ext_vector_type(4))) float;

__device__ __forceinline__ float b2f(unsigned short u) {
    union { unsigned int i; float f; } v; v.i = ((unsigned int)u) << 16; return v.f;
}
__device__ __forceinline__ unsigned short f2b(float f) {
    union { float f; unsigned int i; } v; v.f = f;
    unsigned int x = v.i;
    unsigned int r = x + 0x7FFFu + ((x >> 16) & 1u);
    return (unsigned short)(r >> 16);
}

__device__ __forceinline__ void async_ld16(const unsigned short* g, unsigned short* l) {
    __builtin_amdgcn_global_load_lds(
        (const __attribute__((address_space(1))) unsigned int*)g,
        (__attribute__((address_space(3))) unsigned int*)l,
        16, 0, 0);
}

// ---------------------------------------------------------------------------
// dtype sniffer: flag=1 -> inputs bf16; flag=0 -> inputs fp32.
// ---------------------------------------------------------------------------
__global__ void k_sniff(const unsigned short* x, int* flag) {
    __shared__ int cnt;
    if (threadIdx.x == 0) cnt = 0;
    __syncthreads();
    int local = 0;
    for (int i = threadIdx.x; i < 1024; i += 256) {
        unsigned e = (x[i * 2] >> 7) & 0xFF;
        if (e >= 90 && e <= 160) local++;
    }
    atomicAdd(&cnt, local);
    __syncthreads();
    if (threadIdx.x == 0) *flag = (cnt >= 640) ? 1 : 0;
}

// ---------------------------------------------------------------------------
// normalize inputs: x, q_down, W* -> bf16; biases -> f32; biasf[4096..5119]=0
// ---------------------------------------------------------------------------
__global__ __launch_bounds__(256) void k_convert(
    const void* x, const void* qd,
    const void* wq, const void* wk, const void* wv, const void* wo,
    const void* bq, const void* bk, const void* bv, const void* bo,
    const int* __restrict__ flag,
    unsigned short* xb, unsigned short* qdb,
    unsigned short* Wqb, unsigned short* Wkb, unsigned short* Wvb, unsigned short* Wob,
    float* biasf)
{
    const int isbf = *flag;
    const size_t tid = (size_t)blockIdx.x * 256 + threadIdx.x;
    const size_t stride = (size_t)gridDim.x * 256;

    auto cv = [&](const void* src, unsigned short* dst, size_t n) {
        if (isbf) {
            const short8* s = (const short8*)src;
            short8* d = (short8*)dst;
            for (size_t i = tid; i < n / 8; i += stride) d[i] = s[i];
        } else {
            const float4* s = (const float4*)src;
            for (size_t i = tid; i < n / 4; i += stride) {
                float4 v = s[i];
                ushort4 o;
                o.x = f2b(v.x); o.y = f2b(v.y); o.z = f2b(v.z); o.w = f2b(v.w);
                ((ushort4*)dst)[i] = o;
            }
        }
    };
    cv(x,  xb,  (size_t)SB * DM);
    cv(qd, qdb, (size_t)CC * DM);
    cv(wq, Wqb, (size_t)DM * DM);
    cv(wk, Wkb, (size_t)DM * DM);
    cv(wv, Wvb, (size_t)DM * DM);
    cv(wo, Wob, (size_t)DM * DM);
    for (size_t i = tid; i < 5 * DM; i += stride) {
        int w = (int)(i >> 10), o = (int)(i & 1023);
        float val;
        if (w == 4) val = 0.f;
        else {
            const void* bp = (w == 0) ? bq : ((w == 1) ? bk : ((w == 2) ? bv : bo));
            val = isbf ? b2f(((const unsigned short*)bp)[o]) : ((const float*)bp)[o];
        }
        biasf[i] = val;
    }
}

// ---------------------------------------------------------------------------
// k_wt: transpose Wv (1024x1024 bf16) -> WvT. Block: 128 rows x 64 cols.
// ---------------------------------------------------------------------------
__global__ __launch_bounds__(256) void k_wt(const unsigned short* __restrict__ Wv,
                                            unsigned short* __restrict__ WvT)
{
    const int r0 = blockIdx.x * 128;
    const int c0 = blockIdx.y * 64;
    const int t = threadIdx.x;
    __shared__ unsigned short T[128 * 68];
    for (int u = t; u < 128 * 8; u += 256) {
        int r = u >> 3, cb = (u & 7) * 8;
        *(short8*)&T[r * 68 + cb] = *(const short8*)&Wv[(size_t)(r0 + r) * DM + c0 + cb];
    }
    __syncthreads();
    for (int u = t; u < 64 * 16; u += 256) {
        int c = u >> 4, r8 = (u & 15) * 8;
        short8 o;
#pragma unroll
        for (int k = 0; k < 8; ++k) o[k] = T[(r8 + k) * 68 + c];
        *(short8*)&WvT[(size_t)(c0 + c) * DM + r0 + r8] = o;
    }
}

// ---------------------------------------------------------------------------
// k_bias2: b2k[n] = dot(Wk[n,:], bv) + bk[n]; b2v[n] = dot(Wv[n,:], bv) + bv[n]
// ---------------------------------------------------------------------------
__global__ __launch_bounds__(256) void k_bias2(const unsigned short* __restrict__ Wkb,
                                               const unsigned short* __restrict__ Wvb,
                                               const float* __restrict__ biasf,
                                               float* __restrict__ b2k,
                                               float* __restrict__ b2v)
{
    const int set = blockIdx.y;
    const unsigned short* W = set ? Wvb : Wkb;
    const float* bvf = biasf + 2048;
    const float* badd = set ? (biasf + 2048) : (biasf + 1024);
    float* out = set ? b2v : b2k;
    const int w = threadIdx.x >> 6, l = threadIdx.x & 63;
    const int gw = blockIdx.x * 4 + w;   // 0..127
    for (int i = 0; i < 8; ++i) {
        int row = gw * 8 + i;
        const unsigned short* wr = &W[(size_t)row * DM + l * 16];
        short8 a = *(const short8*)wr;
        short8 b = *(const short8*)(wr + 8);
        float s = 0.f;
#pragma unroll
        for (int j = 0; j < 8; ++j) {
            s += b2f((unsigned short)a[j]) * bvf[l * 16 + j];
            s += b2f((unsigned short)b[j]) * bvf[l * 16 + 8 + j];
        }
#pragma unroll
        for (int m = 1; m < 64; m <<= 1) s += __shfl_xor(s, m);
        if (l == 0) out[row] = s + badd[row];
    }
}

// ---------------------------------------------------------------------------
// GEMM: out[M,N] = (A[M,K] . Bt[N,K]^T + bias[N]) * scale
// mode: 0 = f32 out, 1 = bf16 out, 2 = flag ? bf16 : f32
// ---------------------------------------------------------------------------
struct GArg {
    const unsigned short* A;
    const unsigned short* Bt;
    const float* bias;
    void* out;
    float scale;
    int mode;
};

__device__ __forceinline__ int out_is_f32(int mode, const int* flag) {
    if (mode == 0) return 1;
    if (mode == 1) return 0;
    return (*flag == 0);
}

__global__ __launch_bounds__(256) void gemm_bt(GArg g0, GArg g1, GArg g2, GArg g3,
                                               const int* __restrict__ flag,
                                               int M, int N, int K)
{
    GArg ga = (blockIdx.z == 0) ? g0 : (blockIdx.z == 1) ? g1 : (blockIdx.z == 2) ? g2 : g3;
    const int m0 = blockIdx.y * 128;
    const int n0 = blockIdx.x * 128;
    __shared__ __align__(16) unsigned short As[128 * 32];
    __shared__ __align__(16) unsigned short Bs[128 * 32];
    const int t = threadIdx.x;
    const int w = t >> 6, l = t & 63;
    const int wy = w >> 1, wx = w & 1;
    const int lr = l >> 2;
    const int lk = (l & 3) * 8;
    const int ln = l & 15;
    const int lq = l >> 4;

    f32x4 acc[4][4] = {};

    const unsigned short* Ab0 = ga.A  + (size_t)(m0 + w * 32 +      lr) * K + lk;
    const unsigned short* Ab1 = ga.A  + (size_t)(m0 + w * 32 + 16 + lr) * K + lk;
    const unsigned short* Bb0 = ga.Bt + (size_t)(n0 + w * 32 +      lr) * K + lk;
    const unsigned short* Bb1 = ga.Bt + (size_t)(n0 + w * 32 + 16 + lr) * K + lk;
    unsigned short* Al0 = &As[w * 1024];
    unsigned short* Al1 = &As[w * 1024 + 512];
    unsigned short* Bl0 = &Bs[w * 1024];
    unsigned short* Bl1 = &Bs[w * 1024 + 512];

    for (int kk = 0; kk < K; kk += 32) {
        async_ld16(Ab0 + kk, Al0);
        async_ld16(Ab1 + kk, Al1);
        async_ld16(Bb0 + kk, Bl0);
        async_ld16(Bb1 + kk, Bl1);
        __syncthreads();
        short8 af[4], bfr[4];
#pragma unroll
        for (int i = 0; i < 4; ++i)
            af[i] = *(const short8*)&As[(wy * 64 + i * 16 + ln) * 32 + lq * 8];
#pragma unroll
        for (int j = 0; j < 4; ++j)
            bfr[j] = *(const short8*)&Bs[(wx * 64 + j * 16 + ln) * 32 + lq * 8];
#pragma unroll
        for (int i = 0; i < 4; ++i)
#pragma unroll
            for (int j = 0; j < 4; ++j)
                acc[i][j] = __builtin_amdgcn_mfma_f32_16x16x32_bf16(af[i], bfr[j], acc[i][j], 0, 0, 0);
        __syncthreads();
    }

    const int f32o = out_is_f32(ga.mode, flag);
    const float sc = ga.scale;
#pragma unroll
    for (int j = 0; j < 4; ++j) {
        int col = n0 + wx * 64 + j * 16 + ln;
        float bv = ga.bias[col];
#pragma unroll
        for (int i = 0; i < 4; ++i) {
            int row0 = m0 + wy * 64 + i * 16 + lq * 4;
#pragma unroll
            for (int r = 0; r < 4; ++r) {
                float v = (acc[i][j][r] + bv) * sc;
                size_t idx = (size_t)(row0 + r) * N + col;
                if (f32o) ((float*)ga.out)[idx] = v;
                else      ((unsigned short*)ga.out)[idx] = f2b(v);
            }
        }
    }
}

// ---------------------------------------------------------------------------
// gemm_bt_n64: 128x64 tiles (better packing for N=1024 / small-M launches)
// ---------------------------------------------------------------------------
__global__ __launch_bounds__(256) void gemm_bt_n64(GArg g0, GArg g1,
                                                   const int* __restrict__ flag,
                                                   int M, int N, int K)
{
    GArg ga = (blockIdx.z == 0) ? g0 : g1;
    const int m0 = blockIdx.y * 128;
    const int n0 = blockIdx.x * 64;
    __shared__ __align__(16) unsigned short As[128 * 32];
    __shared__ __align__(16) unsigned short Bs[64 * 32];
    const int t = threadIdx.x;
    const int w = t >> 6, l = t & 63;
    const int wy = w >> 1, wx = w & 1;
    const int lr = l >> 2;
    const int lk = (l & 3) * 8;
    const int ln = l & 15;
    const int lq = l >> 4;

    f32x4 acc[4][2] = {};

    const unsigned short* Ab0 = ga.A  + (size_t)(m0 + w * 32 +      lr) * K + lk;
    const unsigned short* Ab1 = ga.A  + (size_t)(m0 + w * 32 + 16 + lr) * K + lk;
    const unsigned short* Bb  = ga.Bt + (size_t)(n0 + w * 16 + lr) * K + lk;
    unsigned short* Al0 = &As[w * 1024];
    unsigned short* Al1 = &As[w * 1024 + 512];
    unsigned short* Bl  = &Bs[w * 512];

    for (int kk = 0; kk < K; kk += 32) {
        async_ld16(Ab0 + kk, Al0);
        async_ld16(Ab1 + kk, Al1);
        async_ld16(Bb + kk, Bl);
        __syncthreads();
        short8 af[4], bfr[2];
#pragma unroll
        for (int i = 0; i < 4; ++i)
            af[i] = *(const short8*)&As[(wy * 64 + i * 16 + ln) * 32 + lq * 8];
#pragma unroll
        for (int j = 0; j < 2; ++j)
            bfr[j] = *(const short8*)&Bs[(wx * 32 + j * 16 + ln) * 32 + lq * 8];
#pragma unroll
        for (int i = 0; i < 4; ++i)
#pragma unroll
            for (int j = 0; j < 2; ++j)
                acc[i][j] = __builtin_amdgcn_mfma_f32_16x16x32_bf16(af[i], bfr[j], acc[i][j], 0, 0, 0);
        __syncthreads();
    }

    const int f32o = out_is_f32(ga.mode, flag);
    const float sc = ga.scale;
#pragma unroll
    for (int j = 0; j < 2; ++j) {
        int col = n0 + wx * 32 + j * 16 + ln;
        float bv = ga.bias[col];
#pragma unroll
        for (int i = 0; i < 4; ++i) {
            int row0 = m0 + wy * 64 + i * 16 + lq * 4;
#pragma unroll
            for (int r = 0; r < 4; ++r) {
                float v = (acc[i][j][r] + bv) * sc;
                size_t idx = (size_t)(row0 + r) * N + col;
                if (f32o) ((float*)ga.out)[idx] = v;
                else      ((unsigned short*)ga.out)[idx] = f2b(v);
            }
        }
    }
}

// ---------------------------------------------------------------------------
// down[bh,c,s] = 0.125 * sum_d q_down[c,h*64+d] * k_d[s,b,h*64+d]; chunk max
// ---------------------------------------------------------------------------
__global__ __launch_bounds__(256) void k_down(const unsigned short* __restrict__ kd,
                                              const unsigned short* __restrict__ qdw,
                                              float* __restrict__ wbuf,
                                              float* __restrict__ cmax)
{
    const int bh = blockIdx.x;
    const int b = bh >> 4, h = bh & 15;
    const int chunk = blockIdx.y;
    const int s0 = chunk * TSD;
    const int t = threadIdx.x;

    __shared__ float qd[CC * DH];
    __shared__ float kt[TSD * DH];
    __shared__ float pm[CC * 8];

    for (int idx = t; idx < CC * DH; idx += 256)
        qd[idx] = b2f(qdw[(idx >> 6) * DM + h * DH + (idx & 63)]);
    for (int u = t; u < TSD * DH / 8; u += 256) {
        int sl = u >> 3, d8 = (u & 7) * 8;
        short8 v = *(const short8*)&kd[(size_t)((s0 + sl) * BATCH + b) * DM + h * DH + d8];
#pragma unroll
        for (int j = 0; j < 8; ++j) kt[sl * DH + d8 + j] = b2f((unsigned short)v[j]);
    }
    __syncthreads();

    const int c = t & 31;
    float lmax = -3.4e38f;
    for (int idx = t; idx < CC * TSD; idx += 256) {
        int sl = idx >> 5;
        float s = 0.f;
#pragma unroll
        for (int d = 0; d < DH; d += 4) {
            float4 qa = *(const float4*)&qd[c * DH + d];
            float4 kb = *(const float4*)&kt[sl * DH + d];
            s += qa.x * kb.x + qa.y * kb.y + qa.z * kb.z + qa.w * kb.w;
        }
        s *= 0.125f;
        wbuf[((size_t)bh * CC + c) * S_LEN + s0 + sl] = s;
        lmax = fmaxf(lmax, s);
    }
    pm[c * 8 + (t >> 5)] = lmax;
    __syncthreads();
    if (t < CC) {
        float m = pm[t * 8];
#pragma unroll
        for (int g = 1; g < 8; ++g) m = fmaxf(m, pm[t * 8 + g]);
        cmax[((size_t)bh * CC + t) * NCHD + chunk] = m;
    }
}

// ---------------------------------------------------------------------------
// k_wsum: per (bh, seg of 128): segsum[bh,c,seg] = sum_{s in seg} exp(down-gmax)
// ---------------------------------------------------------------------------
__global__ __launch_bounds__(256) void k_wsum(const float* __restrict__ wbuf,
                                              const float* __restrict__ cmax,
                                              float* __restrict__ segsum)
{
    const int bh = blockIdx.x, seg = blockIdx.y;
    const int t = threadIdx.x;
    __shared__ float gm[CC];
    if (t < CC) {
        float m = cmax[(size_t)(bh * CC + t) * NCHD];
#pragma unroll
        for (int g = 1; g < NCHD; ++g) m = fmaxf(m, cmax[(size_t)(bh * CC + t) * NCHD + g]);
        gm[t] = m;
    }
    __syncthreads();
    const int c = t >> 3, sub = t & 7;
    const float gmc = gm[c];
    const size_t base = (size_t)bh * 32768 + c * 1024 + seg * 128 + sub * 16;
    float s = 0.f;
#pragma unroll
    for (int i = 0; i < 16; ++i) s += __expf(wbuf[base + i] - gmc);
    s += __shfl_xor(s, 1);
    s += __shfl_xor(s, 2);
    s += __shfl_xor(s, 4);
    if (sub == 0) segsum[(size_t)(bh * CC + c) * 8 + seg] = s;
}

// ---------------------------------------------------------------------------
// k_wapply: w -> wb[bh][c][s], wT[bh][s][c], invn[bh][s][c] = 1/cumsum
// ---------------------------------------------------------------------------
__global__ __launch_bounds__(256) void k_wapply(const float* __restrict__ wbuf,
                                                const float* __restrict__ cmax,
                                                const float* __restrict__ segsum,
                                                unsigned short* __restrict__ wb,
                                                unsigned short* __restrict__ wT,
                                                float* __restrict__ invn)
{
    const int bh = blockIdx.x, seg = blockIdx.y;
    const int t = threadIdx.x;
    __shared__ float gm[CC];
    __shared__ float basep[CC];
    __shared__ float psum[CC][9];
    __shared__ unsigned short wTt[128 * 40];
    __shared__ float invt[128 * 36];

    if (t < CC) {
        float m = cmax[(size_t)(bh * CC + t) * NCHD];
#pragma unroll
        for (int g = 1; g < NCHD; ++g) m = fmaxf(m, cmax[(size_t)(bh * CC + t) * NCHD + g]);
        gm[t] = m;
        float bsum = 0.f;
        for (int k = 0; k < seg; ++k) bsum += segsum[(size_t)(bh * CC + t) * 8 + k];
        basep[t] = bsum;
    }
    __syncthreads();

    const int c = t >> 3, sub = t & 7;
    const float gmc = gm[c];
    const size_t rbase = (size_t)bh * 32768 + c * 1024 + seg * 128 + sub * 16;
    float w16[16];
    float s = 0.f;
#pragma unroll
    for (int i = 0; i < 16; ++i) {
        float v = __expf(wbuf[rbase + i] - gmc);
        w16[i] = v; s += v;
    }
    psum[c][sub] = s;
    short8 o0, o1;
#pragma unroll
    for (int i = 0; i < 8; ++i) { o0[i] = f2b(w16[i]); o1[i] = f2b(w16[8 + i]); }
    *(short8*)&wb[rbase] = o0;
    *(short8*)&wb[rbase + 8] = o1;
#pragma unroll
    for (int i = 0; i < 16; ++i) wTt[(sub * 16 + i) * 40 + c] = f2b(w16[i]);
    __syncthreads();

    float run = basep[c];
    for (int k = 0; k < sub; ++k) run += psum[c][k];
#pragma unroll
    for (int i = 0; i < 16; ++i) {
        run += w16[i];
        invt[(sub * 16 + i) * 36 + c] = 1.0f / fmaxf(run, 1e-30f);
    }
    __syncthreads();

    for (int u = t; u < 128 * 4; u += 256) {
        int r = u >> 2, cb = (u & 3) * 8;
        *(short8*)&wT[(size_t)bh * 32768 + (seg * 128 + r) * 32 + cb] =
            *(const short8*)&wTt[r * 40 + cb];
    }
    for (int u = t; u < 128 * 8; u += 256) {
        int r = u >> 3, cb = (u & 7) * 4;
        *(float4*)&invn[(size_t)bh * 32768 + (seg * 128 + r) * 32 + cb] =
            *(const float4*)&invt[r * 36 + cb];
    }
}

// ---------------------------------------------------------------------------
// k_vt: transpose [s][b][dm] -> [bh][d][s] for v_dk (z=0) and v_dv (z=1)
// ---------------------------------------------------------------------------
__global__ __launch_bounds__(256) void k_vt(const unsigned short* __restrict__ vdk,
                                            const unsigned short* __restrict__ vdv,
                                            unsigned short* __restrict__ vTk,
                                            unsigned short* __restrict__ vTv)
{
    const unsigned short* src = blockIdx.z ? vdv : vdk;
    unsigned short* dst = blockIdx.z ? vTv : vTk;
    const int bh = blockIdx.x, b = bh >> 4, h = bh & 15;
    const int s0 = blockIdx.y * 128;
    const int t = threadIdx.x;
    __shared__ unsigned short T[128 * 68];
    for (int u = t; u < 128 * 8; u += 256) {
        int r = u >> 3, cb = (u & 7) * 8;
        *(short8*)&T[r * 68 + cb] =
            *(const short8*)&src[(size_t)(s0 + r) * 2048 + b * 1024 + h * 64 + cb];
    }
    __syncthreads();
    for (int u = t; u < 64 * 16; u += 256) {
        int d = u >> 4, s8 = (u & 15) * 8;
        short8 o;
#pragma unroll
        for (int k = 0; k < 8; ++k) o[k] = T[(s8 + k) * 68 + d];
        *(short8*)&dst[(size_t)bh * 65536 + d * 1024 + s0 + s8] = o;
    }
}

// ---------------------------------------------------------------------------
// k_state: per (bh, chunk of 64): M[c,d] = sum_s' w[c,s']*v_dk[s',d] (f32)
//                                 NT[d,c] = sum_s' v_dv[s',d]*w[c,s'] (f32)
// ---------------------------------------------------------------------------
__global__ __launch_bounds__(256) void k_state(const unsigned short* __restrict__ wb,
                                               const unsigned short* __restrict__ vTk,
                                               const unsigned short* __restrict__ vTv,
                                               float* __restrict__ Mst,
                                               float* __restrict__ NTst)
{
    const int bh = blockIdx.x, ch = blockIdx.y;
    const int s0 = ch * 64;
    const int t = threadIdx.x;
    const int w = t >> 6, l = t & 63;
    const int ln = l & 15, lq = l >> 4;
    __shared__ __align__(16) unsigned short Ws[32 * 72];
    __shared__ __align__(16) unsigned short KT[64 * 72];
    __shared__ __align__(16) unsigned short VT[64 * 72];

    for (int u = t; u < 32 * 8; u += 256) {
        int r = u >> 3, cb = (u & 7) * 8;
        *(short8*)&Ws[r * 72 + cb] = *(const short8*)&wb[(size_t)bh * 32768 + r * 1024 + s0 + cb];
    }
    for (int u = t; u < 64 * 8; u += 256) {
        int r = u >> 3, cb = (u & 7) * 8;
        *(short8*)&KT[r * 72 + cb] = *(const short8*)&vTk[(size_t)bh * 65536 + r * 1024 + s0 + cb];
        *(short8*)&VT[r * 72 + cb] = *(const short8*)&vTv[(size_t)bh * 65536 + r * 1024 + s0 + cb];
    }
    __syncthreads();

    f32x4 accM[2] = {};
#pragma unroll
    for (int ks = 0; ks < 2; ++ks) {
        short8 b8 = *(const short8*)&KT[(w * 16 + ln) * 72 + ks * 32 + lq * 8];
#pragma unroll
        for (int i = 0; i < 2; ++i) {
            short8 a8 = *(const short8*)&Ws[(i * 16 + ln) * 72 + ks * 32 + lq * 8];
            accM[i] = __builtin_amdgcn_mfma_f32_16x16x32_bf16(a8, b8, accM[i], 0, 0, 0);
        }
    }
#pragma unroll
    for (int i = 0; i < 2; ++i)
#pragma unroll
        for (int r = 0; r < 4; ++r)
            Mst[((size_t)(bh * 16 + ch) * 32 + i * 16 + lq * 4 + r) * 64 + w * 16 + ln] = accM[i][r];

    f32x4 accN[2] = {};
#pragma unroll
    for (int ks = 0; ks < 2; ++ks) {
        short8 a8 = *(const short8*)&VT[(w * 16 + ln) * 72 + ks * 32 + lq * 8];
#pragma unroll
        for (int j = 0; j < 2; ++j) {
            short8 b8 = *(const short8*)&Ws[(j * 16 + ln) * 72 + ks * 32 + lq * 8];
            accN[j] = __builtin_amdgcn_mfma_f32_16x16x32_bf16(a8, b8, accN[j], 0, 0, 0);
        }
    }
#pragma unroll
    for (int j = 0; j < 2; ++j)
#pragma unroll
        for (int r = 0; r < 4; ++r)
            NTst[((size_t)(bh * 16 + ch) * 64 + w * 16 + lq * 4 + r) * 32 + j * 16 + ln] = accN[j][r];
}

// ---------------------------------------------------------------------------
// k_prefix: exclusive prefix over 16 chunks (f32) -> bf16; y: 0=M, 1=NT
// ---------------------------------------------------------------------------
__global__ __launch_bounds__(256) void k_prefix(const float* __restrict__ Mst,
                                                const float* __restrict__ NTst,
                                                unsigned short* __restrict__ Mcum,
                                                unsigned short* __restrict__ NTcum)
{
    const int bh = blockIdx.x;
    const float* src = blockIdx.y ? NTst : Mst;
    unsigned short* dst = blockIdx.y ? NTcum : Mcum;
    const int e0 = threadIdx.x * 8;
    float run[8];
#pragma unroll
    for (int j = 0; j < 8; ++j) run[j] = 0.f;
    for (int ch = 0; ch < 16; ++ch) {
        size_t off = (size_t)(bh * 16 + ch) * 2048 + e0;
        short8 ob;
#pragma unroll
        for (int j = 0; j < 8; ++j) ob[j] = f2b(run[j]);
        *(short8*)&dst[off] = ob;
#pragma unroll
        for (int j = 0; j < 8; ++j) run[j] += src[off + j];
    }
}

// ---------------------------------------------------------------------------
// k_att (chunked): per (bh, q-tile 64). Uniform work, 5 barriers/block.
// ---------------------------------------------------------------------------
__global__ __launch_bounds__(256) void k_att(
    const unsigned short* __restrict__ qu,
    const unsigned short* __restrict__ vdk,
    const unsigned short* __restrict__ wb,
    const float* __restrict__ invn,
    const unsigned short* __restrict__ wT,
    const unsigned short* __restrict__ vTv,
    const unsigned short* __restrict__ Mcum,
    const unsigned short* __restrict__ NTcum,
    unsigned short* __restrict__ attout)
{
    const int bh = blockIdx.x, b = bh >> 4, h = bh & 15;
    const int qi = blockIdx.y;
    const int s0 = qi * 64;
    const int t = threadIdx.x;
    const int w = t >> 6, l = t & 63;
    const int wy = w >> 1, wx = w & 1;
    const int ln = l & 15, lq = l >> 4;

    __shared__ __align__(16) unsigned short Qs[64 * 72];
    __shared__ __align__(16) unsigned short Gs[64 * 72];
    __shared__ __align__(16) unsigned short Kd[64 * 72];
    __shared__ __align__(16) unsigned short Wd[32 * 72];
    __shared__ __align__(16) unsigned short WTd[64 * 40];
    __shared__ __align__(16) unsigned short VTd[64 * 72];
    __shared__ __align__(16) unsigned short Mc[32 * 72];
    __shared__ __align__(16) unsigned short Nc[64 * 40];

    for (int u = t; u < 64 * 8; u += 256) {
        int r = u >> 3, cb = (u & 7) * 8;
        *(short8*)&Qs[r * 72 + cb] =
            *(const short8*)&qu[(size_t)(s0 + r) * 2048 + b * 1024 + h * 64 + cb];
        *(short8*)&Kd[r * 72 + cb] =
            *(const short8*)&vdk[(size_t)(s0 + r) * 2048 + b * 1024 + h * 64 + cb];
        *(short8*)&VTd[r * 72 + cb] =
            *(const short8*)&vTv[(size_t)bh * 65536 + r * 1024 + s0 + cb];
    }
    for (int u = t; u < 32 * 8; u += 256) {
        int r = u >> 3, cb = (u & 7) * 8;
        *(short8*)&Wd[r * 72 + cb] =
            *(const short8*)&wb[(size_t)bh * 32768 + r * 1024 + s0 + cb];
        *(short8*)&Mc[r * 72 + cb] =
            *(const short8*)&Mcum[((size_t)(bh * 16 + qi) * 32 + r) * 64 + cb];
    }
    for (int u = t; u < 64 * 4; u += 256) {
        int r = u >> 2, cb = (u & 3) * 8;
        *(short8*)&WTd[r * 40 + cb] =
            *(const short8*)&wT[(size_t)bh * 32768 + (s0 + r) * 32 + cb];
        *(short8*)&Nc[r * 40 + cb] =
            *(const short8*)&NTcum[((size_t)(bh * 16 + qi) * 64 + r) * 32 + cb];
    }
    __syncthreads();

    // P2: G = q @ k_diag^T, causal, -> Gs
    {
        f32x4 accG[2][2] = {};
#pragma unroll
        for (int ks = 0; ks < 2; ++ks) {
            short8 a8[2], b8[2];
#pragma unroll
            for (int i = 0; i < 2; ++i)
                a8[i] = *(const short8*)&Qs[(wy * 32 + i * 16 + ln) * 72 + ks * 32 + lq * 8];
#pragma unroll
            for (int j = 0; j < 2; ++j)
                b8[j] = *(const short8*)&Kd[(wx * 32 + j * 16 + ln) * 72 + ks * 32 + lq * 8];
#pragma unroll
            for (int i = 0; i < 2; ++i)
#pragma unroll
                for (int j = 0; j < 2; ++j)
                    accG[i][j] = __builtin_amdgcn_mfma_f32_16x16x32_bf16(a8[i], b8[j], accG[i][j], 0, 0, 0);
        }
#pragma unroll
        for (int i = 0; i < 2; ++i) {
            int row = wy * 32 + i * 16 + lq * 4;
#pragma unroll
            for (int j = 0; j < 2; ++j) {
                int col = wx * 32 + j * 16 + ln;
#pragma unroll
                for (int r = 0; r < 4; ++r) {
                    float v = accG[i][j][r];
                    if (col > row + r) v = 0.f;
                    Gs[(row + r) * 72 + col] = f2b(v);
                }
            }
        }
    }
    __syncthreads();

    // P3: up = G @ w_diag^T + q @ Mcum^T
    f32x4 accU[2] = {};
#pragma unroll
    for (int ks = 0; ks < 2; ++ks) {
        short8 ga = *(const short8*)&Gs[(w * 16 + ln) * 72 + ks * 32 + lq * 8];
        short8 qa = *(const short8*)&Qs[(w * 16 + ln) * 72 + ks * 32 + lq * 8];
#pragma unroll
        for (int j = 0; j < 2; ++j) {
            short8 wf = *(const short8*)&Wd[(j * 16 + ln) * 72 + ks * 32 + lq * 8];
            short8 mf = *(const short8*)&Mc[(j * 16 + ln) * 72 + ks * 32 + lq * 8];
            accU[j] = __builtin_amdgcn_mfma_f32_16x16x32_bf16(ga, wf, accU[j], 0, 0, 0);
            accU[j] = __builtin_amdgcn_mfma_f32_16x16x32_bf16(qa, mf, accU[j], 0, 0, 0);
        }
    }
    __syncthreads();

    // P4: softmax(up*invn) -> ptil into Qs (stride 40)
    {
        int rowl = w * 16 + lq * 4;
#pragma unroll
        for (int r = 0; r < 4; ++r) {
            int srow = s0 + rowl + r;
            float inv0 = invn[(size_t)bh * 32768 + srow * 32 + ln];
            float inv1 = invn[(size_t)bh * 32768 + srow * 32 + 16 + ln];
            float l0 = accU[0][r] * inv0;
            float l1 = accU[1][r] * inv1;
            float m = fmaxf(l0, l1);
#pragma unroll
            for (int msk = 1; msk < 16; msk <<= 1) m = fmaxf(m, __shfl_xor(m, msk));
            float e0 = __expf(l0 - m), e1 = __expf(l1 - m);
            float Z = e0 + e1;
#pragma unroll
            for (int msk = 1; msk < 16; msk <<= 1) Z += __shfl_xor(Z, msk);
            float iz = 1.0f / Z;
            Qs[(rowl + r) * 40 + ln]      = f2b(e0 * iz * inv0);
            Qs[(rowl + r) * 40 + 16 + ln] = f2b(e1 * iz * inv1);
        }
    }
    __syncthreads();

    // P5: SC = ptil @ wT_diag^T (K=32), causal, -> Gs
    short8 pa[2];
#pragma unroll
    for (int i = 0; i < 2; ++i)
        pa[i] = *(const short8*)&Qs[(wy * 32 + i * 16 + ln) * 40 + lq * 8];
    {
        f32x4 accS[2][2] = {};
        short8 b8[2];
#pragma unroll
        for (int j = 0; j < 2; ++j)
            b8[j] = *(const short8*)&WTd[(wx * 32 + j * 16 + ln) * 40 + lq * 8];
#pragma unroll
        for (int i = 0; i < 2; ++i)
#pragma unroll
            for (int j = 0; j < 2; ++j)
                accS[i][j] = __builtin_amdgcn_mfma_f32_16x16x32_bf16(pa[i], b8[j], accS[i][j], 0, 0, 0);
#pragma unroll
        for (int i = 0; i < 2; ++i) {
            int row = wy * 32 + i * 16 + lq * 4;
#pragma unroll
            for (int j = 0; j < 2; ++j) {
                int col = wx * 32 + j * 16 + ln;
#pragma unroll
                for (int r = 0; r < 4; ++r) {
                    float v = accS[i][j][r];
                    if (col > row + r) v = 0.f;
                    Gs[(row + r) * 72 + col] = f2b(v);
                }
            }
        }
    }
    __syncthreads();

    // P6: out = SC @ vT_diag^T + ptil @ NTcum^T -> attout
    {
        f32x4 accO[2][2] = {};
        short8 n8[2];
#pragma unroll
        for (int j = 0; j < 2; ++j)
            n8[j] = *(const short8*)&Nc[(wx * 32 + j * 16 + ln) * 40 + lq * 8];
#pragma unroll
        for (int i = 0; i < 2; ++i)
#pragma unroll
            for (int j = 0; j < 2; ++j)
                accO[i][j] = __builtin_amdgcn_mfma_f32_16x16x32_bf16(pa[i], n8[j], accO[i][j], 0, 0, 0);
#pragma unroll
        for (int ks = 0; ks < 2; ++ks) {
            short8 a8[2], b8[2];
#pragma unroll
            for (int i = 0; i < 2; ++i)
                a8[i] = *(const short8*)&Gs[(wy * 32 + i * 16 + ln) * 72 + ks * 32 + lq * 8];
#pragma unroll
            for (int j = 0; j < 2; ++j)
                b8[j] = *(const short8*)&VTd[(wx * 32 + j * 16 + ln) * 72 + ks * 32 + lq * 8];
#pragma unroll
            for (int i = 0; i < 2; ++i)
#pragma unroll
                for (int j = 0; j < 2; ++j)
                    accO[i][j] = __builtin_amdgcn_mfma_f32_16x16x32_bf16(a8[i], b8[j], accO[i][j], 0, 0, 0);
        }
#pragma unroll
        for (int i = 0; i < 2; ++i) {
            int rowb = s0 + wy * 32 + i * 16 + lq * 4;
#pragma unroll
            for (int j = 0; j < 2; ++j) {
                int d = wx * 32 + j * 16 + ln;
#pragma unroll
                for (int r = 0; r < 4; ++r)
                    attout[(size_t)(rowb + r) * 2048 + b * 1024 + h * 64 + d] = f2b(accO[i][j][r]);
            }
        }
    }
}

// ---------------------------------------------------------------------------
extern "C" void kernel_launch(void* const* d_in, const int* in_sizes, int n_in,
                              void* d_out, int out_size, void* d_ws, size_t ws_size,
                              hipStream_t stream)
{
    (void)in_sizes; (void)n_in; (void)out_size; (void)ws_size;
    char* ws = (char*)d_ws;
    const size_t MB = (size_t)1 << 20;
    const size_t KB = (size_t)1 << 10;
    unsigned short* attout = (unsigned short*)(ws + 0 * MB);   // 4 MB
    unsigned short* q_u    = (unsigned short*)(ws + 4 * MB);   // 4 MB (pre-scaled)
    unsigned short* k_d    = (unsigned short*)(ws + 8 * MB);   // 4 MB
    unsigned short* v_dk   = (unsigned short*)(ws + 12 * MB);  // 4 MB
    unsigned short* v_dv   = (unsigned short*)(ws + 16 * MB);  // 4 MB
    float* wbuf = (float*)(ws + 20 * MB);                      // 4 MB (down scores)
    unsigned short* wb  = (unsigned short*)(ws + 24 * MB);     // 2 MB [bh][c][s]
    unsigned short* wT  = (unsigned short*)(ws + 26 * MB);     // 2 MB [bh][s][c]
    float* invn = (float*)(ws + 28 * MB);                      // 4 MB [bh][s][c]
    unsigned short* vTk = (unsigned short*)(ws + 32 * MB);     // 4 MB
    unsigned short* vTv = (unsigned short*)(ws + 36 * MB);     // 4 MB
    float* Mst  = (float*)(ws + 40 * MB);                      // 4 MB
    float* NTst = (float*)(ws + 44 * MB);                      // 4 MB
    unsigned short* Mcum  = (unsigned short*)(ws + 48 * MB);   // 2 MB
    unsigned short* NTcum = (unsigned short*)(ws + 50 * MB);   // 2 MB
    unsigned short* xb  = (unsigned short*)(ws + 52 * MB);     // 4 MB
    unsigned short* Wqb = (unsigned short*)(ws + 56 * MB);     // 2 MB
    unsigned short* Wkb = (unsigned short*)(ws + 58 * MB);     // 2 MB
    unsigned short* Wvb = (unsigned short*)(ws + 60 * MB);     // 2 MB
    unsigned short* Wob = (unsigned short*)(ws + 62 * MB);     // 2 MB
    unsigned short* WvT = (unsigned short*)(ws + 64 * MB);     // 2 MB
    unsigned short* W2k = (unsigned short*)(ws + 66 * MB);     // 2 MB (Wk·Wv)
    unsigned short* W2v = (unsigned short*)(ws + 68 * MB);     // 2 MB (Wv·Wv)
    unsigned short* qdb = (unsigned short*)(ws + 70 * MB);     // 64 KB
    float* biasf  = (float*)(ws + 70 * MB + 64 * KB);          // 20 KB [bq,bk,bv,bo,zero]
    float* b2k    = (float*)(ws + 70 * MB + 128 * KB);         // 4 KB
    float* b2v    = (float*)(ws + 70 * MB + 132 * KB);         // 4 KB
    float* cmax   = (float*)(ws + 70 * MB + 192 * KB);         // 32 KB
    float* segsum = (float*)(ws + 70 * MB + 256 * KB);         // 32 KB
    int*   flag   = (int*)  (ws + 70 * MB + 320 * KB);

    k_sniff<<<1, 256, 0, stream>>>((const unsigned short*)d_in[0], flag);
    k_convert<<<1024, 256, 0, stream>>>(
        d_in[0], d_in[1], d_in[2], d_in[4], d_in[6], d_in[8],
        d_in[3], d_in[5], d_in[7], d_in[9],
        flag, xb, qdb, Wqb, Wkb, Wvb, Wob, biasf);

    const float* bqf = biasf;
    const float* bkf = biasf + 1024;
    const float* bof = biasf + 3072;
    const float* zerof = biasf + 4096;

    // weight prep: WvT, combined biases, W2k = Wk·Wv, W2v = Wv·Wv
    k_wt<<<dim3(8, 16), 256, 0, stream>>>(Wvb, WvT);
    k_bias2<<<dim3(32, 2), 256, 0, stream>>>(Wkb, Wvb, biasf, b2k, b2v);
    GArg wpk{ Wkb, WvT, zerof, (void*)W2k, 1.0f, 1 };
    GArg wpv{ Wvb, WvT, zerof, (void*)W2v, 1.0f, 1 };
    gemm_bt_n64<<<dim3(16, 8, 2), 256, 0, stream>>>(wpk, wpv, flag, DM, DM, DM);

    // main projections: q_u (scaled), k_d, v_dk, v_dv in ONE launch (512 blocks)
    GArg gq { xb, Wqb, bqf, (void*)q_u, 0.125f, 1 };
    GArg gk { xb, Wkb, bkf, (void*)k_d, 1.0f, 1 };
    GArg gvk{ xb, W2k, b2k, (void*)v_dk, 1.0f, 1 };
    GArg gvv{ xb, W2v, b2v, (void*)v_dv, 1.0f, 1 };
    gemm_bt<<<dim3(8, 16, 4), 256, 0, stream>>>(gq, gk, gvk, gvv, flag, SB, DM, DM);

    // attention mid-section
    k_down<<<dim3(32, NCHD), 256, 0, stream>>>(k_d, qdb, wbuf, cmax);
    k_wsum<<<dim3(32, 8), 256, 0, stream>>>(wbuf, cmax, segsum);
    k_wapply<<<dim3(32, 8), 256, 0, stream>>>(wbuf, cmax, segsum, wb, wT, invn);
    k_vt<<<dim3(32, 8, 2), 256, 0, stream>>>(v_dk, v_dv, vTk, vTv);
    k_state<<<dim3(32, 16), 256, 0, stream>>>(wb, vTk, vTv, Mst, NTst);
    k_prefix<<<dim3(32, 2), 256, 0, stream>>>(Mst, NTst, Mcum, NTcum);
    k_att<<<dim3(32, 16), 256, 0, stream>>>(q_u, v_dk, wb, invn, wT, vTv, Mcum, NTcum, attout);

    // final projection (256 blocks): out dtype follows sniffed input dtype
    GArg go{ attout, Wob, bof, d_out, 1.0f, 2 };
    gemm_bt_n64<<<dim3(16, 16, 1), 256, 0, stream>>>(go, go, flag, SB, DM, DM);
}

// Round 8
// 197.847 us; speedup vs baseline: 1.5268x; 1.0629x over previous
//
#include <hip/hip_runtime.h>
#include <cstdint>
#include <cstddef>

// Problem constants
#define S_LEN 1024
#define BATCH 2
#define DM    1024
#define NH    16
#define DH    64
#define CC    32     // compressed length
#define SB    2048   // S*B rows
#define TSD   128
#define NCHD  8

using short8 = __attribute__((ext_vector_type(8))) short;
using f32x4  = __attribute__((ext_vector_type(4))) float;

__device__ __forceinline__ float b2f(unsigned short u) {
    union { unsigned int i; float f; } v; v.i = ((unsigned int)u) << 16; return v.f;
}
__device__ __forceinline__ unsigned short f2b(float f) {
    union { float f; unsigned int i; } v; v.f = f;
    unsigned int x = v.i;
    unsigned int r = x + 0x7FFFu + ((x >> 16) & 1u);
    return (unsigned short)(r >> 16);
}

__device__ __forceinline__ void async_ld16(const unsigned short* g, unsigned short* l) {
    __builtin_amdgcn_global_load_lds(
        (const __attribute__((address_space(1))) unsigned int*)g,
        (__attribute__((address_space(3))) unsigned int*)l,
        16, 0, 0);
}

// ---------------------------------------------------------------------------
// k_convert: inline dtype sniff (per-block, deterministic) + normalize inputs
// x, q_down, W* -> bf16; biases -> f32; biasf[4096..5119]=0; block0 writes flag
// ---------------------------------------------------------------------------
__global__ __launch_bounds__(256) void k_convert(
    const void* x, const void* qd,
    const void* wq, const void* wk, const void* wv, const void* wo,
    const void* bq, const void* bk, const void* bv, const void* bo,
    int* __restrict__ flag,
    unsigned short* xb, unsigned short* qdb,
    unsigned short* Wqb, unsigned short* Wkb, unsigned short* Wvb, unsigned short* Wob,
    float* biasf)
{
    __shared__ int cnt;
    if (threadIdx.x == 0) cnt = 0;
    __syncthreads();
    {
        const unsigned short* xs = (const unsigned short*)x;
        int local = 0;
        for (int i = threadIdx.x; i < 1024; i += 256) {
            unsigned e = (xs[i * 2] >> 7) & 0xFF;
            if (e >= 90 && e <= 160) local++;
        }
        atomicAdd(&cnt, local);
    }
    __syncthreads();
    const int isbf = (cnt >= 640);
    if (blockIdx.x == 0 && threadIdx.x == 0) *flag = isbf;

    const size_t tid = (size_t)blockIdx.x * 256 + threadIdx.x;
    const size_t stride = (size_t)gridDim.x * 256;

    auto cv = [&](const void* src, unsigned short* dst, size_t n) {
        if (isbf) {
            const short8* s = (const short8*)src;
            short8* d = (short8*)dst;
            for (size_t i = tid; i < n / 8; i += stride) d[i] = s[i];
        } else {
            const float4* s = (const float4*)src;
            for (size_t i = tid; i < n / 4; i += stride) {
                float4 v = s[i];
                ushort4 o;
                o.x = f2b(v.x); o.y = f2b(v.y); o.z = f2b(v.z); o.w = f2b(v.w);
                ((ushort4*)dst)[i] = o;
            }
        }
    };
    cv(x,  xb,  (size_t)SB * DM);
    cv(qd, qdb, (size_t)CC * DM);
    cv(wq, Wqb, (size_t)DM * DM);
    cv(wk, Wkb, (size_t)DM * DM);
    cv(wv, Wvb, (size_t)DM * DM);
    cv(wo, Wob, (size_t)DM * DM);
    for (size_t i = tid; i < 5 * DM; i += stride) {
        int w = (int)(i >> 10), o = (int)(i & 1023);
        float val;
        if (w == 4) val = 0.f;
        else {
            const void* bp = (w == 0) ? bq : ((w == 1) ? bk : ((w == 2) ? bv : bo));
            val = isbf ? b2f(((const unsigned short*)bp)[o]) : ((const float*)bp)[o];
        }
        biasf[i] = val;
    }
}

// ---------------------------------------------------------------------------
// k_prep: blocks 0..127 -> WvT transpose tiles; 128..191 -> combined biases
// b2k[n] = dot(Wk[n,:], bv) + bk[n]; b2v[n] = dot(Wv[n,:], bv) + bv[n]
// ---------------------------------------------------------------------------
__global__ __launch_bounds__(256) void k_prep(const unsigned short* __restrict__ Wvb,
                                              const unsigned short* __restrict__ Wkb,
                                              const float* __restrict__ biasf,
                                              unsigned short* __restrict__ WvT,
                                              float* __restrict__ b2k,
                                              float* __restrict__ b2v)
{
    const int t = threadIdx.x;
    if (blockIdx.x < 128) {
        const int r0 = (blockIdx.x & 7) * 128;
        const int c0 = (blockIdx.x >> 3) * 64;
        __shared__ unsigned short T[128 * 68];
        for (int u = t; u < 128 * 8; u += 256) {
            int r = u >> 3, cb = (u & 7) * 8;
            *(short8*)&T[r * 68 + cb] = *(const short8*)&Wvb[(size_t)(r0 + r) * DM + c0 + cb];
        }
        __syncthreads();
        for (int u = t; u < 64 * 16; u += 256) {
            int c = u >> 4, r8 = (u & 15) * 8;
            short8 o;
#pragma unroll
            for (int k = 0; k < 8; ++k) o[k] = T[(r8 + k) * 68 + c];
            *(short8*)&WvT[(size_t)(c0 + c) * DM + r0 + r8] = o;
        }
    } else {
        const int idx = blockIdx.x - 128;   // 0..63
        const int set = idx >> 5;
        const int bx = idx & 31;
        const unsigned short* W = set ? Wvb : Wkb;
        const float* bvf = biasf + 2048;
        const float* badd = set ? (biasf + 2048) : (biasf + 1024);
        float* out = set ? b2v : b2k;
        const int w = t >> 6, l = t & 63;
        const int gw = bx * 4 + w;   // 0..127
        for (int i = 0; i < 8; ++i) {
            int row = gw * 8 + i;
            const unsigned short* wr = &W[(size_t)row * DM + l * 16];
            short8 a = *(const short8*)wr;
            short8 b = *(const short8*)(wr + 8);
            float s = 0.f;
#pragma unroll
            for (int j = 0; j < 8; ++j) {
                s += b2f((unsigned short)a[j]) * bvf[l * 16 + j];
                s += b2f((unsigned short)b[j]) * bvf[l * 16 + 8 + j];
            }
#pragma unroll
            for (int m = 1; m < 64; m <<= 1) s += __shfl_xor(s, m);
            if (l == 0) out[row] = s + badd[row];
        }
    }
}

// ---------------------------------------------------------------------------
// GEMM: out[M,N] = (A[M,K] . Bt[N,K]^T + bias[N]) * scale, BK=64 (2 halves)
// mode: 0 = f32 out, 1 = bf16 out, 2 = flag ? bf16 : f32
// ---------------------------------------------------------------------------
struct GArg {
    const unsigned short* A;
    const unsigned short* Bt;
    const float* bias;
    void* out;
    float scale;
    int mode;
};

__device__ __forceinline__ int out_is_f32(int mode, const int* flag) {
    if (mode == 0) return 1;
    if (mode == 1) return 0;
    return (*flag == 0);
}

__global__ __launch_bounds__(256) void gemm_bt(GArg g0, GArg g1, GArg g2, GArg g3,
                                               const int* __restrict__ flag,
                                               int M, int N, int K)
{
    GArg ga = (blockIdx.z == 0) ? g0 : (blockIdx.z == 1) ? g1 : (blockIdx.z == 2) ? g2 : g3;
    const int m0 = blockIdx.y * 128;
    const int n0 = blockIdx.x * 128;
    __shared__ __align__(16) unsigned short As[2][128 * 32];
    __shared__ __align__(16) unsigned short Bs[2][128 * 32];
    const int t = threadIdx.x;
    const int w = t >> 6, l = t & 63;
    const int wy = w >> 1, wx = w & 1;
    const int lr = l >> 2;
    const int lk = (l & 3) * 8;
    const int ln = l & 15;
    const int lq = l >> 4;

    f32x4 acc[4][4] = {};

    const unsigned short* Ab0 = ga.A  + (size_t)(m0 + w * 32 +      lr) * K + lk;
    const unsigned short* Ab1 = ga.A  + (size_t)(m0 + w * 32 + 16 + lr) * K + lk;
    const unsigned short* Bb0 = ga.Bt + (size_t)(n0 + w * 32 +      lr) * K + lk;
    const unsigned short* Bb1 = ga.Bt + (size_t)(n0 + w * 32 + 16 + lr) * K + lk;

    for (int kk = 0; kk < K; kk += 64) {
#pragma unroll
        for (int hh = 0; hh < 2; ++hh) {
            async_ld16(Ab0 + kk + hh * 32, &As[hh][w * 1024]);
            async_ld16(Ab1 + kk + hh * 32, &As[hh][w * 1024 + 512]);
            async_ld16(Bb0 + kk + hh * 32, &Bs[hh][w * 1024]);
            async_ld16(Bb1 + kk + hh * 32, &Bs[hh][w * 1024 + 512]);
        }
        __syncthreads();
#pragma unroll
        for (int hh = 0; hh < 2; ++hh) {
            short8 af[4], bfr[4];
#pragma unroll
            for (int i = 0; i < 4; ++i)
                af[i] = *(const short8*)&As[hh][(wy * 64 + i * 16 + ln) * 32 + lq * 8];
#pragma unroll
            for (int j = 0; j < 4; ++j)
                bfr[j] = *(const short8*)&Bs[hh][(wx * 64 + j * 16 + ln) * 32 + lq * 8];
#pragma unroll
            for (int i = 0; i < 4; ++i)
#pragma unroll
                for (int j = 0; j < 4; ++j)
                    acc[i][j] = __builtin_amdgcn_mfma_f32_16x16x32_bf16(af[i], bfr[j], acc[i][j], 0, 0, 0);
        }
        __syncthreads();
    }

    const int f32o = out_is_f32(ga.mode, flag);
    const float sc = ga.scale;
#pragma unroll
    for (int j = 0; j < 4; ++j) {
        int col = n0 + wx * 64 + j * 16 + ln;
        float bv = ga.bias[col];
#pragma unroll
        for (int i = 0; i < 4; ++i) {
            int row0 = m0 + wy * 64 + i * 16 + lq * 4;
#pragma unroll
            for (int r = 0; r < 4; ++r) {
                float v = (acc[i][j][r] + bv) * sc;
                size_t idx = (size_t)(row0 + r) * N + col;
                if (f32o) ((float*)ga.out)[idx] = v;
                else      ((unsigned short*)ga.out)[idx] = f2b(v);
            }
        }
    }
}

// ---------------------------------------------------------------------------
// gemm_bt_n64: 128x64 tiles, BK=64
// ---------------------------------------------------------------------------
__global__ __launch_bounds__(256) void gemm_bt_n64(GArg g0, GArg g1,
                                                   const int* __restrict__ flag,
                                                   int M, int N, int K)
{
    GArg ga = (blockIdx.z == 0) ? g0 : g1;
    const int m0 = blockIdx.y * 128;
    const int n0 = blockIdx.x * 64;
    __shared__ __align__(16) unsigned short As[2][128 * 32];
    __shared__ __align__(16) unsigned short Bs[2][64 * 32];
    const int t = threadIdx.x;
    const int w = t >> 6, l = t & 63;
    const int wy = w >> 1, wx = w & 1;
    const int lr = l >> 2;
    const int lk = (l & 3) * 8;
    const int ln = l & 15;
    const int lq = l >> 4;

    f32x4 acc[4][2] = {};

    const unsigned short* Ab0 = ga.A  + (size_t)(m0 + w * 32 +      lr) * K + lk;
    const unsigned short* Ab1 = ga.A  + (size_t)(m0 + w * 32 + 16 + lr) * K + lk;
    const unsigned short* Bb  = ga.Bt + (size_t)(n0 + w * 16 + lr) * K + lk;

    for (int kk = 0; kk < K; kk += 64) {
#pragma unroll
        for (int hh = 0; hh < 2; ++hh) {
            async_ld16(Ab0 + kk + hh * 32, &As[hh][w * 1024]);
            async_ld16(Ab1 + kk + hh * 32, &As[hh][w * 1024 + 512]);
            async_ld16(Bb  + kk + hh * 32, &Bs[hh][w * 512]);
        }
        __syncthreads();
#pragma unroll
        for (int hh = 0; hh < 2; ++hh) {
            short8 af[4], bfr[2];
#pragma unroll
            for (int i = 0; i < 4; ++i)
                af[i] = *(const short8*)&As[hh][(wy * 64 + i * 16 + ln) * 32 + lq * 8];
#pragma unroll
            for (int j = 0; j < 2; ++j)
                bfr[j] = *(const short8*)&Bs[hh][(wx * 32 + j * 16 + ln) * 32 + lq * 8];
#pragma unroll
            for (int i = 0; i < 4; ++i)
#pragma unroll
                for (int j = 0; j < 2; ++j)
                    acc[i][j] = __builtin_amdgcn_mfma_f32_16x16x32_bf16(af[i], bfr[j], acc[i][j], 0, 0, 0);
        }
        __syncthreads();
    }

    const int f32o = out_is_f32(ga.mode, flag);
    const float sc = ga.scale;
#pragma unroll
    for (int j = 0; j < 2; ++j) {
        int col = n0 + wx * 32 + j * 16 + ln;
        float bv = ga.bias[col];
#pragma unroll
        for (int i = 0; i < 4; ++i) {
            int row0 = m0 + wy * 64 + i * 16 + lq * 4;
#pragma unroll
            for (int r = 0; r < 4; ++r) {
                float v = (acc[i][j][r] + bv) * sc;
                size_t idx = (size_t)(row0 + r) * N + col;
                if (f32o) ((float*)ga.out)[idx] = v;
                else      ((unsigned short*)ga.out)[idx] = f2b(v);
            }
        }
    }
}

// ---------------------------------------------------------------------------
// k_down: down scores -> wbuf; per-chunk max -> cmax; per-chunk exp-sum
// (vs chunk max) -> csum. Rescaled to global max later in k_wapply.
// ---------------------------------------------------------------------------
__global__ __launch_bounds__(256) void k_down(const unsigned short* __restrict__ kd,
                                              const unsigned short* __restrict__ qdw,
                                              float* __restrict__ wbuf,
                                              float* __restrict__ cmax,
                                              float* __restrict__ csum)
{
    const int bh = blockIdx.x;
    const int b = bh >> 4, h = bh & 15;
    const int chunk = blockIdx.y;
    const int s0 = chunk * TSD;
    const int t = threadIdx.x;

    __shared__ float qd[CC * DH];
    __shared__ float kt[TSD * DH];
    __shared__ float pm[CC * 8];
    __shared__ float cmf[CC];

    for (int idx = t; idx < CC * DH; idx += 256)
        qd[idx] = b2f(qdw[(idx >> 6) * DM + h * DH + (idx & 63)]);
    for (int u = t; u < TSD * DH / 8; u += 256) {
        int sl = u >> 3, d8 = (u & 7) * 8;
        short8 v = *(const short8*)&kd[(size_t)((s0 + sl) * BATCH + b) * DM + h * DH + d8];
#pragma unroll
        for (int j = 0; j < 8; ++j) kt[sl * DH + d8 + j] = b2f((unsigned short)v[j]);
    }
    __syncthreads();

    const int c = t & 31;
    float s16[16];
    float lmax = -3.4e38f;
    int it = 0;
    for (int idx = t; idx < CC * TSD; idx += 256, ++it) {
        int sl = idx >> 5;
        float s = 0.f;
#pragma unroll
        for (int d = 0; d < DH; d += 4) {
            float4 qa = *(const float4*)&qd[c * DH + d];
            float4 kb = *(const float4*)&kt[sl * DH + d];
            s += qa.x * kb.x + qa.y * kb.y + qa.z * kb.z + qa.w * kb.w;
        }
        s *= 0.125f;
        wbuf[((size_t)bh * CC + c) * S_LEN + s0 + sl] = s;
        s16[it] = s;
        lmax = fmaxf(lmax, s);
    }
    pm[c * 8 + (t >> 5)] = lmax;
    __syncthreads();
    if (t < CC) {
        float m = pm[t * 8];
#pragma unroll
        for (int g = 1; g < 8; ++g) m = fmaxf(m, pm[t * 8 + g]);
        cmf[t] = m;
        cmax[((size_t)bh * CC + t) * NCHD + chunk] = m;
    }
    __syncthreads();
    const float cm = cmf[c];
    float es = 0.f;
#pragma unroll
    for (int k = 0; k < 16; ++k) es += __expf(s16[k] - cm);
    pm[c * 8 + (t >> 5)] = es;
    __syncthreads();
    if (t < CC) {
        float ssum = pm[t * 8];
#pragma unroll
        for (int g = 1; g < 8; ++g) ssum += pm[t * 8 + g];
        csum[((size_t)bh * CC + t) * NCHD + chunk] = ssum;
    }
}

// ---------------------------------------------------------------------------
// k_wapply: w -> wb[bh][c][s], wT[bh][s][c], invn[bh][s][c] = 1/cumsum
// seg base from csum rescaled by exp(cmax-gmax).
// ---------------------------------------------------------------------------
__global__ __launch_bounds__(256) void k_wapply(const float* __restrict__ wbuf,
                                                const float* __restrict__ cmax,
                                                const float* __restrict__ csum,
                                                unsigned short* __restrict__ wb,
                                                unsigned short* __restrict__ wT,
                                                float* __restrict__ invn)
{
    const int bh = blockIdx.x, seg = blockIdx.y;
    const int t = threadIdx.x;
    __shared__ float gm[CC];
    __shared__ float basep[CC];
    __shared__ float psum[CC][9];
    __shared__ unsigned short wTt[128 * 40];
    __shared__ float invt[128 * 36];

    if (t < CC) {
        const size_t cb = (size_t)(bh * CC + t) * NCHD;
        float m = cmax[cb];
#pragma unroll
        for (int g = 1; g < NCHD; ++g) m = fmaxf(m, cmax[cb + g]);
        gm[t] = m;
        float bsum = 0.f;
        for (int k = 0; k < seg; ++k)
            bsum += csum[cb + k] * __expf(cmax[cb + k] - m);
        basep[t] = bsum;
    }
    __syncthreads();

    const int c = t >> 3, sub = t & 7;
    const float gmc = gm[c];
    const size_t rbase = (size_t)bh * 32768 + c * 1024 + seg * 128 + sub * 16;
    float w16[16];
    float s = 0.f;
#pragma unroll
    for (int i = 0; i < 16; ++i) {
        float v = __expf(wbuf[rbase + i] - gmc);
        w16[i] = v; s += v;
    }
    psum[c][sub] = s;
    short8 o0, o1;
#pragma unroll
    for (int i = 0; i < 8; ++i) { o0[i] = f2b(w16[i]); o1[i] = f2b(w16[8 + i]); }
    *(short8*)&wb[rbase] = o0;
    *(short8*)&wb[rbase + 8] = o1;
#pragma unroll
    for (int i = 0; i < 16; ++i) wTt[(sub * 16 + i) * 40 + c] = f2b(w16[i]);
    __syncthreads();

    float run = basep[c];
    for (int k = 0; k < sub; ++k) run += psum[c][k];
#pragma unroll
    for (int i = 0; i < 16; ++i) {
        run += w16[i];
        invt[(sub * 16 + i) * 36 + c] = 1.0f / fmaxf(run, 1e-30f);
    }
    __syncthreads();

    for (int u = t; u < 128 * 4; u += 256) {
        int r = u >> 2, cb = (u & 3) * 8;
        *(short8*)&wT[(size_t)bh * 32768 + (seg * 128 + r) * 32 + cb] =
            *(const short8*)&wTt[r * 40 + cb];
    }
    for (int u = t; u < 128 * 8; u += 256) {
        int r = u >> 3, cb = (u & 7) * 4;
        *(float4*)&invn[(size_t)bh * 32768 + (seg * 128 + r) * 32 + cb] =
            *(const float4*)&invt[r * 36 + cb];
    }
}

// ---------------------------------------------------------------------------
// k_state: per (bh, chunk of 64): M[c,d] = sum_s' w[c,s']*v_dk[s',d] (f32)
//          NT[d,c] = sum_s' v_dv[s',d]*w[c,s'] (f32). In-LDS transposes.
// ---------------------------------------------------------------------------
__global__ __launch_bounds__(256) void k_state(const unsigned short* __restrict__ wb,
                                               const unsigned short* __restrict__ vdk,
                                               const unsigned short* __restrict__ vdv,
                                               float* __restrict__ Mst,
                                               float* __restrict__ NTst)
{
    const int bh = blockIdx.x, ch = blockIdx.y;
    const int b = bh >> 4, h = bh & 15;
    const int s0 = ch * 64;
    const int t = threadIdx.x;
    const int w = t >> 6, l = t & 63;
    const int ln = l & 15, lq = l >> 4;
    __shared__ __align__(16) unsigned short Ws[32 * 72];
    __shared__ __align__(16) unsigned short T1[64 * 72];
    __shared__ __align__(16) unsigned short T2[64 * 72];
    __shared__ __align__(16) unsigned short KT[64 * 72];
    __shared__ __align__(16) unsigned short VT[64 * 72];

    for (int u = t; u < 32 * 8; u += 256) {
        int r = u >> 3, cb = (u & 7) * 8;
        *(short8*)&Ws[r * 72 + cb] = *(const short8*)&wb[(size_t)bh * 32768 + r * 1024 + s0 + cb];
    }
    for (int u = t; u < 64 * 8; u += 256) {
        int r = u >> 3, cb = (u & 7) * 8;
        *(short8*)&T1[r * 72 + cb] =
            *(const short8*)&vdk[(size_t)((s0 + r) * BATCH + b) * DM + h * DH + cb];
        *(short8*)&T2[r * 72 + cb] =
            *(const short8*)&vdv[(size_t)((s0 + r) * BATCH + b) * DM + h * DH + cb];
    }
    __syncthreads();
    for (int u = t; u < 64 * 8; u += 256) {
        int d = u >> 3, s8 = (u & 7) * 8;
        short8 o1, o2;
#pragma unroll
        for (int k = 0; k < 8; ++k) {
            o1[k] = T1[(s8 + k) * 72 + d];
            o2[k] = T2[(s8 + k) * 72 + d];
        }
        *(short8*)&KT[d * 72 + s8] = o1;
        *(short8*)&VT[d * 72 + s8] = o2;
    }
    __syncthreads();

    f32x4 accM[2] = {};
#pragma unroll
    for (int ks = 0; ks < 2; ++ks) {
        short8 b8 = *(const short8*)&KT[(w * 16 + ln) * 72 + ks * 32 + lq * 8];
#pragma unroll
        for (int i = 0; i < 2; ++i) {
            short8 a8 = *(const short8*)&Ws[(i * 16 + ln) * 72 + ks * 32 + lq * 8];
            accM[i] = __builtin_amdgcn_mfma_f32_16x16x32_bf16(a8, b8, accM[i], 0, 0, 0);
        }
    }
#pragma unroll
    for (int i = 0; i < 2; ++i)
#pragma unroll
        for (int r = 0; r < 4; ++r)
            Mst[((size_t)(bh * 16 + ch) * 32 + i * 16 + lq * 4 + r) * 64 + w * 16 + ln] = accM[i][r];

    f32x4 accN[2] = {};
#pragma unroll
    for (int ks = 0; ks < 2; ++ks) {
        short8 a8 = *(const short8*)&VT[(w * 16 + ln) * 72 + ks * 32 + lq * 8];
#pragma unroll
        for (int j = 0; j < 2; ++j) {
            short8 b8 = *(const short8*)&Ws[(j * 16 + ln) * 72 + ks * 32 + lq * 8];
            accN[j] = __builtin_amdgcn_mfma_f32_16x16x32_bf16(a8, b8, accN[j], 0, 0, 0);
        }
    }
#pragma unroll
    for (int j = 0; j < 2; ++j)
#pragma unroll
        for (int r = 0; r < 4; ++r)
            NTst[((size_t)(bh * 16 + ch) * 64 + w * 16 + lq * 4 + r) * 32 + j * 16 + ln] = accN[j][r];
}

// ---------------------------------------------------------------------------
// k_prefix: exclusive prefix over 16 chunks (f32) -> bf16; y: 0=M, 1=NT
// ---------------------------------------------------------------------------
__global__ __launch_bounds__(256) void k_prefix(const float* __restrict__ Mst,
                                                const float* __restrict__ NTst,
                                                unsigned short* __restrict__ Mcum,
                                                unsigned short* __restrict__ NTcum)
{
    const int bh = blockIdx.x;
    const float* src = blockIdx.y ? NTst : Mst;
    unsigned short* dst = blockIdx.y ? NTcum : Mcum;
    const int e0 = threadIdx.x * 8;
    float run[8];
#pragma unroll
    for (int j = 0; j < 8; ++j) run[j] = 0.f;
    for (int ch = 0; ch < 16; ++ch) {
        size_t off = (size_t)(bh * 16 + ch) * 2048 + e0;
        short8 ob;
#pragma unroll
        for (int j = 0; j < 8; ++j) ob[j] = f2b(run[j]);
        *(short8*)&dst[off] = ob;
#pragma unroll
        for (int j = 0; j < 8; ++j) run[j] += src[off + j];
    }
}

// ---------------------------------------------------------------------------
// k_att (chunked): per (bh, q-tile 64). Uniform work, 6 barriers/block.
// VTd built by in-LDS transpose of the vdv diag tile (staged via Gs).
// ---------------------------------------------------------------------------
__global__ __launch_bounds__(256) void k_att(
    const unsigned short* __restrict__ qu,
    const unsigned short* __restrict__ vdk,
    const unsigned short* __restrict__ wb,
    const float* __restrict__ invn,
    const unsigned short* __restrict__ wT,
    const unsigned short* __restrict__ vdv,
    const unsigned short* __restrict__ Mcum,
    const unsigned short* __restrict__ NTcum,
    unsigned short* __restrict__ attout)
{
    const int bh = blockIdx.x, b = bh >> 4, h = bh & 15;
    const int qi = blockIdx.y;
    const int s0 = qi * 64;
    const int t = threadIdx.x;
    const int w = t >> 6, l = t & 63;
    const int wy = w >> 1, wx = w & 1;
    const int ln = l & 15, lq = l >> 4;

    __shared__ __align__(16) unsigned short Qs[64 * 72];
    __shared__ __align__(16) unsigned short Gs[64 * 72];
    __shared__ __align__(16) unsigned short Kd[64 * 72];
    __shared__ __align__(16) unsigned short Wd[32 * 72];
    __shared__ __align__(16) unsigned short WTd[64 * 40];
    __shared__ __align__(16) unsigned short VTd[64 * 72];
    __shared__ __align__(16) unsigned short Mc[32 * 72];
    __shared__ __align__(16) unsigned short Nc[64 * 40];

    // P0: stage (vdv rows go into Gs temporarily)
    for (int u = t; u < 64 * 8; u += 256) {
        int r = u >> 3, cb = (u & 7) * 8;
        *(short8*)&Qs[r * 72 + cb] =
            *(const short8*)&qu[(size_t)(s0 + r) * 2048 + b * 1024 + h * 64 + cb];
        *(short8*)&Kd[r * 72 + cb] =
            *(const short8*)&vdk[(size_t)(s0 + r) * 2048 + b * 1024 + h * 64 + cb];
        *(short8*)&Gs[r * 72 + cb] =
            *(const short8*)&vdv[(size_t)(s0 + r) * 2048 + b * 1024 + h * 64 + cb];
    }
    for (int u = t; u < 32 * 8; u += 256) {
        int r = u >> 3, cb = (u & 7) * 8;
        *(short8*)&Wd[r * 72 + cb] =
            *(const short8*)&wb[(size_t)bh * 32768 + r * 1024 + s0 + cb];
        *(short8*)&Mc[r * 72 + cb] =
            *(const short8*)&Mcum[((size_t)(bh * 16 + qi) * 32 + r) * 64 + cb];
    }
    for (int u = t; u < 64 * 4; u += 256) {
        int r = u >> 2, cb = (u & 3) * 8;
        *(short8*)&WTd[r * 40 + cb] =
            *(const short8*)&wT[(size_t)bh * 32768 + (s0 + r) * 32 + cb];
        *(short8*)&Nc[r * 40 + cb] =
            *(const short8*)&NTcum[((size_t)(bh * 16 + qi) * 64 + r) * 32 + cb];
    }
    __syncthreads();

    // P1: VTd[d][s] = Gs[s][d]
    for (int u = t; u < 64 * 8; u += 256) {
        int d = u >> 3, s8 = (u & 7) * 8;
        short8 o;
#pragma unroll
        for (int k = 0; k < 8; ++k) o[k] = Gs[(s8 + k) * 72 + d];
        *(short8*)&VTd[d * 72 + s8] = o;
    }
    __syncthreads();

    // P2: G = q @ k_diag^T, causal, -> Gs
    {
        f32x4 accG[2][2] = {};
#pragma unroll
        for (int ks = 0; ks < 2; ++ks) {
            short8 a8[2], b8[2];
#pragma unroll
            for (int i = 0; i < 2; ++i)
                a8[i] = *(const short8*)&Qs[(wy * 32 + i * 16 + ln) * 72 + ks * 32 + lq * 8];
#pragma unroll
            for (int j = 0; j < 2; ++j)
                b8[j] = *(const short8*)&Kd[(wx * 32 + j * 16 + ln) * 72 + ks * 32 + lq * 8];
#pragma unroll
            for (int i = 0; i < 2; ++i)
#pragma unroll
                for (int j = 0; j < 2; ++j)
                    accG[i][j] = __builtin_amdgcn_mfma_f32_16x16x32_bf16(a8[i], b8[j], accG[i][j], 0, 0, 0);
        }
        __syncthreads();  // VTd transpose reads of Gs done before overwrite
#pragma unroll
        for (int i = 0; i < 2; ++i) {
            int row = wy * 32 + i * 16 + lq * 4;
#pragma unroll
            for (int j = 0; j < 2; ++j) {
                int col = wx * 32 + j * 16 + ln;
#pragma unroll
                for (int r = 0; r < 4; ++r) {
                    float v = accG[i][j][r];
                    if (col > row + r) v = 0.f;
                    Gs[(row + r) * 72 + col] = f2b(v);
                }
            }
        }
    }
    __syncthreads();

    // P3: up = G @ w_diag^T + q @ Mcum^T
    f32x4 accU[2] = {};
#pragma unroll
    for (int ks = 0; ks < 2; ++ks) {
        short8 ga = *(const short8*)&Gs[(w * 16 + ln) * 72 + ks * 32 + lq * 8];
        short8 qa = *(const short8*)&Qs[(w * 16 + ln) * 72 + ks * 32 + lq * 8];
#pragma unroll
        for (int j = 0; j < 2; ++j) {
            short8 wf = *(const short8*)&Wd[(j * 16 + ln) * 72 + ks * 32 + lq * 8];
            short8 mf = *(const short8*)&Mc[(j * 16 + ln) * 72 + ks * 32 + lq * 8];
            accU[j] = __builtin_amdgcn_mfma_f32_16x16x32_bf16(ga, wf, accU[j], 0, 0, 0);
            accU[j] = __builtin_amdgcn_mfma_f32_16x16x32_bf16(qa, mf, accU[j], 0, 0, 0);
        }
    }
    __syncthreads();

    // P4: softmax(up*invn) -> ptil into Qs (stride 40)
    {
        int rowl = w * 16 + lq * 4;
#pragma unroll
        for (int r = 0; r < 4; ++r) {
            int srow = s0 + rowl + r;
            float inv0 = invn[(size_t)bh * 32768 + srow * 32 + ln];
            float inv1 = invn[(size_t)bh * 32768 + srow * 32 + 16 + ln];
            float l0 = accU[0][r] * inv0;
            float l1 = accU[1][r] * inv1;
            float m = fmaxf(l0, l1);
#pragma unroll
            for (int msk = 1; msk < 16; msk <<= 1) m = fmaxf(m, __shfl_xor(m, msk));
            float e0 = __expf(l0 - m), e1 = __expf(l1 - m);
            float Z = e0 + e1;
#pragma unroll
            for (int msk = 1; msk < 16; msk <<= 1) Z += __shfl_xor(Z, msk);
            float iz = 1.0f / Z;
            Qs[(rowl + r) * 40 + ln]      = f2b(e0 * iz * inv0);
            Qs[(rowl + r) * 40 + 16 + ln] = f2b(e1 * iz * inv1);
        }
    }
    __syncthreads();

    // P5: SC = ptil @ wT_diag^T (K=32), causal, -> Gs
    short8 pa[2];
#pragma unroll
    for (int i = 0; i < 2; ++i)
        pa[i] = *(const short8*)&Qs[(wy * 32 + i * 16 + ln) * 40 + lq * 8];
    {
        f32x4 accS[2][2] = {};
        short8 b8[2];
#pragma unroll
        for (int j = 0; j < 2; ++j)
            b8[j] = *(const short8*)&WTd[(wx * 32 + j * 16 + ln) * 40 + lq * 8];
#pragma unroll
        for (int i = 0; i < 2; ++i)
#pragma unroll
            for (int j = 0; j < 2; ++j)
                accS[i][j] = __builtin_amdgcn_mfma_f32_16x16x32_bf16(pa[i], b8[j], accS[i][j], 0, 0, 0);
#pragma unroll
        for (int i = 0; i < 2; ++i) {
            int row = wy * 32 + i * 16 + lq * 4;
#pragma unroll
            for (int j = 0; j < 2; ++j) {
                int col = wx * 32 + j * 16 + ln;
#pragma unroll
                for (int r = 0; r < 4; ++r) {
                    float v = accS[i][j][r];
                    if (col > row + r) v = 0.f;
                    Gs[(row + r) * 72 + col] = f2b(v);
                }
            }
        }
    }
    __syncthreads();

    // P6: out = SC @ vT_diag^T + ptil @ NTcum^T -> attout
    {
        f32x4 accO[2][2] = {};
        short8 n8[2];
#pragma unroll
        for (int j = 0; j < 2; ++j)
            n8[j] = *(const short8*)&Nc[(wx * 32 + j * 16 + ln) * 40 + lq * 8];
#pragma unroll
        for (int i = 0; i < 2; ++i)
#pragma unroll
            for (int j = 0; j < 2; ++j)
                accO[i][j] = __builtin_amdgcn_mfma_f32_16x16x32_bf16(pa[i], n8[j], accO[i][j], 0, 0, 0);
#pragma unroll
        for (int ks = 0; ks < 2; ++ks) {
            short8 a8[2], b8[2];
#pragma unroll
            for (int i = 0; i < 2; ++i)
                a8[i] = *(const short8*)&Gs[(wy * 32 + i * 16 + ln) * 72 + ks * 32 + lq * 8];
#pragma unroll
            for (int j = 0; j < 2; ++j)
                b8[j] = *(const short8*)&VTd[(wx * 32 + j * 16 + ln) * 72 + ks * 32 + lq * 8];
#pragma unroll
            for (int i = 0; i < 2; ++i)
#pragma unroll
                for (int j = 0; j < 2; ++j)
                    accO[i][j] = __builtin_amdgcn_mfma_f32_16x16x32_bf16(a8[i], b8[j], accO[i][j], 0, 0, 0);
        }
#pragma unroll
        for (int i = 0; i < 2; ++i) {
            int rowb = s0 + wy * 32 + i * 16 + lq * 4;
#pragma unroll
            for (int j = 0; j < 2; ++j) {
                int d = wx * 32 + j * 16 + ln;
#pragma unroll
                for (int r = 0; r < 4; ++r)
                    attout[(size_t)(rowb + r) * 2048 + b * 1024 + h * 64 + d] = f2b(accO[i][j][r]);
            }
        }
    }
}

// ---------------------------------------------------------------------------
extern "C" void kernel_launch(void* const* d_in, const int* in_sizes, int n_in,
                              void* d_out, int out_size, void* d_ws, size_t ws_size,
                              hipStream_t stream)
{
    (void)in_sizes; (void)n_in; (void)out_size; (void)ws_size;
    char* ws = (char*)d_ws;
    const size_t MB = (size_t)1 << 20;
    const size_t KB = (size_t)1 << 10;
    unsigned short* attout = (unsigned short*)(ws + 0 * MB);   // 4 MB
    unsigned short* q_u    = (unsigned short*)(ws + 4 * MB);   // 4 MB (pre-scaled)
    unsigned short* k_d    = (unsigned short*)(ws + 8 * MB);   // 4 MB
    unsigned short* v_dk   = (unsigned short*)(ws + 12 * MB);  // 4 MB
    unsigned short* v_dv   = (unsigned short*)(ws + 16 * MB);  // 4 MB
    float* wbuf = (float*)(ws + 20 * MB);                      // 4 MB (down scores)
    unsigned short* wb  = (unsigned short*)(ws + 24 * MB);     // 2 MB [bh][c][s]
    unsigned short* wT  = (unsigned short*)(ws + 26 * MB);     // 2 MB [bh][s][c]
    float* invn = (float*)(ws + 28 * MB);                      // 4 MB [bh][s][c]
    float* Mst  = (float*)(ws + 32 * MB);                      // 4 MB
    float* NTst = (float*)(ws + 36 * MB);                      // 4 MB
    unsigned short* Mcum  = (unsigned short*)(ws + 40 * MB);   // 2 MB
    unsigned short* NTcum = (unsigned short*)(ws + 42 * MB);   // 2 MB
    unsigned short* xb  = (unsigned short*)(ws + 44 * MB);     // 4 MB
    unsigned short* Wqb = (unsigned short*)(ws + 48 * MB);     // 2 MB
    unsigned short* Wkb = (unsigned short*)(ws + 50 * MB);     // 2 MB
    unsigned short* Wvb = (unsigned short*)(ws + 52 * MB);     // 2 MB
    unsigned short* Wob = (unsigned short*)(ws + 54 * MB);     // 2 MB
    unsigned short* WvT = (unsigned short*)(ws + 56 * MB);     // 2 MB
    unsigned short* W2k = (unsigned short*)(ws + 58 * MB);     // 2 MB (Wk·Wv)
    unsigned short* W2v = (unsigned short*)(ws + 60 * MB);     // 2 MB (Wv·Wv)
    unsigned short* qdb = (unsigned short*)(ws + 62 * MB);     // 64 KB
    float* biasf  = (float*)(ws + 62 * MB + 64 * KB);          // 20 KB [bq,bk,bv,bo,zero]
    float* b2k    = (float*)(ws + 62 * MB + 128 * KB);         // 4 KB
    float* b2v    = (float*)(ws + 62 * MB + 132 * KB);         // 4 KB
    float* cmax   = (float*)(ws + 62 * MB + 192 * KB);         // 32 KB
    float* csum   = (float*)(ws + 62 * MB + 256 * KB);         // 32 KB
    int*   flag   = (int*)  (ws + 62 * MB + 320 * KB);

    // convert (inline sniff)
    k_convert<<<1024, 256, 0, stream>>>(
        d_in[0], d_in[1], d_in[2], d_in[4], d_in[6], d_in[8],
        d_in[3], d_in[5], d_in[7], d_in[9],
        flag, xb, qdb, Wqb, Wkb, Wvb, Wob, biasf);

    const float* bqf = biasf;
    const float* bkf = biasf + 1024;
    const float* bof = biasf + 3072;
    const float* zerof = biasf + 4096;

    // weight prep: WvT + combined biases (one launch), then W2k/W2v
    k_prep<<<192, 256, 0, stream>>>(Wvb, Wkb, biasf, WvT, b2k, b2v);
    GArg wpk{ Wkb, WvT, zerof, (void*)W2k, 1.0f, 1 };
    GArg wpv{ Wvb, WvT, zerof, (void*)W2v, 1.0f, 1 };
    gemm_bt_n64<<<dim3(16, 8, 2), 256, 0, stream>>>(wpk, wpv, flag, DM, DM, DM);

    // main projections: q_u (scaled), k_d, v_dk, v_dv in ONE launch (512 blocks)
    GArg gq { xb, Wqb, bqf, (void*)q_u, 0.125f, 1 };
    GArg gk { xb, Wkb, bkf, (void*)k_d, 1.0f, 1 };
    GArg gvk{ xb, W2k, b2k, (void*)v_dk, 1.0f, 1 };
    GArg gvv{ xb, W2v, b2v, (void*)v_dv, 1.0f, 1 };
    gemm_bt<<<dim3(8, 16, 4), 256, 0, stream>>>(gq, gk, gvk, gvv, flag, SB, DM, DM);

    // attention mid-section
    k_down<<<dim3(32, NCHD), 256, 0, stream>>>(k_d, qdb, wbuf, cmax, csum);
    k_wapply<<<dim3(32, 8), 256, 0, stream>>>(wbuf, cmax, csum, wb, wT, invn);
    k_state<<<dim3(32, 16), 256, 0, stream>>>(wb, v_dk, v_dv, Mst, NTst);
    k_prefix<<<dim3(32, 2), 256, 0, stream>>>(Mst, NTst, Mcum, NTcum);
    k_att<<<dim3(32, 16), 256, 0, stream>>>(q_u, v_dk, wb, invn, wT, v_dv, Mcum, NTcum, attout);

    // final projection (256 blocks): out dtype follows sniffed input dtype
    GArg go{ attout, Wob, bof, d_out, 1.0f, 2 };
    gemm_bt_n64<<<dim3(16, 16, 1), 256, 0, stream>>>(go, go, flag, SB, DM, DM);
}

// Round 9
// 188.934 us; speedup vs baseline: 1.5988x; 1.0472x over previous
//
#include <hip/hip_runtime.h>
#include <cstdint>
#include <cstddef>

// Problem constants
#define S_LEN 1024
#define BATCH 2
#define DM    1024
#define NH    16
#define DH    64
#define CC    32     // compressed length
#define SB    2048   // S*B rows
#define TSD   128
#define NCHD  8

using short8 = __attribute__((ext_vector_type(8))) short;
using f32x4  = __attribute__((ext_vector_type(4))) float;

__device__ __forceinline__ float b2f(unsigned short u) {
    union { unsigned int i; float f; } v; v.i = ((unsigned int)u) << 16; return v.f;
}
__device__ __forceinline__ unsigned short f2b(float f) {
    union { float f; unsigned int i; } v; v.f = f;
    unsigned int x = v.i;
    unsigned int r = x + 0x7FFFu + ((x >> 16) & 1u);
    return (unsigned short)(r >> 16);
}

__device__ __forceinline__ void async_ld16(const unsigned short* g, unsigned short* l) {
    __builtin_amdgcn_global_load_lds(
        (const __attribute__((address_space(1))) unsigned int*)g,
        (__attribute__((address_space(3))) unsigned int*)l,
        16, 0, 0);
}

// ---------------------------------------------------------------------------
// k_convert: inline dtype sniff. If inputs are bf16, ONLY biases are
// converted (consumers use raw d_in pointers). If fp32, full conversion.
// ---------------------------------------------------------------------------
__global__ __launch_bounds__(256) void k_convert(
    const void* x, const void* qd,
    const void* wq, const void* wk, const void* wv, const void* wo,
    const void* bq, const void* bk, const void* bv, const void* bo,
    int* __restrict__ flag,
    unsigned short* xb, unsigned short* qdb,
    unsigned short* Wqb, unsigned short* Wkb, unsigned short* Wvb, unsigned short* Wob,
    float* biasf)
{
    __shared__ int cnt;
    if (threadIdx.x == 0) cnt = 0;
    __syncthreads();
    {
        const unsigned short* xs = (const unsigned short*)x;
        int local = 0;
        for (int i = threadIdx.x; i < 1024; i += 256) {
            unsigned e = (xs[i * 2] >> 7) & 0xFF;
            if (e >= 90 && e <= 160) local++;
        }
        atomicAdd(&cnt, local);
    }
    __syncthreads();
    const int isbf = (cnt >= 640);
    if (blockIdx.x == 0 && threadIdx.x == 0) *flag = isbf;

    const size_t tid = (size_t)blockIdx.x * 256 + threadIdx.x;
    const size_t stride = (size_t)gridDim.x * 256;

    if (!isbf) {
        auto cv = [&](const void* src, unsigned short* dst, size_t n) {
            const float4* s = (const float4*)src;
            for (size_t i = tid; i < n / 4; i += stride) {
                float4 v = s[i];
                ushort4 o;
                o.x = f2b(v.x); o.y = f2b(v.y); o.z = f2b(v.z); o.w = f2b(v.w);
                ((ushort4*)dst)[i] = o;
            }
        };
        cv(x,  xb,  (size_t)SB * DM);
        cv(qd, qdb, (size_t)CC * DM);
        cv(wq, Wqb, (size_t)DM * DM);
        cv(wk, Wkb, (size_t)DM * DM);
        cv(wv, Wvb, (size_t)DM * DM);
        cv(wo, Wob, (size_t)DM * DM);
    }
    for (size_t i = tid; i < 5 * DM; i += stride) {
        int w = (int)(i >> 10), o = (int)(i & 1023);
        float val;
        if (w == 4) val = 0.f;
        else {
            const void* bp = (w == 0) ? bq : ((w == 1) ? bk : ((w == 2) ? bv : bo));
            val = isbf ? b2f(((const unsigned short*)bp)[o]) : ((const float*)bp)[o];
        }
        biasf[i] = val;
    }
}

// ---------------------------------------------------------------------------
// k_prep: blocks 0..127 -> WvT transpose tiles; 128..191 -> combined biases
// ---------------------------------------------------------------------------
__global__ __launch_bounds__(256) void k_prep(const unsigned short* __restrict__ Wv0,
                                              const unsigned short* __restrict__ Wv1,
                                              const unsigned short* __restrict__ Wk0,
                                              const unsigned short* __restrict__ Wk1,
                                              const int* __restrict__ flag,
                                              const float* __restrict__ biasf,
                                              unsigned short* __restrict__ WvT,
                                              float* __restrict__ b2k,
                                              float* __restrict__ b2v)
{
    const int isbf = *flag;
    const unsigned short* Wvb = isbf ? Wv1 : Wv0;
    const unsigned short* Wkb = isbf ? Wk1 : Wk0;
    const int t = threadIdx.x;
    if (blockIdx.x < 128) {
        const int r0 = (blockIdx.x & 7) * 128;
        const int c0 = (blockIdx.x >> 3) * 64;
        __shared__ unsigned short T[128 * 68];
        for (int u = t; u < 128 * 8; u += 256) {
            int r = u >> 3, cb = (u & 7) * 8;
            *(short8*)&T[r * 68 + cb] = *(const short8*)&Wvb[(size_t)(r0 + r) * DM + c0 + cb];
        }
        __syncthreads();
        for (int u = t; u < 64 * 16; u += 256) {
            int c = u >> 4, r8 = (u & 15) * 8;
            short8 o;
#pragma unroll
            for (int k = 0; k < 8; ++k) o[k] = T[(r8 + k) * 68 + c];
            *(short8*)&WvT[(size_t)(c0 + c) * DM + r0 + r8] = o;
        }
    } else {
        const int idx = blockIdx.x - 128;   // 0..63
        const int set = idx >> 5;
        const int bx = idx & 31;
        const unsigned short* W = set ? Wvb : Wkb;
        const float* bvf = biasf + 2048;
        const float* badd = set ? (biasf + 2048) : (biasf + 1024);
        float* out = set ? b2v : b2k;
        const int w = t >> 6, l = t & 63;
        const int gw = bx * 4 + w;   // 0..127
        for (int i = 0; i < 8; ++i) {
            int row = gw * 8 + i;
            const unsigned short* wr = &W[(size_t)row * DM + l * 16];
            short8 a = *(const short8*)wr;
            short8 b = *(const short8*)(wr + 8);
            float s = 0.f;
#pragma unroll
            for (int j = 0; j < 8; ++j) {
                s += b2f((unsigned short)a[j]) * bvf[l * 16 + j];
                s += b2f((unsigned short)b[j]) * bvf[l * 16 + 8 + j];
            }
#pragma unroll
            for (int m = 1; m < 64; m <<= 1) s += __shfl_xor(s, m);
            if (l == 0) out[row] = s + badd[row];
        }
    }
}

// ---------------------------------------------------------------------------
// GEMM: out[M,N] = (A[M,K] . Bt[N,K]^T + bias[N]) * scale, BK=64.
// A/Bt have converted (0) and raw (1) variants selected by *flag.
// mode: 0 = f32 out, 1 = bf16 out, 2 = flag ? bf16 : f32
// ---------------------------------------------------------------------------
struct GArg {
    const unsigned short* A0;
    const unsigned short* A1;
    const unsigned short* B0;
    const unsigned short* B1;
    const float* bias;
    void* out;
    float scale;
    int mode;
};

__global__ __launch_bounds__(256) void gemm_bt(GArg g0, GArg g1, GArg g2, GArg g3,
                                               const int* __restrict__ flag,
                                               int M, int N, int K)
{
    GArg ga = (blockIdx.z == 0) ? g0 : (blockIdx.z == 1) ? g1 : (blockIdx.z == 2) ? g2 : g3;
    const int isbf = *flag;
    const unsigned short* Ap = isbf ? ga.A1 : ga.A0;
    const unsigned short* Bp = isbf ? ga.B1 : ga.B0;
    const int m0 = blockIdx.y * 128;
    const int n0 = blockIdx.x * 128;
    __shared__ __align__(16) unsigned short As[2][128 * 32];
    __shared__ __align__(16) unsigned short Bs[2][128 * 32];
    const int t = threadIdx.x;
    const int w = t >> 6, l = t & 63;
    const int wy = w >> 1, wx = w & 1;
    const int lr = l >> 2;
    const int lk = (l & 3) * 8;
    const int ln = l & 15;
    const int lq = l >> 4;

    f32x4 acc[4][4] = {};

    const unsigned short* Ab0 = Ap + (size_t)(m0 + w * 32 +      lr) * K + lk;
    const unsigned short* Ab1 = Ap + (size_t)(m0 + w * 32 + 16 + lr) * K + lk;
    const unsigned short* Bb0 = Bp + (size_t)(n0 + w * 32 +      lr) * K + lk;
    const unsigned short* Bb1 = Bp + (size_t)(n0 + w * 32 + 16 + lr) * K + lk;

    for (int kk = 0; kk < K; kk += 64) {
#pragma unroll
        for (int hh = 0; hh < 2; ++hh) {
            async_ld16(Ab0 + kk + hh * 32, &As[hh][w * 1024]);
            async_ld16(Ab1 + kk + hh * 32, &As[hh][w * 1024 + 512]);
            async_ld16(Bb0 + kk + hh * 32, &Bs[hh][w * 1024]);
            async_ld16(Bb1 + kk + hh * 32, &Bs[hh][w * 1024 + 512]);
        }
        __syncthreads();
#pragma unroll
        for (int hh = 0; hh < 2; ++hh) {
            short8 af[4], bfr[4];
#pragma unroll
            for (int i = 0; i < 4; ++i)
                af[i] = *(const short8*)&As[hh][(wy * 64 + i * 16 + ln) * 32 + lq * 8];
#pragma unroll
            for (int j = 0; j < 4; ++j)
                bfr[j] = *(const short8*)&Bs[hh][(wx * 64 + j * 16 + ln) * 32 + lq * 8];
#pragma unroll
            for (int i = 0; i < 4; ++i)
#pragma unroll
                for (int j = 0; j < 4; ++j)
                    acc[i][j] = __builtin_amdgcn_mfma_f32_16x16x32_bf16(af[i], bfr[j], acc[i][j], 0, 0, 0);
        }
        __syncthreads();
    }

    const int f32o = (ga.mode == 0) ? 1 : (ga.mode == 1) ? 0 : (!isbf);
    const float sc = ga.scale;
#pragma unroll
    for (int j = 0; j < 4; ++j) {
        int col = n0 + wx * 64 + j * 16 + ln;
        float bv = ga.bias[col];
#pragma unroll
        for (int i = 0; i < 4; ++i) {
            int row0 = m0 + wy * 64 + i * 16 + lq * 4;
#pragma unroll
            for (int r = 0; r < 4; ++r) {
                float v = (acc[i][j][r] + bv) * sc;
                size_t idx = (size_t)(row0 + r) * N + col;
                if (f32o) ((float*)ga.out)[idx] = v;
                else      ((unsigned short*)ga.out)[idx] = f2b(v);
            }
        }
    }
}

// ---------------------------------------------------------------------------
// gemm_bt_n64: 128x64 tiles, BK=64
// ---------------------------------------------------------------------------
__global__ __launch_bounds__(256) void gemm_bt_n64(GArg g0, GArg g1,
                                                   const int* __restrict__ flag,
                                                   int M, int N, int K)
{
    GArg ga = (blockIdx.z == 0) ? g0 : g1;
    const int isbf = *flag;
    const unsigned short* Ap = isbf ? ga.A1 : ga.A0;
    const unsigned short* Bp = isbf ? ga.B1 : ga.B0;
    const int m0 = blockIdx.y * 128;
    const int n0 = blockIdx.x * 64;
    __shared__ __align__(16) unsigned short As[2][128 * 32];
    __shared__ __align__(16) unsigned short Bs[2][64 * 32];
    const int t = threadIdx.x;
    const int w = t >> 6, l = t & 63;
    const int wy = w >> 1, wx = w & 1;
    const int lr = l >> 2;
    const int lk = (l & 3) * 8;
    const int ln = l & 15;
    const int lq = l >> 4;

    f32x4 acc[4][2] = {};

    const unsigned short* Ab0 = Ap + (size_t)(m0 + w * 32 +      lr) * K + lk;
    const unsigned short* Ab1 = Ap + (size_t)(m0 + w * 32 + 16 + lr) * K + lk;
    const unsigned short* Bb  = Bp + (size_t)(n0 + w * 16 + lr) * K + lk;

    for (int kk = 0; kk < K; kk += 64) {
#pragma unroll
        for (int hh = 0; hh < 2; ++hh) {
            async_ld16(Ab0 + kk + hh * 32, &As[hh][w * 1024]);
            async_ld16(Ab1 + kk + hh * 32, &As[hh][w * 1024 + 512]);
            async_ld16(Bb  + kk + hh * 32, &Bs[hh][w * 512]);
        }
        __syncthreads();
#pragma unroll
        for (int hh = 0; hh < 2; ++hh) {
            short8 af[4], bfr[2];
#pragma unroll
            for (int i = 0; i < 4; ++i)
                af[i] = *(const short8*)&As[hh][(wy * 64 + i * 16 + ln) * 32 + lq * 8];
#pragma unroll
            for (int j = 0; j < 2; ++j)
                bfr[j] = *(const short8*)&Bs[hh][(wx * 32 + j * 16 + ln) * 32 + lq * 8];
#pragma unroll
            for (int i = 0; i < 4; ++i)
#pragma unroll
                for (int j = 0; j < 2; ++j)
                    acc[i][j] = __builtin_amdgcn_mfma_f32_16x16x32_bf16(af[i], bfr[j], acc[i][j], 0, 0, 0);
        }
        __syncthreads();
    }

    const int f32o = (ga.mode == 0) ? 1 : (ga.mode == 1) ? 0 : (!isbf);
    const float sc = ga.scale;
#pragma unroll
    for (int j = 0; j < 2; ++j) {
        int col = n0 + wx * 32 + j * 16 + ln;
        float bv = ga.bias[col];
#pragma unroll
        for (int i = 0; i < 4; ++i) {
            int row0 = m0 + wy * 64 + i * 16 + lq * 4;
#pragma unroll
            for (int r = 0; r < 4; ++r) {
                float v = (acc[i][j][r] + bv) * sc;
                size_t idx = (size_t)(row0 + r) * N + col;
                if (f32o) ((float*)ga.out)[idx] = v;
                else      ((unsigned short*)ga.out)[idx] = f2b(v);
            }
        }
    }
}

// ---------------------------------------------------------------------------
// k_down (MFMA): per (bh, chunk of 128): scores = 0.125 * q_down @ k_d^T via
// 16x16x32 MFMA -> LDS + wbuf; per-chunk max -> cmax; exp-sum vs cmax -> csum
// ---------------------------------------------------------------------------
__global__ __launch_bounds__(256) void k_down(const unsigned short* __restrict__ kd,
                                              const unsigned short* __restrict__ qd0,
                                              const unsigned short* __restrict__ qd1,
                                              const int* __restrict__ flag,
                                              float* __restrict__ wbuf,
                                              float* __restrict__ cmax,
                                              float* __restrict__ csum)
{
    const unsigned short* qdw = (*flag) ? qd1 : qd0;
    const int bh = blockIdx.x;
    const int b = bh >> 4, h = bh & 15;
    const int chunk = blockIdx.y;
    const int s0 = chunk * TSD;
    const int t = threadIdx.x;
    const int w = t >> 6, l = t & 63;
    const int ln = l & 15, lq = l >> 4;

    __shared__ __align__(16) unsigned short QD[32 * 72];   // [c][d]
    __shared__ __align__(16) unsigned short KT[128 * 72];  // [sl][d]
    __shared__ float SS[32 * 132];                         // [c][sl]
    __shared__ float pm[256];
    __shared__ float cmf[CC];

    {
        int r = t >> 3, cb = (t & 7) * 8;   // 256 threads exactly cover 32x64
        *(short8*)&QD[r * 72 + cb] = *(const short8*)&qdw[(size_t)r * DM + h * DH + cb];
    }
    for (int u = t; u < 128 * 8; u += 256) {
        int r = u >> 3, cb = (u & 7) * 8;
        *(short8*)&KT[r * 72 + cb] =
            *(const short8*)&kd[(size_t)((s0 + r) * BATCH + b) * DM + h * DH + cb];
    }
    __syncthreads();

    // scores: wave w covers sl = w*32..+32; accG[i][j]: c-tile i, sl-tile j
    f32x4 accG[2][2] = {};
#pragma unroll
    for (int ks = 0; ks < 2; ++ks) {
        short8 a8[2], b8[2];
#pragma unroll
        for (int i = 0; i < 2; ++i)
            a8[i] = *(const short8*)&QD[(i * 16 + ln) * 72 + ks * 32 + lq * 8];
#pragma unroll
        for (int j = 0; j < 2; ++j)
            b8[j] = *(const short8*)&KT[(w * 32 + j * 16 + ln) * 72 + ks * 32 + lq * 8];
#pragma unroll
        for (int i = 0; i < 2; ++i)
#pragma unroll
            for (int j = 0; j < 2; ++j)
                accG[i][j] = __builtin_amdgcn_mfma_f32_16x16x32_bf16(a8[i], b8[j], accG[i][j], 0, 0, 0);
    }
#pragma unroll
    for (int i = 0; i < 2; ++i) {
#pragma unroll
        for (int j = 0; j < 2; ++j) {
            int sl = w * 32 + j * 16 + ln;
#pragma unroll
            for (int r = 0; r < 4; ++r) {
                int c = i * 16 + lq * 4 + r;
                float v = accG[i][j][r] * 0.125f;
                SS[c * 132 + sl] = v;
                wbuf[((size_t)bh * CC + c) * S_LEN + s0 + sl] = v;
            }
        }
    }
    __syncthreads();

    // reductions: thread (c = t>>3, sub = t&7) owns sl = sub*16..+16
    const int c = t >> 3, sub = t & 7;
    float lmax = -3.4e38f;
#pragma unroll
    for (int k = 0; k < 16; ++k) lmax = fmaxf(lmax, SS[c * 132 + sub * 16 + k]);
    lmax = fmaxf(lmax, __shfl_xor(lmax, 1));
    lmax = fmaxf(lmax, __shfl_xor(lmax, 2));
    lmax = fmaxf(lmax, __shfl_xor(lmax, 4));
    if (sub == 0) {
        cmf[c] = lmax;
        cmax[((size_t)bh * CC + c) * NCHD + chunk] = lmax;
    }
    __syncthreads();
    const float cm = cmf[c];
    float es = 0.f;
#pragma unroll
    for (int k = 0; k < 16; ++k) es += __expf(SS[c * 132 + sub * 16 + k] - cm);
    es += __shfl_xor(es, 1);
    es += __shfl_xor(es, 2);
    es += __shfl_xor(es, 4);
    if (sub == 0) csum[((size_t)bh * CC + c) * NCHD + chunk] = es;
}

// ---------------------------------------------------------------------------
// k_wapply: w -> wb[bh][c][s], wT[bh][s][c], invn[bh][s][c] = 1/cumsum
// ---------------------------------------------------------------------------
__global__ __launch_bounds__(256) void k_wapply(const float* __restrict__ wbuf,
                                                const float* __restrict__ cmax,
                                                const float* __restrict__ csum,
                                                unsigned short* __restrict__ wb,
                                                unsigned short* __restrict__ wT,
                                                float* __restrict__ invn)
{
    const int bh = blockIdx.x, seg = blockIdx.y;
    const int t = threadIdx.x;
    __shared__ float gm[CC];
    __shared__ float basep[CC];
    __shared__ float psum[CC][9];
    __shared__ unsigned short wTt[128 * 40];
    __shared__ float invt[128 * 36];

    if (t < CC) {
        const size_t cb = (size_t)(bh * CC + t) * NCHD;
        float m = cmax[cb];
#pragma unroll
        for (int g = 1; g < NCHD; ++g) m = fmaxf(m, cmax[cb + g]);
        gm[t] = m;
        float bsum = 0.f;
        for (int k = 0; k < seg; ++k)
            bsum += csum[cb + k] * __expf(cmax[cb + k] - m);
        basep[t] = bsum;
    }
    __syncthreads();

    const int c = t >> 3, sub = t & 7;
    const float gmc = gm[c];
    const size_t rbase = (size_t)bh * 32768 + c * 1024 + seg * 128 + sub * 16;
    float w16[16];
    float s = 0.f;
#pragma unroll
    for (int i = 0; i < 16; ++i) {
        float v = __expf(wbuf[rbase + i] - gmc);
        w16[i] = v; s += v;
    }
    psum[c][sub] = s;
    short8 o0, o1;
#pragma unroll
    for (int i = 0; i < 8; ++i) { o0[i] = f2b(w16[i]); o1[i] = f2b(w16[8 + i]); }
    *(short8*)&wb[rbase] = o0;
    *(short8*)&wb[rbase + 8] = o1;
#pragma unroll
    for (int i = 0; i < 16; ++i) wTt[(sub * 16 + i) * 40 + c] = f2b(w16[i]);
    __syncthreads();

    float run = basep[c];
    for (int k = 0; k < sub; ++k) run += psum[c][k];
#pragma unroll
    for (int i = 0; i < 16; ++i) {
        run += w16[i];
        invt[(sub * 16 + i) * 36 + c] = 1.0f / fmaxf(run, 1e-30f);
    }
    __syncthreads();

    for (int u = t; u < 128 * 4; u += 256) {
        int r = u >> 2, cb = (u & 3) * 8;
        *(short8*)&wT[(size_t)bh * 32768 + (seg * 128 + r) * 32 + cb] =
            *(const short8*)&wTt[r * 40 + cb];
    }
    for (int u = t; u < 128 * 8; u += 256) {
        int r = u >> 3, cb = (u & 7) * 4;
        *(float4*)&invn[(size_t)bh * 32768 + (seg * 128 + r) * 32 + cb] =
            *(const float4*)&invt[r * 36 + cb];
    }
}

// ---------------------------------------------------------------------------
// k_state: per (bh, chunk of 64): M[c,d] = sum_s' w[c,s']*v_dk[s',d] (f32)
//          NT[d,c] = sum_s' v_dv[s',d]*w[c,s'] (f32). In-LDS transposes.
// ---------------------------------------------------------------------------
__global__ __launch_bounds__(256) void k_state(const unsigned short* __restrict__ wb,
                                               const unsigned short* __restrict__ vdk,
                                               const unsigned short* __restrict__ vdv,
                                               float* __restrict__ Mst,
                                               float* __restrict__ NTst)
{
    const int bh = blockIdx.x, ch = blockIdx.y;
    const int b = bh >> 4, h = bh & 15;
    const int s0 = ch * 64;
    const int t = threadIdx.x;
    const int w = t >> 6, l = t & 63;
    const int ln = l & 15, lq = l >> 4;
    __shared__ __align__(16) unsigned short Ws[32 * 72];
    __shared__ __align__(16) unsigned short T1[64 * 72];
    __shared__ __align__(16) unsigned short T2[64 * 72];
    __shared__ __align__(16) unsigned short KT[64 * 72];
    __shared__ __align__(16) unsigned short VT[64 * 72];

    for (int u = t; u < 32 * 8; u += 256) {
        int r = u >> 3, cb = (u & 7) * 8;
        *(short8*)&Ws[r * 72 + cb] = *(const short8*)&wb[(size_t)bh * 32768 + r * 1024 + s0 + cb];
    }
    for (int u = t; u < 64 * 8; u += 256) {
        int r = u >> 3, cb = (u & 7) * 8;
        *(short8*)&T1[r * 72 + cb] =
            *(const short8*)&vdk[(size_t)((s0 + r) * BATCH + b) * DM + h * DH + cb];
        *(short8*)&T2[r * 72 + cb] =
            *(const short8*)&vdv[(size_t)((s0 + r) * BATCH + b) * DM + h * DH + cb];
    }
    __syncthreads();
    for (int u = t; u < 64 * 8; u += 256) {
        int d = u >> 3, s8 = (u & 7) * 8;
        short8 o1, o2;
#pragma unroll
        for (int k = 0; k < 8; ++k) {
            o1[k] = T1[(s8 + k) * 72 + d];
            o2[k] = T2[(s8 + k) * 72 + d];
        }
        *(short8*)&KT[d * 72 + s8] = o1;
        *(short8*)&VT[d * 72 + s8] = o2;
    }
    __syncthreads();

    f32x4 accM[2] = {};
#pragma unroll
    for (int ks = 0; ks < 2; ++ks) {
        short8 b8 = *(const short8*)&KT[(w * 16 + ln) * 72 + ks * 32 + lq * 8];
#pragma unroll
        for (int i = 0; i < 2; ++i) {
            short8 a8 = *(const short8*)&Ws[(i * 16 + ln) * 72 + ks * 32 + lq * 8];
            accM[i] = __builtin_amdgcn_mfma_f32_16x16x32_bf16(a8, b8, accM[i], 0, 0, 0);
        }
    }
#pragma unroll
    for (int i = 0; i < 2; ++i)
#pragma unroll
        for (int r = 0; r < 4; ++r)
            Mst[((size_t)(bh * 16 + ch) * 32 + i * 16 + lq * 4 + r) * 64 + w * 16 + ln] = accM[i][r];

    f32x4 accN[2] = {};
#pragma unroll
    for (int ks = 0; ks < 2; ++ks) {
        short8 a8 = *(const short8*)&VT[(w * 16 + ln) * 72 + ks * 32 + lq * 8];
#pragma unroll
        for (int j = 0; j < 2; ++j) {
            short8 b8 = *(const short8*)&Ws[(j * 16 + ln) * 72 + ks * 32 + lq * 8];
            accN[j] = __builtin_amdgcn_mfma_f32_16x16x32_bf16(a8, b8, accN[j], 0, 0, 0);
        }
    }
#pragma unroll
    for (int j = 0; j < 2; ++j)
#pragma unroll
        for (int r = 0; r < 4; ++r)
            NTst[((size_t)(bh * 16 + ch) * 64 + w * 16 + lq * 4 + r) * 32 + j * 16 + ln] = accN[j][r];
}

// ---------------------------------------------------------------------------
// k_prefix: exclusive prefix over 16 chunks (f32) -> bf16; y: 0=M, 1=NT
// ---------------------------------------------------------------------------
__global__ __launch_bounds__(256) void k_prefix(const float* __restrict__ Mst,
                                                const float* __restrict__ NTst,
                                                unsigned short* __restrict__ Mcum,
                                                unsigned short* __restrict__ NTcum)
{
    const int bh = blockIdx.x;
    const float* src = blockIdx.y ? NTst : Mst;
    unsigned short* dst = blockIdx.y ? NTcum : Mcum;
    const int e0 = threadIdx.x * 8;
    float run[8];
#pragma unroll
    for (int j = 0; j < 8; ++j) run[j] = 0.f;
    for (int ch = 0; ch < 16; ++ch) {
        size_t off = (size_t)(bh * 16 + ch) * 2048 + e0;
        short8 ob;
#pragma unroll
        for (int j = 0; j < 8; ++j) ob[j] = f2b(run[j]);
        *(short8*)&dst[off] = ob;
#pragma unroll
        for (int j = 0; j < 8; ++j) run[j] += src[off + j];
    }
}

// ---------------------------------------------------------------------------
// k_att (chunked): per (bh, q-tile 64). Uniform work, 7 barriers/block.
// ---------------------------------------------------------------------------
__global__ __launch_bounds__(256) void k_att(
    const unsigned short* __restrict__ qu,
    const unsigned short* __restrict__ vdk,
    const unsigned short* __restrict__ wb,
    const float* __restrict__ invn,
    const unsigned short* __restrict__ wT,
    const unsigned short* __restrict__ vdv,
    const unsigned short* __restrict__ Mcum,
    const unsigned short* __restrict__ NTcum,
    unsigned short* __restrict__ attout)
{
    const int bh = blockIdx.x, b = bh >> 4, h = bh & 15;
    const int qi = blockIdx.y;
    const int s0 = qi * 64;
    const int t = threadIdx.x;
    const int w = t >> 6, l = t & 63;
    const int wy = w >> 1, wx = w & 1;
    const int ln = l & 15, lq = l >> 4;

    __shared__ __align__(16) unsigned short Qs[64 * 72];
    __shared__ __align__(16) unsigned short Gs[64 * 72];
    __shared__ __align__(16) unsigned short Kd[64 * 72];
    __shared__ __align__(16) unsigned short Wd[32 * 72];
    __shared__ __align__(16) unsigned short WTd[64 * 40];
    __shared__ __align__(16) unsigned short VTd[64 * 72];
    __shared__ __align__(16) unsigned short Mc[32 * 72];
    __shared__ __align__(16) unsigned short Nc[64 * 40];

    // P0: stage (vdv rows go into Gs temporarily)
    for (int u = t; u < 64 * 8; u += 256) {
        int r = u >> 3, cb = (u & 7) * 8;
        *(short8*)&Qs[r * 72 + cb] =
            *(const short8*)&qu[(size_t)(s0 + r) * 2048 + b * 1024 + h * 64 + cb];
        *(short8*)&Kd[r * 72 + cb] =
            *(const short8*)&vdk[(size_t)(s0 + r) * 2048 + b * 1024 + h * 64 + cb];
        *(short8*)&Gs[r * 72 + cb] =
            *(const short8*)&vdv[(size_t)(s0 + r) * 2048 + b * 1024 + h * 64 + cb];
    }
    for (int u = t; u < 32 * 8; u += 256) {
        int r = u >> 3, cb = (u & 7) * 8;
        *(short8*)&Wd[r * 72 + cb] =
            *(const short8*)&wb[(size_t)bh * 32768 + r * 1024 + s0 + cb];
        *(short8*)&Mc[r * 72 + cb] =
            *(const short8*)&Mcum[((size_t)(bh * 16 + qi) * 32 + r) * 64 + cb];
    }
    for (int u = t; u < 64 * 4; u += 256) {
        int r = u >> 2, cb = (u & 3) * 8;
        *(short8*)&WTd[r * 40 + cb] =
            *(const short8*)&wT[(size_t)bh * 32768 + (s0 + r) * 32 + cb];
        *(short8*)&Nc[r * 40 + cb] =
            *(const short8*)&NTcum[((size_t)(bh * 16 + qi) * 64 + r) * 32 + cb];
    }
    __syncthreads();

    // P1: VTd[d][s] = Gs[s][d]
    for (int u = t; u < 64 * 8; u += 256) {
        int d = u >> 3, s8 = (u & 7) * 8;
        short8 o;
#pragma unroll
        for (int k = 0; k < 8; ++k) o[k] = Gs[(s8 + k) * 72 + d];
        *(short8*)&VTd[d * 72 + s8] = o;
    }
    __syncthreads();

    // P2: G = q @ k_diag^T, causal, -> Gs
    {
        f32x4 accG[2][2] = {};
#pragma unroll
        for (int ks = 0; ks < 2; ++ks) {
            short8 a8[2], b8[2];
#pragma unroll
            for (int i = 0; i < 2; ++i)
                a8[i] = *(const short8*)&Qs[(wy * 32 + i * 16 + ln) * 72 + ks * 32 + lq * 8];
#pragma unroll
            for (int j = 0; j < 2; ++j)
                b8[j] = *(const short8*)&Kd[(wx * 32 + j * 16 + ln) * 72 + ks * 32 + lq * 8];
#pragma unroll
            for (int i = 0; i < 2; ++i)
#pragma unroll
                for (int j = 0; j < 2; ++j)
                    accG[i][j] = __builtin_amdgcn_mfma_f32_16x16x32_bf16(a8[i], b8[j], accG[i][j], 0, 0, 0);
        }
        __syncthreads();  // VTd transpose reads of Gs done before overwrite
#pragma unroll
        for (int i = 0; i < 2; ++i) {
            int row = wy * 32 + i * 16 + lq * 4;
#pragma unroll
            for (int j = 0; j < 2; ++j) {
                int col = wx * 32 + j * 16 + ln;
#pragma unroll
                for (int r = 0; r < 4; ++r) {
                    float v = accG[i][j][r];
                    if (col > row + r) v = 0.f;
                    Gs[(row + r) * 72 + col] = f2b(v);
                }
            }
        }
    }
    __syncthreads();

    // P3: up = G @ w_diag^T + q @ Mcum^T
    f32x4 accU[2] = {};
#pragma unroll
    for (int ks = 0; ks < 2; ++ks) {
        short8 ga = *(const short8*)&Gs[(w * 16 + ln) * 72 + ks * 32 + lq * 8];
        short8 qa = *(const short8*)&Qs[(w * 16 + ln) * 72 + ks * 32 + lq * 8];
#pragma unroll
        for (int j = 0; j < 2; ++j) {
            short8 wf = *(const short8*)&Wd[(j * 16 + ln) * 72 + ks * 32 + lq * 8];
            short8 mf = *(const short8*)&Mc[(j * 16 + ln) * 72 + ks * 32 + lq * 8];
            accU[j] = __builtin_amdgcn_mfma_f32_16x16x32_bf16(ga, wf, accU[j], 0, 0, 0);
            accU[j] = __builtin_amdgcn_mfma_f32_16x16x32_bf16(qa, mf, accU[j], 0, 0, 0);
        }
    }
    __syncthreads();

    // P4: softmax(up*invn) -> ptil into Qs (stride 40)
    {
        int rowl = w * 16 + lq * 4;
#pragma unroll
        for (int r = 0; r < 4; ++r) {
            int srow = s0 + rowl + r;
            float inv0 = invn[(size_t)bh * 32768 + srow * 32 + ln];
            float inv1 = invn[(size_t)bh * 32768 + srow * 32 + 16 + ln];
            float l0 = accU[0][r] * inv0;
            float l1 = accU[1][r] * inv1;
            float m = fmaxf(l0, l1);
#pragma unroll
            for (int msk = 1; msk < 16; msk <<= 1) m = fmaxf(m, __shfl_xor(m, msk));
            float e0 = __expf(l0 - m), e1 = __expf(l1 - m);
            float Z = e0 + e1;
#pragma unroll
            for (int msk = 1; msk < 16; msk <<= 1) Z += __shfl_xor(Z, msk);
            float iz = 1.0f / Z;
            Qs[(rowl + r) * 40 + ln]      = f2b(e0 * iz * inv0);
            Qs[(rowl + r) * 40 + 16 + ln] = f2b(e1 * iz * inv1);
        }
    }
    __syncthreads();

    // P5: SC = ptil @ wT_diag^T (K=32), causal, -> Gs
    short8 pa[2];
#pragma unroll
    for (int i = 0; i < 2; ++i)
        pa[i] = *(const short8*)&Qs[(wy * 32 + i * 16 + ln) * 40 + lq * 8];
    {
        f32x4 accS[2][2] = {};
        short8 b8[2];
#pragma unroll
        for (int j = 0; j < 2; ++j)
            b8[j] = *(const short8*)&WTd[(wx * 32 + j * 16 + ln) * 40 + lq * 8];
#pragma unroll
        for (int i = 0; i < 2; ++i)
#pragma unroll
            for (int j = 0; j < 2; ++j)
                accS[i][j] = __builtin_amdgcn_mfma_f32_16x16x32_bf16(pa[i], b8[j], accS[i][j], 0, 0, 0);
#pragma unroll
        for (int i = 0; i < 2; ++i) {
            int row = wy * 32 + i * 16 + lq * 4;
#pragma unroll
            for (int j = 0; j < 2; ++j) {
                int col = wx * 32 + j * 16 + ln;
#pragma unroll
                for (int r = 0; r < 4; ++r) {
                    float v = accS[i][j][r];
                    if (col > row + r) v = 0.f;
                    Gs[(row + r) * 72 + col] = f2b(v);
                }
            }
        }
    }
    __syncthreads();

    // P6: out = SC @ vT_diag^T + ptil @ NTcum^T -> attout
    {
        f32x4 accO[2][2] = {};
        short8 n8[2];
#pragma unroll
        for (int j = 0; j < 2; ++j)
            n8[j] = *(const short8*)&Nc[(wx * 32 + j * 16 + ln) * 40 + lq * 8];
#pragma unroll
        for (int i = 0; i < 2; ++i)
#pragma unroll
            for (int j = 0; j < 2; ++j)
                accO[i][j] = __builtin_amdgcn_mfma_f32_16x16x32_bf16(pa[i], n8[j], accO[i][j], 0, 0, 0);
#pragma unroll
        for (int ks = 0; ks < 2; ++ks) {
            short8 a8[2], b8[2];
#pragma unroll
            for (int i = 0; i < 2; ++i)
                a8[i] = *(const short8*)&Gs[(wy * 32 + i * 16 + ln) * 72 + ks * 32 + lq * 8];
#pragma unroll
            for (int j = 0; j < 2; ++j)
                b8[j] = *(const short8*)&VTd[(wx * 32 + j * 16 + ln) * 72 + ks * 32 + lq * 8];
#pragma unroll
            for (int i = 0; i < 2; ++i)
#pragma unroll
                for (int j = 0; j < 2; ++j)
                    accO[i][j] = __builtin_amdgcn_mfma_f32_16x16x32_bf16(a8[i], b8[j], accO[i][j], 0, 0, 0);
        }
#pragma unroll
        for (int i = 0; i < 2; ++i) {
            int rowb = s0 + wy * 32 + i * 16 + lq * 4;
#pragma unroll
            for (int j = 0; j < 2; ++j) {
                int d = wx * 32 + j * 16 + ln;
#pragma unroll
                for (int r = 0; r < 4; ++r)
                    attout[(size_t)(rowb + r) * 2048 + b * 1024 + h * 64 + d] = f2b(accO[i][j][r]);
            }
        }
    }
}

// ---------------------------------------------------------------------------
extern "C" void kernel_launch(void* const* d_in, const int* in_sizes, int n_in,
                              void* d_out, int out_size, void* d_ws, size_t ws_size,
                              hipStream_t stream)
{
    (void)in_sizes; (void)n_in; (void)out_size; (void)ws_size;
    char* ws = (char*)d_ws;
    const size_t MB = (size_t)1 << 20;
    const size_t KB = (size_t)1 << 10;
    unsigned short* attout = (unsigned short*)(ws + 0 * MB);   // 4 MB
    unsigned short* q_u    = (unsigned short*)(ws + 4 * MB);   // 4 MB (pre-scaled)
    unsigned short* k_d    = (unsigned short*)(ws + 8 * MB);   // 4 MB
    unsigned short* v_dk   = (unsigned short*)(ws + 12 * MB);  // 4 MB
    unsigned short* v_dv   = (unsigned short*)(ws + 16 * MB);  // 4 MB
    float* wbuf = (float*)(ws + 20 * MB);                      // 4 MB (down scores)
    unsigned short* wb  = (unsigned short*)(ws + 24 * MB);     // 2 MB [bh][c][s]
    unsigned short* wT  = (unsigned short*)(ws + 26 * MB);     // 2 MB [bh][s][c]
    float* invn = (float*)(ws + 28 * MB);                      // 4 MB [bh][s][c]
    float* Mst  = (float*)(ws + 32 * MB);                      // 4 MB
    float* NTst = (float*)(ws + 36 * MB);                      // 4 MB
    unsigned short* Mcum  = (unsigned short*)(ws + 40 * MB);   // 2 MB
    unsigned short* NTcum = (unsigned short*)(ws + 42 * MB);   // 2 MB
    unsigned short* xb  = (unsigned short*)(ws + 44 * MB);     // 4 MB
    unsigned short* Wqb = (unsigned short*)(ws + 48 * MB);     // 2 MB
    unsigned short* Wkb = (unsigned short*)(ws + 50 * MB);     // 2 MB
    unsigned short* Wvb = (unsigned short*)(ws + 52 * MB);     // 2 MB
    unsigned short* Wob = (unsigned short*)(ws + 54 * MB);     // 2 MB
    unsigned short* WvT = (unsigned short*)(ws + 56 * MB);     // 2 MB
    unsigned short* W2k = (unsigned short*)(ws + 58 * MB);     // 2 MB (Wk·Wv)
    unsigned short* W2v = (unsigned short*)(ws + 60 * MB);     // 2 MB (Wv·Wv)
    unsigned short* qdb = (unsigned short*)(ws + 62 * MB);     // 64 KB
    float* biasf  = (float*)(ws + 62 * MB + 64 * KB);          // 20 KB [bq,bk,bv,bo,zero]
    float* b2k    = (float*)(ws + 62 * MB + 128 * KB);         // 4 KB
    float* b2v    = (float*)(ws + 62 * MB + 132 * KB);         // 4 KB
    float* cmax   = (float*)(ws + 62 * MB + 192 * KB);         // 32 KB
    float* csum   = (float*)(ws + 62 * MB + 256 * KB);         // 32 KB
    int*   flag   = (int*)  (ws + 62 * MB + 320 * KB);

    const unsigned short* xraw  = (const unsigned short*)d_in[0];
    const unsigned short* qdraw = (const unsigned short*)d_in[1];
    const unsigned short* wqraw = (const unsigned short*)d_in[2];
    const unsigned short* wkraw = (const unsigned short*)d_in[4];
    const unsigned short* wvraw = (const unsigned short*)d_in[6];
    const unsigned short* woraw = (const unsigned short*)d_in[8];

    // convert (inline sniff; bf16 case converts only biases)
    k_convert<<<1024, 256, 0, stream>>>(
        d_in[0], d_in[1], d_in[2], d_in[4], d_in[6], d_in[8],
        d_in[3], d_in[5], d_in[7], d_in[9],
        flag, xb, qdb, Wqb, Wkb, Wvb, Wob, biasf);

    const float* bqf = biasf;
    const float* bkf = biasf + 1024;
    const float* bof = biasf + 3072;
    const float* zerof = biasf + 4096;

    // weight prep: WvT + combined biases, then W2k = Wk·Wv, W2v = Wv·Wv
    k_prep<<<192, 256, 0, stream>>>(Wvb, wvraw, Wkb, wkraw, flag, biasf, WvT, b2k, b2v);
    GArg wpk{ Wkb, wkraw, WvT, WvT, zerof, (void*)W2k, 1.0f, 1 };
    GArg wpv{ Wvb, wvraw, WvT, WvT, zerof, (void*)W2v, 1.0f, 1 };
    gemm_bt_n64<<<dim3(16, 8, 2), 256, 0, stream>>>(wpk, wpv, flag, DM, DM, DM);

    // main projections: q_u (scaled), k_d, v_dk, v_dv in ONE launch (512 blocks)
    GArg gq { xb, xraw, Wqb, wqraw, bqf, (void*)q_u, 0.125f, 1 };
    GArg gk { xb, xraw, Wkb, wkraw, bkf, (void*)k_d, 1.0f, 1 };
    GArg gvk{ xb, xraw, W2k, W2k,   b2k, (void*)v_dk, 1.0f, 1 };
    GArg gvv{ xb, xraw, W2v, W2v,   b2v, (void*)v_dv, 1.0f, 1 };
    gemm_bt<<<dim3(8, 16, 4), 256, 0, stream>>>(gq, gk, gvk, gvv, flag, SB, DM, DM);

    // attention mid-section
    k_down<<<dim3(32, NCHD), 256, 0, stream>>>(k_d, qdb, qdraw, flag, wbuf, cmax, csum);
    k_wapply<<<dim3(32, 8), 256, 0, stream>>>(wbuf, cmax, csum, wb, wT, invn);
    k_state<<<dim3(32, 16), 256, 0, stream>>>(wb, v_dk, v_dv, Mst, NTst);
    k_prefix<<<dim3(32, 2), 256, 0, stream>>>(Mst, NTst, Mcum, NTcum);
    k_att<<<dim3(32, 16), 256, 0, stream>>>(q_u, v_dk, wb, invn, wT, v_dv, Mcum, NTcum, attout);

    // final projection (256 blocks): out dtype follows sniffed input dtype
    GArg go{ attout, attout, Wob, woraw, bof, d_out, 1.0f, 2 };
    gemm_bt_n64<<<dim3(16, 16, 1), 256, 0, stream>>>(go, go, flag, SB, DM, DM);
}